// Round 1
// baseline (9637.254 us; speedup 1.0000x reference)
//
#include <hip/hip_runtime.h>
#include <math.h>

// ---------------- constants ----------------
#define B_SZ 4
#define DIM 384
#define HEADS 6
#define HD 64
#define GRID_T 32          // 32x32 token grid
#define NTOK 4096          // B*32*32
#define WS 14
#define NWIN 36            // B * 9
#define WTOK 196           // 14*14
#define PWTOK 7056         // 36*196
#define SCALE_F 0.125f     // 64^-0.5

// ---------------- im2col for patch embed ----------------
__global__ __launch_bounds__(256) void im2col_kernel(const float* __restrict__ x,
                                                     float* __restrict__ col) {
    size_t idx = (size_t)blockIdx.x * 256 + threadIdx.x;
    if (idx >= (size_t)NTOK * 768) return;
    int kk = (int)(idx % 768);
    int p  = (int)(idx / 768);
    int b  = p / 1024;
    int ph = (p % 1024) / 32;
    int pw = p % 32;
    int c = kk / 256;
    int r = kk % 256;
    int i = r / 16, j = r % 16;
    col[idx] = x[(size_t)b * 3 * 512 * 512 + (size_t)c * 512 * 512 +
                 (size_t)(ph * 16 + i) * 512 + (pw * 16 + j)];
}

// ---------------- bicubic pos embed (jax.image.resize semantics) ----------------
__device__ inline float cubic_keys(float x) {
    x = fabsf(x);
    if (x <= 1.f) return ((1.5f * x - 2.5f) * x) * x + 1.f;
    if (x < 2.f)  return ((-0.5f * x + 2.5f) * x - 4.f) * x + 2.f;
    return 0.f;
}

__global__ __launch_bounds__(256) void add_pos_kernel(const float* __restrict__ pe,
                                                      float* __restrict__ y) {
    int idx = blockIdx.x * 256 + threadIdx.x;   // 1024*384
    if (idx >= 1024 * 384) return;
    int c = idx % 384;
    int g = idx / 384;
    int gy = g / 32, gx = g % 32;
    float wy[14], wx[14];
    float sy = (gy + 0.5f) * (14.f / 32.f) - 0.5f;
    float sx = (gx + 0.5f) * (14.f / 32.f) - 0.5f;
    float toty = 0.f, totx = 0.f;
    #pragma unroll
    for (int k = 0; k < 14; ++k) {
        wy[k] = cubic_keys(sy - (float)k); toty += wy[k];
        wx[k] = cubic_keys(sx - (float)k); totx += wx[k];
    }
    float val = 0.f;
    #pragma unroll 1
    for (int iy = 0; iy < 14; ++iy) {
        if (wy[iy] == 0.f) continue;
        float row = 0.f;
        for (int ix = 0; ix < 14; ++ix) {
            if (wx[ix] == 0.f) continue;
            row += wx[ix] * pe[(iy * 14 + ix) * 384 + c];
        }
        val += wy[iy] * row;
    }
    val /= (toty * totx);
    #pragma unroll
    for (int b = 0; b < B_SZ; ++b)
        y[((size_t)(b * 1024 + g)) * 384 + c] += val;
}

// ---------------- layernorm: one wave per token ----------------
__global__ __launch_bounds__(64) void ln_kernel(const float* __restrict__ x,
                                                const float* __restrict__ w,
                                                const float* __restrict__ b,
                                                float* __restrict__ out) {
    int tok = blockIdx.x;
    int t = threadIdx.x;
    const float* xr = x + (size_t)tok * 384;
    float v[6];
    float s = 0.f;
    #pragma unroll
    for (int i = 0; i < 6; ++i) { v[i] = xr[t + 64 * i]; s += v[i]; }
    #pragma unroll
    for (int off = 32; off > 0; off >>= 1) s += __shfl_xor(s, off);
    float mean = s * (1.f / 384.f);
    float vs = 0.f;
    #pragma unroll
    for (int i = 0; i < 6; ++i) { float d = v[i] - mean; vs += d * d; }
    #pragma unroll
    for (int off = 32; off > 0; off >>= 1) vs += __shfl_xor(vs, off);
    float inv = rsqrtf(vs * (1.f / 384.f) + 1e-5f);
    float* orow = out + (size_t)tok * 384;
    #pragma unroll
    for (int i = 0; i < 6; ++i) {
        int c = t + 64 * i;
        orow[c] = (v[i] - mean) * inv * w[c] + b[c];
    }
}

// ---------------- window partition / unpartition ----------------
__global__ __launch_bounds__(256) void winpart_kernel(const float* __restrict__ xn,
                                                      float* __restrict__ win) {
    size_t idx = (size_t)blockIdx.x * 256 + threadIdx.x;   // 7056*384
    if (idx >= (size_t)PWTOK * 384) return;
    int c = (int)(idx % 384);
    int tk = (int)(idx / 384);
    int wtok = tk % WTOK;
    int w = tk / WTOK;
    int b = w / 9;
    int wy = (w % 9) / 3, wx = w % 3;
    int iy = wtok / WS, ix = wtok % WS;
    int gy = wy * WS + iy, gx = wx * WS + ix;
    float val = 0.f;
    if (gy < 32 && gx < 32)
        val = xn[((size_t)(b * 1024 + gy * 32 + gx)) * 384 + c];
    win[idx] = val;
}

__global__ __launch_bounds__(256) void winunpart_kernel(const float* __restrict__ aout,
                                                        float* __restrict__ out) {
    size_t idx = (size_t)blockIdx.x * 256 + threadIdx.x;   // 4096*384
    if (idx >= (size_t)NTOK * 384) return;
    int c = (int)(idx % 384);
    int tk = (int)(idx / 384);
    int b = tk / 1024;
    int g = tk % 1024;
    int gy = g / 32, gx = g % 32;
    int wy = gy / WS, iy = gy % WS;
    int wx = gx / WS, ix = gx % WS;
    int w = b * 9 + wy * 3 + wx;
    out[idx] = aout[((size_t)(w * WTOK + iy * WS + ix)) * 384 + c];
}

// ---------------- generic tiled GEMM: C = A[M,K] @ W[N,K]^T + bias (+res) (gelu) ----------------
__global__ __launch_bounds__(256) void gemm_kernel(const float* __restrict__ A,
                                                   const float* __restrict__ W,
                                                   const float* __restrict__ bias,
                                                   const float* __restrict__ res,
                                                   float* __restrict__ C,
                                                   int M, int N, int K, int act) {
    __shared__ float As[64][17];
    __shared__ float Wsm[64][17];
    int t = threadIdx.x;
    int tx = t & 15, ty = t >> 4;
    int n0 = blockIdx.x * 64, m0 = blockIdx.y * 64;
    float acc[4][4] = {};
    for (int k0 = 0; k0 < K; k0 += 16) {
        #pragma unroll
        for (int rr = 0; rr < 4; ++rr) {
            int r = ty + 16 * rr;
            int m = m0 + r;
            As[r][tx]  = (m < M) ? A[(size_t)m * K + k0 + tx] : 0.f;
            int n = n0 + r;
            Wsm[r][tx] = (n < N) ? W[(size_t)n * K + k0 + tx] : 0.f;
        }
        __syncthreads();
        #pragma unroll
        for (int kk = 0; kk < 16; ++kk) {
            float a[4], w[4];
            #pragma unroll
            for (int i = 0; i < 4; ++i) a[i] = As[ty + 16 * i][kk];
            #pragma unroll
            for (int j = 0; j < 4; ++j) w[j] = Wsm[tx + 16 * j][kk];
            #pragma unroll
            for (int i = 0; i < 4; ++i)
                #pragma unroll
                for (int j = 0; j < 4; ++j) acc[i][j] += a[i] * w[j];
        }
        __syncthreads();
    }
    #pragma unroll
    for (int i = 0; i < 4; ++i) {
        int m = m0 + ty + 16 * i;
        if (m >= M) continue;
        #pragma unroll
        for (int j = 0; j < 4; ++j) {
            int n = n0 + tx + 16 * j;
            if (n >= N) continue;
            float v = acc[i][j] + bias[n];
            if (res) v += res[(size_t)m * N + n];
            if (act == 1) v = 0.5f * v * (1.f + erff(v * 0.70710678118654752f));
            C[(size_t)m * N + n] = v;
        }
    }
}

// ---------------- attention: one block per (unit, head, query) ----------------
__global__ __launch_bounds__(256) void attn_kernel(const float* __restrict__ qkv,
                                                   const float* __restrict__ relh,
                                                   const float* __restrict__ relw,
                                                   float* __restrict__ out,
                                                   int N, int H, int W) {
    __shared__ float q_sh[HD];
    __shared__ float bh[32], bw[32];
    __shared__ float sc[1024];
    __shared__ float red[256];
    __shared__ float part[4][HD];
    int t = threadIdx.x;
    int qi = blockIdx.x % N;
    int h  = (blockIdx.x / N) % HEADS;
    int u  = blockIdx.x / (N * HEADS);
    size_t base = (size_t)u * N;

    if (t < HD) q_sh[t] = qkv[(base + qi) * 1152 + h * 64 + t];
    __syncthreads();

    int qh = qi / W, qw = qi % W;
    for (int idx = t; idx < H + W; idx += 256) {
        const float* r = (idx < H)
            ? relh + (size_t)(qh - idx + H - 1) * 64
            : relw + (size_t)(qw - (idx - H) + W - 1) * 64;
        float s = 0.f;
        #pragma unroll
        for (int c = 0; c < 64; ++c) s += q_sh[c] * r[c];
        if (idx < H) bh[idx] = s; else bw[idx - H] = s;
    }
    __syncthreads();

    float lmax = -1e30f;
    for (int k = t; k < N; k += 256) {
        const float4* krow = (const float4*)(qkv + (base + k) * 1152 + 384 + h * 64);
        float s = 0.f;
        #pragma unroll
        for (int c4 = 0; c4 < 16; ++c4) {
            float4 kv = krow[c4];
            s += q_sh[c4 * 4 + 0] * kv.x + q_sh[c4 * 4 + 1] * kv.y +
                 q_sh[c4 * 4 + 2] * kv.z + q_sh[c4 * 4 + 3] * kv.w;
        }
        s = s * SCALE_F + bh[k / W] + bw[k % W];
        sc[k] = s;
        lmax = fmaxf(lmax, s);
    }
    red[t] = lmax;
    __syncthreads();
    for (int s = 128; s > 0; s >>= 1) {
        if (t < s) red[t] = fmaxf(red[t], red[t + s]);
        __syncthreads();
    }
    float m = red[0];
    __syncthreads();

    float lsum = 0.f;
    for (int k = t; k < N; k += 256) {
        float p = __expf(sc[k] - m);
        sc[k] = p;
        lsum += p;
    }
    red[t] = lsum;
    __syncthreads();
    for (int s = 128; s > 0; s >>= 1) {
        if (t < s) red[t] += red[t + s];
        __syncthreads();
    }
    float inv = 1.f / red[0];

    int d = t & 63, g = t >> 6;
    float acc = 0.f;
    for (int k = g; k < N; k += 4)
        acc += sc[k] * qkv[(base + k) * 1152 + 768 + h * 64 + d];
    part[g][d] = acc;
    __syncthreads();
    if (t < 64) {
        float o = (part[0][t] + part[1][t] + part[2][t] + part[3][t]) * inv;
        out[(base + qi) * 384 + h * 64 + t] = o;
    }
}

// ---------------- final NHWC -> NCHW ----------------
__global__ __launch_bounds__(256) void out_transpose_kernel(const float* __restrict__ y,
                                                            float* __restrict__ out) {
    size_t idx = (size_t)blockIdx.x * 256 + threadIdx.x;   // 4*384*1024
    if (idx >= (size_t)B_SZ * 384 * 1024) return;
    int g = (int)(idx % 1024);
    int c = (int)((idx / 1024) % 384);
    int b = (int)(idx / (1024 * 384));
    out[idx] = y[((size_t)b * 1024 + g) * 384 + c];
}

// ---------------- host ----------------
static inline void launch_gemm(const float* A, const float* W, const float* bias,
                               const float* res, float* C, int M, int N, int K,
                               int act, hipStream_t s) {
    dim3 g((N + 63) / 64, (M + 63) / 64);
    gemm_kernel<<<g, 256, 0, s>>>(A, W, bias, res, C, M, N, K, act);
}

extern "C" void kernel_launch(void* const* d_in, const int* in_sizes, int n_in,
                              void* d_out, int out_size, void* d_ws, size_t ws_size,
                              hipStream_t stream) {
    const float* x      = (const float*)d_in[0];
    const float* patchw = (const float*)d_in[1];
    const float* patchb = (const float*)d_in[2];
    const float* pos    = (const float*)d_in[3];
    const float* n1w    = (const float*)d_in[4];
    const float* n1b    = (const float*)d_in[5];
    const float* qkvw   = (const float*)d_in[6];
    const float* qkvb   = (const float*)d_in[7];
    const float* pw     = (const float*)d_in[8];
    const float* pb     = (const float*)d_in[9];
    const float* n2w    = (const float*)d_in[10];
    const float* n2b    = (const float*)d_in[11];
    const float* f1w    = (const float*)d_in[12];
    const float* f1b    = (const float*)d_in[13];
    const float* f2w    = (const float*)d_in[14];
    const float* f2b    = (const float*)d_in[15];
    const float* rph    = (const float*)d_in[16];
    const float* rpw    = (const float*)d_in[17];
    float* out = (float*)d_out;

    float* ws    = (float*)d_ws;
    float* y     = ws;                       // 4096*384   = 1572864
    float* win   = y     + 1572864;          // 7056*384   = 2709504
    float* qkv   = win   + 2709504;          // 7056*1152  = 8128512
    float* att   = qkv   + 8128512;          // 7056*384   = 2709504
    float* lnout = att   + 2709504;          // 4096*384   = 1572864
    float* mlp   = lnout + 1572864;          // 4096*1536  = 6291456

    // patch embed: im2col (into qkv scratch) + GEMM -> y
    {
        size_t tot = (size_t)NTOK * 768;
        im2col_kernel<<<(int)((tot + 255) / 256), 256, 0, stream>>>(x, qkv);
        launch_gemm(qkv, patchw, patchb, nullptr, y, NTOK, 384, 768, 0, stream);
        add_pos_kernel<<<(1024 * 384 + 255) / 256, 256, 0, stream>>>(pos, y);
    }

    for (int i = 0; i < 6; ++i) {
        bool windowed = (i == 0 || i == 1 || i == 3 || i == 4);
        ln_kernel<<<NTOK, 64, 0, stream>>>(y, n1w + i * 384, n1b + i * 384, lnout);
        const float* rh = rph + (size_t)i * 63 * 64;
        const float* rw = rpw + (size_t)i * 63 * 64;
        if (windowed) {
            size_t tot = (size_t)PWTOK * 384;
            winpart_kernel<<<(int)((tot + 255) / 256), 256, 0, stream>>>(lnout, win);
            launch_gemm(win, qkvw + (size_t)i * 1152 * 384, qkvb + i * 1152,
                        nullptr, qkv, PWTOK, 1152, 384, 0, stream);
            attn_kernel<<<NWIN * HEADS * WTOK, 256, 0, stream>>>(qkv, rh, rw, att,
                                                                 WTOK, WS, WS);
            size_t tot2 = (size_t)NTOK * 384;
            winunpart_kernel<<<(int)((tot2 + 255) / 256), 256, 0, stream>>>(att, lnout);
            launch_gemm(lnout, pw + (size_t)i * 384 * 384, pb + i * 384,
                        y, y, NTOK, 384, 384, 0, stream);
        } else {
            launch_gemm(lnout, qkvw + (size_t)i * 1152 * 384, qkvb + i * 1152,
                        nullptr, qkv, NTOK, 1152, 384, 0, stream);
            attn_kernel<<<B_SZ * HEADS * 1024, 256, 0, stream>>>(qkv, rh, rw, att,
                                                                 1024, 32, 32);
            launch_gemm(att, pw + (size_t)i * 384 * 384, pb + i * 384,
                        y, y, NTOK, 384, 384, 0, stream);
        }
        ln_kernel<<<NTOK, 64, 0, stream>>>(y, n2w + i * 384, n2b + i * 384, lnout);
        launch_gemm(lnout, f1w + (size_t)i * 1536 * 384, f1b + i * 1536,
                    nullptr, mlp, NTOK, 1536, 384, 1, stream);
        launch_gemm(mlp, f2w + (size_t)i * 384 * 1536, f2b + i * 384,
                    y, y, NTOK, 384, 1536, 0, stream);
    }

    {
        size_t tot = (size_t)B_SZ * 384 * 1024;
        out_transpose_kernel<<<(int)((tot + 255) / 256), 256, 0, stream>>>(y, out);
    }
}

// Round 2
// 2879.798 us; speedup vs baseline: 3.3465x; 3.3465x over previous
//
#include <hip/hip_runtime.h>
#include <math.h>

// ---------------- constants ----------------
#define B_SZ 4
#define DIM 384
#define HEADS 6
#define HD 64
#define NTOK 4096          // B*32*32
#define WS 14
#define NWIN 36            // B * 9
#define WTOK 196           // 14*14
#define PWTOK 7056         // 36*196
#define MPAD 7168          // padded rows for windowed qkv GEMM (56*128)
#define SCALE_F 0.125f     // 64^-0.5

typedef unsigned short u16;
typedef __bf16 bf16_t;
typedef bf16_t bf16x8 __attribute__((ext_vector_type(8)));
typedef float f32x4 __attribute__((ext_vector_type(4)));

__device__ __forceinline__ float bf2f(unsigned u) { return __uint_as_float(u << 16); }
__device__ __forceinline__ u16 f2bf(float f) {
    unsigned u = __float_as_uint(f);
    unsigned r = (u + 0x7fffu + ((u >> 16) & 1u)) >> 16;
    return (u16)r;
}

// async global->LDS, 16B per lane, wave-uniform LDS base + lane*16
__device__ __forceinline__ void ldsload16(const u16* g, u16* l) {
    __builtin_amdgcn_global_load_lds(
        (const __attribute__((address_space(1))) unsigned int*)g,
        (__attribute__((address_space(3))) unsigned int*)l, 16, 0, 0);
}

__device__ __forceinline__ int swz(int r) { return (r ^ (r >> 2)) & 3; }

// ---------------- fp32 -> bf16 convert ----------------
__global__ __launch_bounds__(256) void w2b_kernel(const float* __restrict__ s,
                                                  u16* __restrict__ d, int n) {
    int i = blockIdx.x * 256 + threadIdx.x;
    if (i < n) d[i] = f2bf(s[i]);
}

// ---------------- im2col (bf16 out) ----------------
__global__ __launch_bounds__(256) void im2col_kernel(const float* __restrict__ x,
                                                     u16* __restrict__ col) {
    size_t idx = (size_t)blockIdx.x * 256 + threadIdx.x;
    if (idx >= (size_t)NTOK * 768) return;
    int kk = (int)(idx % 768);
    int p  = (int)(idx / 768);
    int b  = p / 1024;
    int ph = (p % 1024) / 32;
    int pw = p % 32;
    int c = kk / 256;
    int r = kk % 256;
    int i = r / 16, j = r % 16;
    col[idx] = f2bf(x[(size_t)b * 3 * 512 * 512 + (size_t)c * 512 * 512 +
                      (size_t)(ph * 16 + i) * 512 + (pw * 16 + j)]);
}

// ---------------- bicubic pos embed (fp32, unchanged) ----------------
__device__ inline float cubic_keys(float x) {
    x = fabsf(x);
    if (x <= 1.f) return ((1.5f * x - 2.5f) * x) * x + 1.f;
    if (x < 2.f)  return ((-0.5f * x + 2.5f) * x - 4.f) * x + 2.f;
    return 0.f;
}

__global__ __launch_bounds__(256) void add_pos_kernel(const float* __restrict__ pe,
                                                      float* __restrict__ y) {
    int idx = blockIdx.x * 256 + threadIdx.x;   // 1024*384
    if (idx >= 1024 * 384) return;
    int c = idx % 384;
    int g = idx / 384;
    int gy = g / 32, gx = g % 32;
    float wy[14], wx[14];
    float sy = (gy + 0.5f) * (14.f / 32.f) - 0.5f;
    float sx = (gx + 0.5f) * (14.f / 32.f) - 0.5f;
    float toty = 0.f, totx = 0.f;
    #pragma unroll
    for (int k = 0; k < 14; ++k) {
        wy[k] = cubic_keys(sy - (float)k); toty += wy[k];
        wx[k] = cubic_keys(sx - (float)k); totx += wx[k];
    }
    float val = 0.f;
    #pragma unroll 1
    for (int iy = 0; iy < 14; ++iy) {
        if (wy[iy] == 0.f) continue;
        float row = 0.f;
        for (int ix = 0; ix < 14; ++ix) {
            if (wx[ix] == 0.f) continue;
            row += wx[ix] * pe[(iy * 14 + ix) * 384 + c];
        }
        val += wy[iy] * row;
    }
    val /= (toty * totx);
    #pragma unroll
    for (int b = 0; b < B_SZ; ++b)
        y[((size_t)(b * 1024 + g)) * 384 + c] += val;
}

// ---------------- layernorm: fp32 in, bf16 out ----------------
__global__ __launch_bounds__(64) void ln_kernel(const float* __restrict__ x,
                                                const float* __restrict__ w,
                                                const float* __restrict__ b,
                                                u16* __restrict__ out) {
    int tok = blockIdx.x;
    int t = threadIdx.x;
    const float* xr = x + (size_t)tok * 384;
    float v[6];
    float s = 0.f;
    #pragma unroll
    for (int i = 0; i < 6; ++i) { v[i] = xr[t + 64 * i]; s += v[i]; }
    #pragma unroll
    for (int off = 32; off > 0; off >>= 1) s += __shfl_xor(s, off);
    float mean = s * (1.f / 384.f);
    float vs = 0.f;
    #pragma unroll
    for (int i = 0; i < 6; ++i) { float d = v[i] - mean; vs += d * d; }
    #pragma unroll
    for (int off = 32; off > 0; off >>= 1) vs += __shfl_xor(vs, off);
    float inv = rsqrtf(vs * (1.f / 384.f) + 1e-5f);
    u16* orow = out + (size_t)tok * 384;
    #pragma unroll
    for (int i = 0; i < 6; ++i) {
        int c = t + 64 * i;
        orow[c] = f2bf((v[i] - mean) * inv * w[c] + b[c]);
    }
}

// ---------------- window partition / unpartition (bf16) ----------------
__global__ __launch_bounds__(256) void winpart_kernel(const u16* __restrict__ xn,
                                                      u16* __restrict__ win) {
    size_t idx = (size_t)blockIdx.x * 256 + threadIdx.x;   // MPAD*384
    if (idx >= (size_t)MPAD * 384) return;
    int c = (int)(idx % 384);
    int tk = (int)(idx / 384);
    if (tk >= PWTOK) { win[idx] = 0; return; }
    int wtok = tk % WTOK;
    int w = tk / WTOK;
    int b = w / 9;
    int wy = (w % 9) / 3, wx = w % 3;
    int iy = wtok / WS, ix = wtok % WS;
    int gy = wy * WS + iy, gx = wx * WS + ix;
    u16 val = 0;
    if (gy < 32 && gx < 32)
        val = xn[((size_t)(b * 1024 + gy * 32 + gx)) * 384 + c];
    win[idx] = val;
}

__global__ __launch_bounds__(256) void winunpart_kernel(const u16* __restrict__ aout,
                                                        u16* __restrict__ out) {
    size_t idx = (size_t)blockIdx.x * 256 + threadIdx.x;   // 4096*384
    if (idx >= (size_t)NTOK * 384) return;
    int c = (int)(idx % 384);
    int tk = (int)(idx / 384);
    int b = tk / 1024;
    int g = tk % 1024;
    int gy = g / 32, gx = g % 32;
    int wy = gy / WS, iy = gy % WS;
    int wx = gx / WS, ix = gx % WS;
    int w = b * 9 + wy * 3 + wx;
    out[idx] = aout[((size_t)(w * WTOK + iy * WS + ix)) * 384 + c];
}

// ---------------- MFMA bf16 GEMM: C = A[M,K] @ W[N,K]^T + bias (+res)(gelu) ----------------
// M % 128 == 0, N % 128 == 0, K % 32 == 0. A, W bf16 (u16 bits); bias/res fp32.
__global__ __launch_bounds__(256) void mfma_gemm(
        const u16* __restrict__ A, const u16* __restrict__ Wt,
        const float* __restrict__ bias, const float* __restrict__ res,
        float* __restrict__ outf, u16* __restrict__ outb,
        int M, int N, int K, int act)
{
    __shared__ u16 As[4096];   // 128 rows x 32 cols (col-quads XOR-swizzled per row)
    __shared__ u16 Bs[4096];
    int t = threadIdx.x;
    int lane = t & 63, wave = t >> 6;
    int wm = (wave >> 1) * 64, wn = (wave & 1) * 64;
    int m0 = blockIdx.y * 128, n0 = blockIdx.x * 128;

    int r0 = t >> 2,        c0 = ((t & 3) ^ swz(t >> 2)) * 8;
    int r1 = 64 + (t >> 2), c1 = ((t & 3) ^ swz(64 + (t >> 2))) * 8;
    const u16* a0 = A + (size_t)(m0 + r0) * K + c0;
    const u16* a1 = A + (size_t)(m0 + r1) * K + c1;
    const u16* b0 = Wt + (size_t)(n0 + r0) * K + c0;
    const u16* b1 = Wt + (size_t)(n0 + r1) * K + c1;
    u16* asd0 = &As[(wave * 64) * 8];
    u16* asd1 = &As[(256 + wave * 64) * 8];
    u16* bsd0 = &Bs[(wave * 64) * 8];
    u16* bsd1 = &Bs[(256 + wave * 64) * 8];

    f32x4 acc[4][4] = {};
    int row_a = wm + (lane & 15);
    int row_b = wn + (lane & 15);
    int lq = lane >> 4;

    for (int k0 = 0; k0 < K; k0 += 32) {
        ldsload16(a0 + k0, asd0);
        ldsload16(a1 + k0, asd1);
        ldsload16(b0 + k0, bsd0);
        ldsload16(b1 + k0, bsd1);
        __syncthreads();   // drains vmcnt before barrier
        bf16x8 af[4], bfr[4];
        #pragma unroll
        for (int i = 0; i < 4; ++i) {
            int r = row_a + i * 16;
            af[i] = *(const bf16x8*)&As[r * 32 + ((lq ^ swz(r)) * 8)];
        }
        #pragma unroll
        for (int j = 0; j < 4; ++j) {
            int r = row_b + j * 16;
            bfr[j] = *(const bf16x8*)&Bs[r * 32 + ((lq ^ swz(r)) * 8)];
        }
        #pragma unroll
        for (int i = 0; i < 4; ++i)
            #pragma unroll
            for (int j = 0; j < 4; ++j)
                acc[i][j] = __builtin_amdgcn_mfma_f32_16x16x32_bf16(
                    af[i], bfr[j], acc[i][j], 0, 0, 0);
        __syncthreads();
    }

    int colq = lane & 15, rowq = (lane >> 4) * 4;
    #pragma unroll
    for (int i = 0; i < 4; ++i) {
        #pragma unroll
        for (int rr = 0; rr < 4; ++rr) {
            int m = m0 + wm + i * 16 + rowq + rr;
            size_t mo = (size_t)m * N;
            #pragma unroll
            for (int j = 0; j < 4; ++j) {
                int n = n0 + wn + j * 16 + colq;
                float v = acc[i][j][rr] + bias[n];
                if (res)  v += res[mo + n];
                if (act)  v = 0.5f * v * (1.f + erff(v * 0.70710678118654752f));
                if (outf) outf[mo + n] = v;
                if (outb) outb[mo + n] = f2bf(v);
            }
        }
    }
}

// ---------------- rel-pos bias precompute ----------------
// bhg[(uh*N+q)*32 + kh] = sum_c q[c]*Rh[qh-kh+H-1][c]; bwg analogous.
__global__ __launch_bounds__(64) void relbias_kernel(const u16* __restrict__ qkv,
        const float* __restrict__ rh, const float* __restrict__ rw,
        float* __restrict__ bhg, float* __restrict__ bwg, int N, int H, int W)
{
    int t = threadIdx.x;
    int q = blockIdx.x % N, uh = blockIdx.x / N;
    int h = uh % HEADS, u = uh / HEADS;
    if (t >= H + W) return;
    const u16* qp = qkv + ((size_t)u * N + q) * 1152 + h * 64;
    int qh = q / W, qw = q - qh * W;
    const float* R = (t < H) ? rh + (size_t)(qh - t + H - 1) * 64
                             : rw + (size_t)(qw - (t - H) + W - 1) * 64;
    float s = 0.f;
    #pragma unroll
    for (int c = 0; c < 64; ++c) s += bf2f(qp[c]) * R[c];
    if (t < H) bhg[((size_t)uh * N + q) * 32 + t] = s;
    else       bwg[((size_t)uh * N + q) * 32 + (t - H)] = s;
}

// ---------------- register-flash attention ----------------
// grid (UH, ceil(N/64)), block 64. Thread: 4 queries x 16 channels.
__device__ __forceinline__ void unpack8(uint4 v, float* d) {
    d[0] = __uint_as_float(v.x << 16); d[1] = __uint_as_float(v.x & 0xffff0000u);
    d[2] = __uint_as_float(v.y << 16); d[3] = __uint_as_float(v.y & 0xffff0000u);
    d[4] = __uint_as_float(v.z << 16); d[5] = __uint_as_float(v.z & 0xffff0000u);
    d[6] = __uint_as_float(v.w << 16); d[7] = __uint_as_float(v.w & 0xffff0000u);
}

__global__ __launch_bounds__(64) void attn_flash(const u16* __restrict__ qkv,
        const float* __restrict__ bhg, const float* __restrict__ bwg,
        u16* __restrict__ outb, int N, int H, int W)
{
    __shared__ float kt[32][64];
    __shared__ float vt[32][64];
    __shared__ float bt[64][33];
    int uh = blockIdx.x;
    int qbase = blockIdx.y * 64;
    int t = threadIdx.x;
    int slice = t & 3, qq = t >> 2;
    int ch0 = slice * 16;
    int h = uh % HEADS, u = uh / HEADS;
    size_t tbase = (size_t)u * N;

    float qreg[4][16];
    #pragma unroll
    for (int j = 0; j < 4; ++j) {
        int q = qbase + qq + 16 * j; if (q >= N) q = N - 1;
        const u16* qp = qkv + (tbase + q) * 1152 + h * 64 + ch0;
        uint4 qa = *(const uint4*)qp;
        uint4 qb2 = *(const uint4*)(qp + 8);
        float tmp[16];
        unpack8(qa, tmp); unpack8(qb2, tmp + 8);
        #pragma unroll
        for (int c = 0; c < 16; ++c) qreg[j][c] = tmp[c] * SCALE_F;
    }
    float o[4][16] = {};
    float l[4] = {0.f, 0.f, 0.f, 0.f};

    int qme = qbase + t; if (qme >= N) qme = N - 1;
    const float* bh_me = bhg + ((size_t)uh * N + qme) * 32;
    const float* bw_me = bwg + ((size_t)uh * N + qme) * 32;

    for (int kt0 = 0; kt0 < N; kt0 += 32) {
        int nk = min(32, N - kt0);
        __syncthreads();
        #pragma unroll
        for (int i = 0; i < 4; ++i) {
            int chunk = i * 64 + t;
            int key = chunk >> 3, cc = (chunk & 7) * 8;
            int kc = kt0 + key; if (kc >= N) kc = N - 1;
            const u16* kp = qkv + (tbase + kc) * 1152 + 384 + h * 64 + cc;
            uint4 kv = *(const uint4*)kp;
            uint4 vv = *(const uint4*)(kp + 384);
            unpack8(kv, &kt[key][cc]);
            unpack8(vv, &vt[key][cc]);
        }
        {
            int kh = kt0 / W, kw = kt0 - kh * W;
            #pragma unroll 4
            for (int kk = 0; kk < nk; ++kk) {
                bt[t][kk] = bh_me[kh] + bw_me[kw];
                if (++kw == W) { kw = 0; ++kh; }
            }
        }
        __syncthreads();
        #pragma unroll 2
        for (int kk = 0; kk < nk; ++kk) {
            const float* kr = &kt[kk][ch0];
            float s0 = 0.f, s1 = 0.f, s2 = 0.f, s3 = 0.f;
            #pragma unroll
            for (int c = 0; c < 16; ++c) {
                float kc_ = kr[c];
                s0 += qreg[0][c] * kc_;
                s1 += qreg[1][c] * kc_;
                s2 += qreg[2][c] * kc_;
                s3 += qreg[3][c] * kc_;
            }
            s0 += __shfl_xor(s0, 1); s0 += __shfl_xor(s0, 2);
            s1 += __shfl_xor(s1, 1); s1 += __shfl_xor(s1, 2);
            s2 += __shfl_xor(s2, 1); s2 += __shfl_xor(s2, 2);
            s3 += __shfl_xor(s3, 1); s3 += __shfl_xor(s3, 2);
            float p0 = __expf(s0 + bt[qq][kk]);
            float p1 = __expf(s1 + bt[qq + 16][kk]);
            float p2 = __expf(s2 + bt[qq + 32][kk]);
            float p3 = __expf(s3 + bt[qq + 48][kk]);
            l[0] += p0; l[1] += p1; l[2] += p2; l[3] += p3;
            const float* vr = &vt[kk][ch0];
            #pragma unroll
            for (int c = 0; c < 16; ++c) {
                float vc = vr[c];
                o[0][c] += p0 * vc;
                o[1][c] += p1 * vc;
                o[2][c] += p2 * vc;
                o[3][c] += p3 * vc;
            }
        }
    }
    #pragma unroll
    for (int j = 0; j < 4; ++j) {
        int q = qbase + qq + 16 * j;
        if (q < N) {
            float inv = 1.f / l[j];
            u16* op = outb + (tbase + q) * 384 + h * 64 + ch0;
            #pragma unroll
            for (int c = 0; c < 16; ++c) op[c] = f2bf(o[j][c] * inv);
        }
    }
}

// ---------------- final NHWC -> NCHW ----------------
__global__ __launch_bounds__(256) void out_transpose_kernel(const float* __restrict__ y,
                                                            float* __restrict__ out) {
    size_t idx = (size_t)blockIdx.x * 256 + threadIdx.x;   // 4*384*1024
    if (idx >= (size_t)B_SZ * 384 * 1024) return;
    int g = (int)(idx % 1024);
    int c = (int)((idx / 1024) % 384);
    int b = (int)(idx / (1024 * 384));
    out[idx] = y[((size_t)b * 1024 + g) * 384 + c];
}

// ---------------- host ----------------
static inline void launch_gemm(const u16* A, const u16* W, const float* bias,
                               const float* res, float* outf, u16* outb,
                               int M, int N, int K, int act, hipStream_t s) {
    dim3 g(N / 128, M / 128);
    mfma_gemm<<<g, 256, 0, s>>>(A, W, bias, res, outf, outb, M, N, K, act);
}

extern "C" void kernel_launch(void* const* d_in, const int* in_sizes, int n_in,
                              void* d_out, int out_size, void* d_ws, size_t ws_size,
                              hipStream_t stream) {
    const float* x      = (const float*)d_in[0];
    const float* patchw = (const float*)d_in[1];
    const float* patchb = (const float*)d_in[2];
    const float* pos    = (const float*)d_in[3];
    const float* n1w    = (const float*)d_in[4];
    const float* n1b    = (const float*)d_in[5];
    const float* qkvw   = (const float*)d_in[6];
    const float* qkvb   = (const float*)d_in[7];
    const float* pw     = (const float*)d_in[8];
    const float* pb     = (const float*)d_in[9];
    const float* n2w    = (const float*)d_in[10];
    const float* n2b    = (const float*)d_in[11];
    const float* f1w    = (const float*)d_in[12];
    const float* f1b    = (const float*)d_in[13];
    const float* f2w    = (const float*)d_in[14];
    const float* f2b    = (const float*)d_in[15];
    const float* rph    = (const float*)d_in[16];
    const float* rpw    = (const float*)d_in[17];
    float* out = (float*)d_out;

    // workspace layout (85.4 MB total)
    float* y   = (float*)d_ws;                  // 4096*384 f32
    u16* qkvx  = (u16*)(y + 1572864);           // 7168*1152 bf16
    u16* winb  = qkvx + 8257536;                // 7168*384 bf16
    u16* lnb   = winb + 2752512;                // 4096*384 bf16
    u16* attb  = lnb + 1572864;                 // 7168*384 bf16
    u16* unpb  = attb + 2752512;                // 4096*384 bf16
    u16* mlpb  = unpb + 1572864;                // 4096*1536 bf16
    u16* wb    = mlpb + 6291456;                // 10911744 bf16 weights
    float* bhg = (float*)(wb + 10911744);       // 1354752 f32
    float* bwg = bhg + 1354752;                 // 1354752 f32
    u16* colb  = qkvx;                          // overlay: 4096*768 bf16 (used pre-qkv)

    u16* wb_patch = wb;
    u16* wb_qkv   = wb + 294912;
    u16* wb_pw    = wb + 2949120;
    u16* wb_f1    = wb + 3833856;
    u16* wb_f2    = wb + 7372800;

    // weight conversion (every call; d_in restored each launch)
    w2b_kernel<<<(294912 + 255) / 256, 256, 0, stream>>>(patchw, wb_patch, 294912);
    w2b_kernel<<<(2654208 + 255) / 256, 256, 0, stream>>>(qkvw, wb_qkv, 2654208);
    w2b_kernel<<<(884736 + 255) / 256, 256, 0, stream>>>(pw, wb_pw, 884736);
    w2b_kernel<<<(3538944 + 255) / 256, 256, 0, stream>>>(f1w, wb_f1, 3538944);
    w2b_kernel<<<(3538944 + 255) / 256, 256, 0, stream>>>(f2w, wb_f2, 3538944);

    // patch embed
    {
        size_t tot = (size_t)NTOK * 768;
        im2col_kernel<<<(int)((tot + 255) / 256), 256, 0, stream>>>(x, colb);
        launch_gemm(colb, wb_patch, patchb, nullptr, y, nullptr, NTOK, 384, 768, 0, stream);
        add_pos_kernel<<<(1024 * 384 + 255) / 256, 256, 0, stream>>>(pos, y);
    }

    for (int i = 0; i < 6; ++i) {
        bool windowed = (i == 0 || i == 1 || i == 3 || i == 4);
        ln_kernel<<<NTOK, 64, 0, stream>>>(y, n1w + i * 384, n1b + i * 384, lnb);
        const float* rh = rph + (size_t)i * 63 * 64;
        const float* rw = rpw + (size_t)i * 63 * 64;
        if (windowed) {
            winpart_kernel<<<(MPAD * 384) / 256, 256, 0, stream>>>(lnb, winb);
            launch_gemm(winb, wb_qkv + (size_t)i * 442368, qkvb + i * 1152,
                        nullptr, nullptr, qkvx, MPAD, 1152, 384, 0, stream);
            relbias_kernel<<<NWIN * HEADS * WTOK, 64, 0, stream>>>(qkvx, rh, rw,
                                                                   bhg, bwg, WTOK, WS, WS);
            attn_flash<<<dim3(NWIN * HEADS, 4), 64, 0, stream>>>(qkvx, bhg, bwg, attb,
                                                                 WTOK, WS, WS);
            winunpart_kernel<<<(NTOK * 384) / 256, 256, 0, stream>>>(attb, unpb);
            launch_gemm(unpb, wb_pw + (size_t)i * 147456, pb + i * 384,
                        y, y, nullptr, NTOK, 384, 384, 0, stream);
        } else {
            launch_gemm(lnb, wb_qkv + (size_t)i * 442368, qkvb + i * 1152,
                        nullptr, nullptr, qkvx, NTOK, 1152, 384, 0, stream);
            relbias_kernel<<<B_SZ * HEADS * 1024, 64, 0, stream>>>(qkvx, rh, rw,
                                                                   bhg, bwg, 1024, 32, 32);
            attn_flash<<<dim3(B_SZ * HEADS, 16), 64, 0, stream>>>(qkvx, bhg, bwg, attb,
                                                                  1024, 32, 32);
            launch_gemm(attb, wb_pw + (size_t)i * 147456, pb + i * 384,
                        y, y, nullptr, NTOK, 384, 384, 0, stream);
        }
        ln_kernel<<<NTOK, 64, 0, stream>>>(y, n2w + i * 384, n2b + i * 384, lnb);
        launch_gemm(lnb, wb_f1 + (size_t)i * 589824, f1b + i * 1536,
                    nullptr, nullptr, mlpb, NTOK, 1536, 384, 1, stream);
        launch_gemm(mlpb, wb_f2 + (size_t)i * 589824, f2b + i * 384,
                    y, y, nullptr, NTOK, 384, 1536, 0, stream);
    }

    {
        size_t tot = (size_t)B_SZ * 384 * 1024;
        out_transpose_kernel<<<(int)((tot + 255) / 256), 256, 0, stream>>>(y, out);
    }
}

// Round 3
// 1474.114 us; speedup vs baseline: 6.5377x; 1.9536x over previous
//
#include <hip/hip_runtime.h>
#include <math.h>

// ---------------- constants ----------------
#define B_SZ 4
#define DIM 384
#define HEADS 6
#define HD 64
#define NTOK 4096          // B*32*32
#define WS 14
#define NWIN 36            // B * 9
#define WTOK 196           // 14*14
#define PWTOK 7056         // 36*196
#define MPAD 7168          // padded rows for windowed qkv GEMM (56*128)

typedef unsigned short u16;
typedef __bf16 bf16_t;
typedef bf16_t bf16x8 __attribute__((ext_vector_type(8)));
typedef float f32x4 __attribute__((ext_vector_type(4)));

__device__ __forceinline__ float bf2f(unsigned u) { return __uint_as_float(u << 16); }
__device__ __forceinline__ u16 f2bf(float f) {
    unsigned u = __float_as_uint(f);
    unsigned r = (u + 0x7fffu + ((u >> 16) & 1u)) >> 16;
    return (u16)r;
}

// async global->LDS, 16B per lane, wave-uniform LDS base + lane*16
__device__ __forceinline__ void ldsload16(const u16* g, u16* l) {
    __builtin_amdgcn_global_load_lds(
        (const __attribute__((address_space(1))) unsigned int*)g,
        (__attribute__((address_space(3))) unsigned int*)l, 16, 0, 0);
}

__device__ __forceinline__ int swz(int r) { return (r ^ (r >> 2)) & 3; }

// ---------------- fp32 -> bf16 convert ----------------
__global__ __launch_bounds__(256) void w2b_kernel(const float* __restrict__ s,
                                                  u16* __restrict__ d, int n) {
    int i = blockIdx.x * 256 + threadIdx.x;
    if (i < n) d[i] = f2bf(s[i]);
}

// ---------------- im2col (bf16 out) ----------------
__global__ __launch_bounds__(256) void im2col_kernel(const float* __restrict__ x,
                                                     u16* __restrict__ col) {
    size_t idx = (size_t)blockIdx.x * 256 + threadIdx.x;
    if (idx >= (size_t)NTOK * 768) return;
    int kk = (int)(idx % 768);
    int p  = (int)(idx / 768);
    int b  = p / 1024;
    int ph = (p % 1024) / 32;
    int pw = p % 32;
    int c = kk / 256;
    int r = kk % 256;
    int i = r / 16, j = r % 16;
    col[idx] = f2bf(x[(size_t)b * 3 * 512 * 512 + (size_t)c * 512 * 512 +
                      (size_t)(ph * 16 + i) * 512 + (pw * 16 + j)]);
}

// ---------------- bicubic pos embed ----------------
__device__ inline float cubic_keys(float x) {
    x = fabsf(x);
    if (x <= 1.f) return ((1.5f * x - 2.5f) * x) * x + 1.f;
    if (x < 2.f)  return ((-0.5f * x + 2.5f) * x - 4.f) * x + 2.f;
    return 0.f;
}

__global__ __launch_bounds__(256) void add_pos_kernel(const float* __restrict__ pe,
                                                      float* __restrict__ y) {
    int idx = blockIdx.x * 256 + threadIdx.x;   // 1024*384
    if (idx >= 1024 * 384) return;
    int c = idx % 384;
    int g = idx / 384;
    int gy = g / 32, gx = g % 32;
    float wy[14], wx[14];
    float sy = (gy + 0.5f) * (14.f / 32.f) - 0.5f;
    float sx = (gx + 0.5f) * (14.f / 32.f) - 0.5f;
    float toty = 0.f, totx = 0.f;
    #pragma unroll
    for (int k = 0; k < 14; ++k) {
        wy[k] = cubic_keys(sy - (float)k); toty += wy[k];
        wx[k] = cubic_keys(sx - (float)k); totx += wx[k];
    }
    float val = 0.f;
    #pragma unroll 1
    for (int iy = 0; iy < 14; ++iy) {
        if (wy[iy] == 0.f) continue;
        float row = 0.f;
        for (int ix = 0; ix < 14; ++ix) {
            if (wx[ix] == 0.f) continue;
            row += wx[ix] * pe[(iy * 14 + ix) * 384 + c];
        }
        val += wy[iy] * row;
    }
    val /= (toty * totx);
    #pragma unroll
    for (int b = 0; b < B_SZ; ++b)
        y[((size_t)(b * 1024 + g)) * 384 + c] += val;
}

// ---------------- layernorm: fp32 in, bf16 out ----------------
__global__ __launch_bounds__(64) void ln_kernel(const float* __restrict__ x,
                                                const float* __restrict__ w,
                                                const float* __restrict__ b,
                                                u16* __restrict__ out) {
    int tok = blockIdx.x;
    int t = threadIdx.x;
    const float* xr = x + (size_t)tok * 384;
    float v[6];
    float s = 0.f;
    #pragma unroll
    for (int i = 0; i < 6; ++i) { v[i] = xr[t + 64 * i]; s += v[i]; }
    #pragma unroll
    for (int off = 32; off > 0; off >>= 1) s += __shfl_xor(s, off);
    float mean = s * (1.f / 384.f);
    float vs = 0.f;
    #pragma unroll
    for (int i = 0; i < 6; ++i) { float d = v[i] - mean; vs += d * d; }
    #pragma unroll
    for (int off = 32; off > 0; off >>= 1) vs += __shfl_xor(vs, off);
    float inv = rsqrtf(vs * (1.f / 384.f) + 1e-5f);
    u16* orow = out + (size_t)tok * 384;
    #pragma unroll
    for (int i = 0; i < 6; ++i) {
        int c = t + 64 * i;
        orow[c] = f2bf((v[i] - mean) * inv * w[c] + b[c]);
    }
}

// ---------------- window partition / unpartition (bf16) ----------------
__global__ __launch_bounds__(256) void winpart_kernel(const u16* __restrict__ xn,
                                                      u16* __restrict__ win) {
    size_t idx = (size_t)blockIdx.x * 256 + threadIdx.x;   // MPAD*384
    if (idx >= (size_t)MPAD * 384) return;
    int c = (int)(idx % 384);
    int tk = (int)(idx / 384);
    if (tk >= PWTOK) { win[idx] = 0; return; }
    int wtok = tk % WTOK;
    int w = tk / WTOK;
    int b = w / 9;
    int wy = (w % 9) / 3, wx = w % 3;
    int iy = wtok / WS, ix = wtok % WS;
    int gy = wy * WS + iy, gx = wx * WS + ix;
    u16 val = 0;
    if (gy < 32 && gx < 32)
        val = xn[((size_t)(b * 1024 + gy * 32 + gx)) * 384 + c];
    win[idx] = val;
}

__global__ __launch_bounds__(256) void winunpart_kernel(const u16* __restrict__ aout,
                                                        u16* __restrict__ out) {
    size_t idx = (size_t)blockIdx.x * 256 + threadIdx.x;   // 4096*384
    if (idx >= (size_t)NTOK * 384) return;
    int c = (int)(idx % 384);
    int tk = (int)(idx / 384);
    int b = tk / 1024;
    int g = tk % 1024;
    int gy = g / 32, gx = g % 32;
    int wy = gy / WS, iy = gy % WS;
    int wx = gx / WS, ix = gx % WS;
    int w = b * 9 + wy * 3 + wx;
    out[idx] = aout[((size_t)(w * WTOK + iy * WS + ix)) * 384 + c];
}

// ---------------- MFMA bf16 GEMM (unchanged from R2) ----------------
__global__ __launch_bounds__(256) void mfma_gemm(
        const u16* __restrict__ A, const u16* __restrict__ Wt,
        const float* __restrict__ bias, const float* __restrict__ res,
        float* __restrict__ outf, u16* __restrict__ outb,
        int M, int N, int K, int act)
{
    __shared__ u16 As[4096];
    __shared__ u16 Bs[4096];
    int t = threadIdx.x;
    int lane = t & 63, wave = t >> 6;
    int wm = (wave >> 1) * 64, wn = (wave & 1) * 64;
    int m0 = blockIdx.y * 128, n0 = blockIdx.x * 128;

    int r0 = t >> 2,        c0 = ((t & 3) ^ swz(t >> 2)) * 8;
    int r1 = 64 + (t >> 2), c1 = ((t & 3) ^ swz(64 + (t >> 2))) * 8;
    const u16* a0 = A + (size_t)(m0 + r0) * K + c0;
    const u16* a1 = A + (size_t)(m0 + r1) * K + c1;
    const u16* b0 = Wt + (size_t)(n0 + r0) * K + c0;
    const u16* b1 = Wt + (size_t)(n0 + r1) * K + c1;
    u16* asd0 = &As[(wave * 64) * 8];
    u16* asd1 = &As[(256 + wave * 64) * 8];
    u16* bsd0 = &Bs[(wave * 64) * 8];
    u16* bsd1 = &Bs[(256 + wave * 64) * 8];

    f32x4 acc[4][4] = {};
    int row_a = wm + (lane & 15);
    int row_b = wn + (lane & 15);
    int lq = lane >> 4;

    for (int k0 = 0; k0 < K; k0 += 32) {
        ldsload16(a0 + k0, asd0);
        ldsload16(a1 + k0, asd1);
        ldsload16(b0 + k0, bsd0);
        ldsload16(b1 + k0, bsd1);
        __syncthreads();
        bf16x8 af[4], bfr[4];
        #pragma unroll
        for (int i = 0; i < 4; ++i) {
            int r = row_a + i * 16;
            af[i] = *(const bf16x8*)&As[r * 32 + ((lq ^ swz(r)) * 8)];
        }
        #pragma unroll
        for (int j = 0; j < 4; ++j) {
            int r = row_b + j * 16;
            bfr[j] = *(const bf16x8*)&Bs[r * 32 + ((lq ^ swz(r)) * 8)];
        }
        #pragma unroll
        for (int i = 0; i < 4; ++i)
            #pragma unroll
            for (int j = 0; j < 4; ++j)
                acc[i][j] = __builtin_amdgcn_mfma_f32_16x16x32_bf16(
                    af[i], bfr[j], acc[i][j], 0, 0, 0);
        __syncthreads();
    }

    int colq = lane & 15, rowq = (lane >> 4) * 4;
    #pragma unroll
    for (int i = 0; i < 4; ++i) {
        #pragma unroll
        for (int rr = 0; rr < 4; ++rr) {
            int m = m0 + wm + i * 16 + rowq + rr;
            size_t mo = (size_t)m * N;
            #pragma unroll
            for (int j = 0; j < 4; ++j) {
                int n = n0 + wn + j * 16 + colq;
                float v = acc[i][j][rr] + bias[n];
                if (res)  v += res[mo + n];
                if (act)  v = 0.5f * v * (1.f + erff(v * 0.70710678118654752f));
                if (outf) outf[mo + n] = v;
                if (outb) outb[mo + n] = f2bf(v);
            }
        }
    }
}

// ---------------- rel-pos bias precompute ----------------
__global__ __launch_bounds__(64) void relbias_kernel(const u16* __restrict__ qkv,
        const float* __restrict__ rh, const float* __restrict__ rw,
        float* __restrict__ bhg, float* __restrict__ bwg, int N, int H, int W)
{
    int t = threadIdx.x;
    int q = blockIdx.x % N, uh = blockIdx.x / N;
    int h = uh % HEADS, u = uh / HEADS;
    if (t >= H + W) return;
    const u16* qp = qkv + ((size_t)u * N + q) * 1152 + h * 64;
    int qh = q / W, qw = q - qh * W;
    const float* R = (t < H) ? rh + (size_t)(qh - t + H - 1) * 64
                             : rw + (size_t)(qw - (t - H) + W - 1) * 64;
    float s = 0.f;
    #pragma unroll
    for (int c = 0; c < 64; ++c) s += bf2f(qp[c]) * R[c];
    if (t < H) bhg[((size_t)uh * N + q) * 32 + t] = s;
    else       bwg[((size_t)uh * N + q) * 32 + (t - H)] = s;
}

// ---------------- MFMA flash attention (transposed products) ----------------
// grid (units*HEADS, ceil(N/64)), block 256 (4 waves, 16 q each).
// S^T = K . Q^T  (A = K from global_load_lds w/ chunk XOR swizzle, B = Q^T)
// O^T = V^T . P^T (A = V^T VALU-transposed in LDS, B = P stored [q][k])
template<int N, int W>
__global__ __launch_bounds__(256) void attn_mfma(const u16* __restrict__ qkv,
        const float* __restrict__ bhg, const float* __restrict__ bwg,
        u16* __restrict__ outb)
{
    __shared__ u16 Ks[2048];          // 32 keys x 64 ch, 16B-chunk XOR-swizzled
    __shared__ u16 Vt[64 * 40];       // [ch][key] stride 40 (80B, 16B-aligned)
    __shared__ u16 Pb[4][16 * 40];    // per-wave P [q][key] stride 40
    __shared__ float bhl[64][33];
    __shared__ float bwl[64][33];
    __shared__ u16 Qt[64 * 66];       // [ch][q] stride 66, pre-scaled

    int t = threadIdx.x, lane = t & 63, wave = t >> 6;
    int quad = lane >> 4, l15 = lane & 15;
    int uh = blockIdx.x, qb0 = blockIdx.y * 64;
    int h = uh % HEADS, u = uh / HEADS;
    size_t tbase = (size_t)u * N;

    // ---- stage Q^T (x 0.125, exact in bf16) ----
    {
        int q = t & 63, ch0 = (t >> 6) * 16;
        int qc = qb0 + q;
        int qcc = (qc < N) ? qc : (N - 1);
        const u16* qp = qkv + (tbase + qcc) * 1152 + h * 64 + ch0;
        uint4 a = *(const uint4*)qp;
        uint4 b = *(const uint4*)(qp + 8);
        u16 vals[16];
        *(uint4*)vals = a; *(uint4*)(vals + 8) = b;
        #pragma unroll
        for (int c = 0; c < 16; ++c) {
            float f = (qc < N) ? bf2f(vals[c]) * 0.125f : 0.f;
            Qt[(ch0 + c) * 66 + q] = f2bf(f);
        }
    }
    // ---- stage bias rows ----
    {
        int q = t >> 2, i0 = (t & 3) * 8;
        int qc = qb0 + q; if (qc >= N) qc = N - 1;
        const float* ph = bhg + ((size_t)uh * N + qc) * 32 + i0;
        const float* pw_ = bwg + ((size_t)uh * N + qc) * 32 + i0;
        #pragma unroll
        for (int c = 0; c < 8; ++c) { bhl[q][i0 + c] = ph[c]; bwl[q][i0 + c] = pw_[c]; }
    }
    __syncthreads();

    // Q^T B-frags (loop-invariant): B[k=ch][n=q], lane: ch=quad*8+j, q=wave*16+l15
    bf16x8 qf[2];
    #pragma unroll
    for (int hc = 0; hc < 2; ++hc) {
        u16* qv = (u16*)&qf[hc];
        #pragma unroll
        for (int j = 0; j < 8; ++j)
            qv[j] = Qt[(hc * 32 + quad * 8 + j) * 66 + wave * 16 + l15];
    }
    int qme = wave * 16 + l15;          // local q of this lane's S/O column
    float bwreg[2][4];
    if constexpr (W == 32) {
        #pragma unroll
        for (int kc2 = 0; kc2 < 2; ++kc2)
            #pragma unroll
            for (int r = 0; r < 4; ++r)
                bwreg[kc2][r] = bwl[qme][kc2 * 16 + quad * 4 + r];
    }

    f32x4 of[4] = {};
    float lsum = 0.f;
    constexpr int NKT = (N + 31) / 32;

    for (int kt = 0; kt < NKT; ++kt) {
        int kb = kt * 32;
        __syncthreads();   // previous tile fully consumed
        // K stage: wave covers LDS chunks [wave*64, wave*64+64)
        {
            int p = wave * 64 + lane;
            int key = p >> 3;
            int c8 = (p & 7) ^ (key & 7);
            int kc = kb + key; if (kc >= N) kc = N - 1;
            ldsload16(qkv + (tbase + kc) * 1152 + 384 + h * 64 + c8 * 8,
                      &Ks[wave * 512]);
        }
        // V stage transposed: thread: key=t&31, ch0=(t>>5)*8
        {
            int k = t & 31, ch0 = (t >> 5) * 8;
            int kc = kb + k; if (kc >= N) kc = N - 1;
            const u16* vp = qkv + (tbase + kc) * 1152 + 768 + h * 64 + ch0;
            uint4 vv = *(const uint4*)vp;
            u16 tmp[8]; *(uint4*)tmp = vv;
            #pragma unroll
            for (int c = 0; c < 8; ++c) Vt[(ch0 + c) * 40 + k] = tmp[c];
        }
        __syncthreads();   // drains global_load_lds (vmcnt) + LDS writes

        // QK: S^T[key][q], two 16-key chunks, K-dim 64 via 2 chained MFMAs
        f32x4 st[2] = {};
        #pragma unroll
        for (int hc = 0; hc < 2; ++hc) {
            #pragma unroll
            for (int kc2 = 0; kc2 < 2; ++kc2) {
                int key = kc2 * 16 + l15;
                int c8 = hc * 4 + quad;
                int p = key * 8 + (c8 ^ (key & 7));
                bf16x8 kf = *(const bf16x8*)&Ks[p * 8];
                st[kc2] = __builtin_amdgcn_mfma_f32_16x16x32_bf16(
                    kf, qf[hc], st[kc2], 0, 0, 0);
            }
        }
        // bias + exp + mask -> P (bf16, [q][key]), accumulate l
        float bh_t = 0.f;
        if constexpr (W == 32) bh_t = bhl[qme][kb >> 5];
        #pragma unroll
        for (int kc2 = 0; kc2 < 2; ++kc2) {
            #pragma unroll
            for (int r = 0; r < 4; ++r) {
                int keyl = kc2 * 16 + quad * 4 + r;
                int key = kb + keyl;
                float b;
                if constexpr (W == 32) {
                    b = bh_t + bwreg[kc2][r];
                } else {
                    int kk2 = (key < N) ? key : (N - 1);
                    int kh = kk2 / W, kw = kk2 - kh * W;
                    b = bhl[qme][kh] + bwl[qme][kw];
                }
                float p = __expf(st[kc2][r] + b);
                if (key >= N) p = 0.f;
                lsum += p;
                Pb[wave][l15 * 40 + keyl] = f2bf(p);
            }
        }
        // PV: O^T += V^T . P^T   (P is per-wave; no barrier needed)
        bf16x8 pf = *(const bf16x8*)&Pb[wave][l15 * 40 + quad * 8];
        #pragma unroll
        for (int ca = 0; ca < 4; ++ca) {
            bf16x8 vf = *(const bf16x8*)&Vt[(ca * 16 + l15) * 40 + quad * 8];
            of[ca] = __builtin_amdgcn_mfma_f32_16x16x32_bf16(
                vf, pf, of[ca], 0, 0, 0);
        }
    }

    // l: sum over key-rows = sum over quads at fixed q-col
    lsum += __shfl_xor(lsum, 16);
    lsum += __shfl_xor(lsum, 32);
    float inv = 1.f / lsum;
    int q = qb0 + qme;
    if (q < N) {
        u16* op = outb + (tbase + q) * 384 + h * 64;
        #pragma unroll
        for (int ca = 0; ca < 4; ++ca)
            #pragma unroll
            for (int r = 0; r < 4; ++r)
                op[ca * 16 + quad * 4 + r] = f2bf(of[ca][r] * inv);
    }
}

// ---------------- final NHWC -> NCHW ----------------
__global__ __launch_bounds__(256) void out_transpose_kernel(const float* __restrict__ y,
                                                            float* __restrict__ out) {
    size_t idx = (size_t)blockIdx.x * 256 + threadIdx.x;   // 4*384*1024
    if (idx >= (size_t)B_SZ * 384 * 1024) return;
    int g = (int)(idx % 1024);
    int c = (int)((idx / 1024) % 384);
    int b = (int)(idx / (1024 * 384));
    out[idx] = y[((size_t)b * 1024 + g) * 384 + c];
}

// ---------------- host ----------------
static inline void launch_gemm(const u16* A, const u16* W, const float* bias,
                               const float* res, float* outf, u16* outb,
                               int M, int N, int K, int act, hipStream_t s) {
    dim3 g(N / 128, M / 128);
    mfma_gemm<<<g, 256, 0, s>>>(A, W, bias, res, outf, outb, M, N, K, act);
}

extern "C" void kernel_launch(void* const* d_in, const int* in_sizes, int n_in,
                              void* d_out, int out_size, void* d_ws, size_t ws_size,
                              hipStream_t stream) {
    const float* x      = (const float*)d_in[0];
    const float* patchw = (const float*)d_in[1];
    const float* patchb = (const float*)d_in[2];
    const float* pos    = (const float*)d_in[3];
    const float* n1w    = (const float*)d_in[4];
    const float* n1b    = (const float*)d_in[5];
    const float* qkvw   = (const float*)d_in[6];
    const float* qkvb   = (const float*)d_in[7];
    const float* pw     = (const float*)d_in[8];
    const float* pb     = (const float*)d_in[9];
    const float* n2w    = (const float*)d_in[10];
    const float* n2b    = (const float*)d_in[11];
    const float* f1w    = (const float*)d_in[12];
    const float* f1b    = (const float*)d_in[13];
    const float* f2w    = (const float*)d_in[14];
    const float* f2b    = (const float*)d_in[15];
    const float* rph    = (const float*)d_in[16];
    const float* rpw    = (const float*)d_in[17];
    float* out = (float*)d_out;

    float* y   = (float*)d_ws;                  // 4096*384 f32
    u16* qkvx  = (u16*)(y + 1572864);           // 7168*1152 bf16
    u16* winb  = qkvx + 8257536;                // 7168*384 bf16
    u16* lnb   = winb + 2752512;                // 4096*384 bf16
    u16* attb  = lnb + 1572864;                 // 7168*384 bf16
    u16* unpb  = attb + 2752512;                // 4096*384 bf16
    u16* mlpb  = unpb + 1572864;                // 4096*1536 bf16
    u16* wb    = mlpb + 6291456;                // 10911744 bf16 weights
    float* bhg = (float*)(wb + 10911744);       // 1354752 f32
    float* bwg = bhg + 1354752;                 // 1354752 f32
    u16* colb  = qkvx;                          // overlay: im2col buffer

    u16* wb_patch = wb;
    u16* wb_qkv   = wb + 294912;
    u16* wb_pw    = wb + 2949120;
    u16* wb_f1    = wb + 3833856;
    u16* wb_f2    = wb + 7372800;

    w2b_kernel<<<(294912 + 255) / 256, 256, 0, stream>>>(patchw, wb_patch, 294912);
    w2b_kernel<<<(2654208 + 255) / 256, 256, 0, stream>>>(qkvw, wb_qkv, 2654208);
    w2b_kernel<<<(884736 + 255) / 256, 256, 0, stream>>>(pw, wb_pw, 884736);
    w2b_kernel<<<(3538944 + 255) / 256, 256, 0, stream>>>(f1w, wb_f1, 3538944);
    w2b_kernel<<<(3538944 + 255) / 256, 256, 0, stream>>>(f2w, wb_f2, 3538944);

    {
        size_t tot = (size_t)NTOK * 768;
        im2col_kernel<<<(int)((tot + 255) / 256), 256, 0, stream>>>(x, colb);
        launch_gemm(colb, wb_patch, patchb, nullptr, y, nullptr, NTOK, 384, 768, 0, stream);
        add_pos_kernel<<<(1024 * 384 + 255) / 256, 256, 0, stream>>>(pos, y);
    }

    for (int i = 0; i < 6; ++i) {
        bool windowed = (i == 0 || i == 1 || i == 3 || i == 4);
        ln_kernel<<<NTOK, 64, 0, stream>>>(y, n1w + i * 384, n1b + i * 384, lnb);
        const float* rh = rph + (size_t)i * 63 * 64;
        const float* rw = rpw + (size_t)i * 63 * 64;
        if (windowed) {
            winpart_kernel<<<(MPAD * 384) / 256, 256, 0, stream>>>(lnb, winb);
            launch_gemm(winb, wb_qkv + (size_t)i * 442368, qkvb + i * 1152,
                        nullptr, nullptr, qkvx, MPAD, 1152, 384, 0, stream);
            relbias_kernel<<<NWIN * HEADS * WTOK, 64, 0, stream>>>(qkvx, rh, rw,
                                                                   bhg, bwg, WTOK, WS, WS);
            attn_mfma<WTOK, WS><<<dim3(NWIN * HEADS, 4), 256, 0, stream>>>(
                qkvx, bhg, bwg, attb);
            winunpart_kernel<<<(NTOK * 384) / 256, 256, 0, stream>>>(attb, unpb);
            launch_gemm(unpb, wb_pw + (size_t)i * 147456, pb + i * 384,
                        y, y, nullptr, NTOK, 384, 384, 0, stream);
        } else {
            launch_gemm(lnb, wb_qkv + (size_t)i * 442368, qkvb + i * 1152,
                        nullptr, nullptr, qkvx, NTOK, 1152, 384, 0, stream);
            relbias_kernel<<<B_SZ * HEADS * 1024, 64, 0, stream>>>(qkvx, rh, rw,
                                                                   bhg, bwg, 1024, 32, 32);
            attn_mfma<1024, 32><<<dim3(B_SZ * HEADS, 16), 256, 0, stream>>>(
                qkvx, bhg, bwg, attb);
            launch_gemm(attb, wb_pw + (size_t)i * 147456, pb + i * 384,
                        y, y, nullptr, NTOK, 384, 384, 0, stream);
        }
        ln_kernel<<<NTOK, 64, 0, stream>>>(y, n2w + i * 384, n2b + i * 384, lnb);
        launch_gemm(lnb, wb_f1 + (size_t)i * 589824, f1b + i * 1536,
                    nullptr, nullptr, mlpb, NTOK, 1536, 384, 1, stream);
        launch_gemm(mlpb, wb_f2 + (size_t)i * 589824, f2b + i * 384,
                    y, y, nullptr, NTOK, 384, 1536, 0, stream);
    }

    {
        size_t tot = (size_t)B_SZ * 384 * 1024;
        out_transpose_kernel<<<(int)((tot + 255) / 256), 256, 0, stream>>>(y, out);
    }
}

// Round 4
// 1230.904 us; speedup vs baseline: 7.8294x; 1.1976x over previous
//
#include <hip/hip_runtime.h>
#include <math.h>

// ---------------- constants ----------------
#define B_SZ 4
#define DIM 384
#define HEADS 6
#define HD 64
#define NTOK 4096          // B*32*32
#define WS 14
#define NWIN 36            // B * 9
#define WTOK 196           // 14*14
#define PWTOK 7056         // 36*196
#define MPAD 7168          // padded rows for windowed qkv GEMM (56*128)

typedef unsigned short u16;
typedef __bf16 bf16_t;
typedef bf16_t bf16x8 __attribute__((ext_vector_type(8)));
typedef float f32x4 __attribute__((ext_vector_type(4)));

__device__ __forceinline__ float bf2f(unsigned u) { return __uint_as_float(u << 16); }
__device__ __forceinline__ u16 f2bf(float f) {
    unsigned u = __float_as_uint(f);
    unsigned r = (u + 0x7fffu + ((u >> 16) & 1u)) >> 16;
    return (u16)r;
}

// async global->LDS, 16B per lane, wave-uniform LDS base + lane*16
__device__ __forceinline__ void ldsload16(const u16* g, u16* l) {
    __builtin_amdgcn_global_load_lds(
        (const __attribute__((address_space(1))) unsigned int*)g,
        (__attribute__((address_space(3))) unsigned int*)l, 16, 0, 0);
}

__device__ __forceinline__ int swz(int r) { return (r ^ (r >> 2)) & 3; }

// ---------------- fp32 -> bf16 convert ----------------
__global__ __launch_bounds__(256) void w2b_kernel(const float* __restrict__ s,
                                                  u16* __restrict__ d, int n) {
    int i = blockIdx.x * 256 + threadIdx.x;
    if (i < n) d[i] = f2bf(s[i]);
}

// ---------------- im2col (bf16 out) ----------------
__global__ __launch_bounds__(256) void im2col_kernel(const float* __restrict__ x,
                                                     u16* __restrict__ col) {
    size_t idx = (size_t)blockIdx.x * 256 + threadIdx.x;
    if (idx >= (size_t)NTOK * 768) return;
    int kk = (int)(idx % 768);
    int p  = (int)(idx / 768);
    int b  = p / 1024;
    int ph = (p % 1024) / 32;
    int pw = p % 32;
    int c = kk / 256;
    int r = kk % 256;
    int i = r / 16, j = r % 16;
    col[idx] = f2bf(x[(size_t)b * 3 * 512 * 512 + (size_t)c * 512 * 512 +
                      (size_t)(ph * 16 + i) * 512 + (pw * 16 + j)]);
}

// ---------------- bicubic pos embed ----------------
__device__ inline float cubic_keys(float x) {
    x = fabsf(x);
    if (x <= 1.f) return ((1.5f * x - 2.5f) * x) * x + 1.f;
    if (x < 2.f)  return ((-0.5f * x + 2.5f) * x - 4.f) * x + 2.f;
    return 0.f;
}

__global__ __launch_bounds__(256) void add_pos_kernel(const float* __restrict__ pe,
                                                      float* __restrict__ y) {
    int idx = blockIdx.x * 256 + threadIdx.x;   // 1024*384
    if (idx >= 1024 * 384) return;
    int c = idx % 384;
    int g = idx / 384;
    int gy = g / 32, gx = g % 32;
    float wy[14], wx[14];
    float sy = (gy + 0.5f) * (14.f / 32.f) - 0.5f;
    float sx = (gx + 0.5f) * (14.f / 32.f) - 0.5f;
    float toty = 0.f, totx = 0.f;
    #pragma unroll
    for (int k = 0; k < 14; ++k) {
        wy[k] = cubic_keys(sy - (float)k); toty += wy[k];
        wx[k] = cubic_keys(sx - (float)k); totx += wx[k];
    }
    float val = 0.f;
    #pragma unroll 1
    for (int iy = 0; iy < 14; ++iy) {
        if (wy[iy] == 0.f) continue;
        float row = 0.f;
        for (int ix = 0; ix < 14; ++ix) {
            if (wx[ix] == 0.f) continue;
            row += wx[ix] * pe[(iy * 14 + ix) * 384 + c];
        }
        val += wy[iy] * row;
    }
    val /= (toty * totx);
    #pragma unroll
    for (int b = 0; b < B_SZ; ++b)
        y[((size_t)(b * 1024 + g)) * 384 + c] += val;
}

// ---------------- layernorm: fp32 in, bf16 out ----------------
__global__ __launch_bounds__(64) void ln_kernel(const float* __restrict__ x,
                                                const float* __restrict__ w,
                                                const float* __restrict__ b,
                                                u16* __restrict__ out) {
    int tok = blockIdx.x;
    int t = threadIdx.x;
    const float* xr = x + (size_t)tok * 384;
    float v[6];
    float s = 0.f;
    #pragma unroll
    for (int i = 0; i < 6; ++i) { v[i] = xr[t + 64 * i]; s += v[i]; }
    #pragma unroll
    for (int off = 32; off > 0; off >>= 1) s += __shfl_xor(s, off);
    float mean = s * (1.f / 384.f);
    float vs = 0.f;
    #pragma unroll
    for (int i = 0; i < 6; ++i) { float d = v[i] - mean; vs += d * d; }
    #pragma unroll
    for (int off = 32; off > 0; off >>= 1) vs += __shfl_xor(vs, off);
    float inv = rsqrtf(vs * (1.f / 384.f) + 1e-5f);
    u16* orow = out + (size_t)tok * 384;
    #pragma unroll
    for (int i = 0; i < 6; ++i) {
        int c = t + 64 * i;
        orow[c] = f2bf((v[i] - mean) * inv * w[c] + b[c]);
    }
}

// ---------------- window partition / unpartition (bf16) ----------------
__global__ __launch_bounds__(256) void winpart_kernel(const u16* __restrict__ xn,
                                                      u16* __restrict__ win) {
    size_t idx = (size_t)blockIdx.x * 256 + threadIdx.x;   // MPAD*384
    if (idx >= (size_t)MPAD * 384) return;
    int c = (int)(idx % 384);
    int tk = (int)(idx / 384);
    if (tk >= PWTOK) { win[idx] = 0; return; }
    int wtok = tk % WTOK;
    int w = tk / WTOK;
    int b = w / 9;
    int wy = (w % 9) / 3, wx = w % 3;
    int iy = wtok / WS, ix = wtok % WS;
    int gy = wy * WS + iy, gx = wx * WS + ix;
    u16 val = 0;
    if (gy < 32 && gx < 32)
        val = xn[((size_t)(b * 1024 + gy * 32 + gx)) * 384 + c];
    win[idx] = val;
}

__global__ __launch_bounds__(256) void winunpart_kernel(const u16* __restrict__ aout,
                                                        u16* __restrict__ out) {
    size_t idx = (size_t)blockIdx.x * 256 + threadIdx.x;   // 4096*384
    if (idx >= (size_t)NTOK * 384) return;
    int c = (int)(idx % 384);
    int tk = (int)(idx / 384);
    int b = tk / 1024;
    int g = tk % 1024;
    int gy = g / 32, gx = g % 32;
    int wy = gy / WS, iy = gy % WS;
    int wx = gx / WS, ix = gx % WS;
    int w = b * 9 + wy * 3 + wx;
    out[idx] = aout[((size_t)(w * WTOK + iy * WS + ix)) * 384 + c];
}

// ---------------- MFMA bf16 GEMM ----------------
__global__ __launch_bounds__(256) void mfma_gemm(
        const u16* __restrict__ A, const u16* __restrict__ Wt,
        const float* __restrict__ bias, const float* __restrict__ res,
        float* __restrict__ outf, u16* __restrict__ outb,
        int M, int N, int K, int act)
{
    __shared__ u16 As[4096];
    __shared__ u16 Bs[4096];
    int t = threadIdx.x;
    int lane = t & 63, wave = t >> 6;
    int wm = (wave >> 1) * 64, wn = (wave & 1) * 64;
    int m0 = blockIdx.y * 128, n0 = blockIdx.x * 128;

    int r0 = t >> 2,        c0 = ((t & 3) ^ swz(t >> 2)) * 8;
    int r1 = 64 + (t >> 2), c1 = ((t & 3) ^ swz(64 + (t >> 2))) * 8;
    const u16* a0 = A + (size_t)(m0 + r0) * K + c0;
    const u16* a1 = A + (size_t)(m0 + r1) * K + c1;
    const u16* b0 = Wt + (size_t)(n0 + r0) * K + c0;
    const u16* b1 = Wt + (size_t)(n0 + r1) * K + c1;
    u16* asd0 = &As[(wave * 64) * 8];
    u16* asd1 = &As[(256 + wave * 64) * 8];
    u16* bsd0 = &Bs[(wave * 64) * 8];
    u16* bsd1 = &Bs[(256 + wave * 64) * 8];

    f32x4 acc[4][4] = {};
    int row_a = wm + (lane & 15);
    int row_b = wn + (lane & 15);
    int lq = lane >> 4;

    for (int k0 = 0; k0 < K; k0 += 32) {
        ldsload16(a0 + k0, asd0);
        ldsload16(a1 + k0, asd1);
        ldsload16(b0 + k0, bsd0);
        ldsload16(b1 + k0, bsd1);
        __syncthreads();
        bf16x8 af[4], bfr[4];
        #pragma unroll
        for (int i = 0; i < 4; ++i) {
            int r = row_a + i * 16;
            af[i] = *(const bf16x8*)&As[r * 32 + ((lq ^ swz(r)) * 8)];
        }
        #pragma unroll
        for (int j = 0; j < 4; ++j) {
            int r = row_b + j * 16;
            bfr[j] = *(const bf16x8*)&Bs[r * 32 + ((lq ^ swz(r)) * 8)];
        }
        #pragma unroll
        for (int i = 0; i < 4; ++i)
            #pragma unroll
            for (int j = 0; j < 4; ++j)
                acc[i][j] = __builtin_amdgcn_mfma_f32_16x16x32_bf16(
                    af[i], bfr[j], acc[i][j], 0, 0, 0);
        __syncthreads();
    }

    int colq = lane & 15, rowq = (lane >> 4) * 4;
    #pragma unroll
    for (int i = 0; i < 4; ++i) {
        #pragma unroll
        for (int rr = 0; rr < 4; ++rr) {
            int m = m0 + wm + i * 16 + rowq + rr;
            size_t mo = (size_t)m * N;
            #pragma unroll
            for (int j = 0; j < 4; ++j) {
                int n = n0 + wn + j * 16 + colq;
                float v = acc[i][j][rr] + bias[n];
                if (res)  v += res[mo + n];
                if (act)  v = 0.5f * v * (1.f + erff(v * 0.70710678118654752f));
                if (outf) outf[mo + n] = v;
                if (outb) outb[mo + n] = f2bf(v);
            }
        }
    }
}

// ---------------- rel-pos bias: batched MFMA GEMM ----------------
// D[uh][q][j] = sum_c q[uh][q][c] * Rtab[j][c]  for both tables (h,w), bf16 out.
// grid (uh_count, qtiles), block 256. JS = padded table length (32 or 64).
template<int JS>
__global__ __launch_bounds__(256) void relbias_mfma(const u16* __restrict__ qkv,
        const float* __restrict__ rh, const float* __restrict__ rw,
        u16* __restrict__ Dh, u16* __restrict__ Dw,
        int N, int L, int qstride)
{
    constexpr int DS = 2 * JS + 8;
    __shared__ u16 Qt[64 * 66];        // [c][q]
    __shared__ u16 Rt[2][JS * 72];     // [table][j][c]
    __shared__ u16 Dl[64 * DS];        // [q][table*JS + j]
    int t = threadIdx.x, lane = t & 63, wave = t >> 6;
    int quad = lane >> 4, l15 = lane & 15;
    int uh = blockIdx.x, qb0 = blockIdx.y * 64;
    int h = uh % HEADS, u = uh / HEADS;
    size_t tbase = (size_t)u * N;

    // stage Q^T (unscaled)
    {
        int q = t & 63, ch0 = (t >> 6) * 16;
        int qc = qb0 + q; if (qc >= N) qc = N - 1;
        const u16* qp = qkv + (tbase + qc) * 1152 + h * 64 + ch0;
        uint4 a = *(const uint4*)qp;
        uint4 b = *(const uint4*)(qp + 8);
        u16 vals[16];
        *(uint4*)vals = a; *(uint4*)(vals + 8) = b;
        #pragma unroll
        for (int c = 0; c < 16; ++c)
            Qt[(ch0 + c) * 66 + q] = vals[c];
    }
    // stage R tables (bf16), rows >= L zeroed
    for (int idx = t; idx < 2 * JS * 8; idx += 256) {
        int table = idx >= JS * 8;
        int rem = idx - table * JS * 8;
        int j = rem >> 3, cc0 = (rem & 7) * 8;
        const float* src = (table ? rw : rh) + (size_t)j * 64 + cc0;
        u16 tmp[8];
        #pragma unroll
        for (int c = 0; c < 8; ++c) tmp[c] = (j < L) ? f2bf(src[c]) : (u16)0;
        *(uint4*)&Rt[table][j * 72 + cc0] = *(uint4*)tmp;
    }
    __syncthreads();

    constexpr int NMT = 2 * (JS / 16);
    for (int mt = wave; mt < NMT; mt += 4) {
        int table = mt / (JS / 16), jt = mt % (JS / 16);
        bf16x8 af0 = *(const bf16x8*)&Rt[table][(jt * 16 + l15) * 72 + quad * 8];
        bf16x8 af1 = *(const bf16x8*)&Rt[table][(jt * 16 + l15) * 72 + 32 + quad * 8];
        #pragma unroll
        for (int qt = 0; qt < 4; ++qt) {
            bf16x8 qf0, qf1;
            u16* p0 = (u16*)&qf0; u16* p1 = (u16*)&qf1;
            #pragma unroll
            for (int z = 0; z < 8; ++z) {
                p0[z] = Qt[(quad * 8 + z) * 66 + qt * 16 + l15];
                p1[z] = Qt[(32 + quad * 8 + z) * 66 + qt * 16 + l15];
            }
            f32x4 acc = {};
            acc = __builtin_amdgcn_mfma_f32_16x16x32_bf16(af0, qf0, acc, 0, 0, 0);
            acc = __builtin_amdgcn_mfma_f32_16x16x32_bf16(af1, qf1, acc, 0, 0, 0);
            #pragma unroll
            for (int r = 0; r < 4; ++r)
                Dl[(qt * 16 + l15) * DS + table * JS + jt * 16 + quad * 4 + r] =
                    f2bf(acc[r]);
        }
    }
    __syncthreads();

    constexpr int CHUNKS = 64 * (2 * JS) / 8;
    for (int ci = t; ci < CHUNKS; ci += 256) {
        int q = ci / (2 * JS / 8);
        int rem = ci % (2 * JS / 8);
        int table = rem >= (JS / 8);
        int j0 = (rem - table * (JS / 8)) * 8;
        uint4 v = *(const uint4*)&Dl[q * DS + table * JS + j0];
        u16* dst = (table ? Dw : Dh) + ((size_t)uh * qstride + qb0 + q) * JS + j0;
        *(uint4*)dst = v;
    }
}

// ---------------- MFMA flash attention (transposed products) ----------------
template<int N, int W>
__global__ __launch_bounds__(256) void attn_mfma(const u16* __restrict__ qkv,
        const u16* __restrict__ Dh, const u16* __restrict__ Dw,
        u16* __restrict__ outb)
{
    constexpr int JS = (W == 32) ? 64 : 32;
    constexpr int QSTRIDE = (W == 32) ? 1024 : 256;
    constexpr int CTR = W - 1;
    __shared__ u16 Ks[2048];          // 32 keys x 64 ch, 16B-chunk XOR-swizzled
    __shared__ u16 Vt[64 * 40];       // [ch][key]
    __shared__ u16 Pb[4][16 * 40];    // per-wave P [q][key]
    __shared__ u16 bhl[64 * 66];      // D rows bf16 [q][j]
    __shared__ u16 bwl[64 * 66];
    __shared__ u16 Qt[64 * 66];       // [ch][q], pre-scaled

    int t = threadIdx.x, lane = t & 63, wave = t >> 6;
    int quad = lane >> 4, l15 = lane & 15;
    int uh = blockIdx.x, qb0 = blockIdx.y * 64;
    int h = uh % HEADS, u = uh / HEADS;
    size_t tbase = (size_t)u * N;

    // ---- stage Q^T (x 0.125, exact in bf16) ----
    {
        int q = t & 63, ch0 = (t >> 6) * 16;
        int qc = qb0 + q;
        int qcc = (qc < N) ? qc : (N - 1);
        const u16* qp = qkv + (tbase + qcc) * 1152 + h * 64 + ch0;
        uint4 a = *(const uint4*)qp;
        uint4 b = *(const uint4*)(qp + 8);
        u16 vals[16];
        *(uint4*)vals = a; *(uint4*)(vals + 8) = b;
        #pragma unroll
        for (int c = 0; c < 16; ++c) {
            float f = (qc < N) ? bf2f(vals[c]) * 0.125f : 0.f;
            Qt[(ch0 + c) * 66 + q] = f2bf(f);
        }
    }
    // ---- stage D bias rows (bf16) ----
    {
        int q = t & 63, rep = t >> 6;
        int qc = qb0 + q; if (qc >= N) qc = N - 1;
        const u16* ph  = Dh + ((size_t)uh * QSTRIDE + qc) * JS;
        const u16* pw_ = Dw + ((size_t)uh * QSTRIDE + qc) * JS;
        #pragma unroll
        for (int g2 = 0; g2 < JS / 32; ++g2) {
            int j0 = rep * (JS / 4) + g2 * 8;
            uint4 a = *(const uint4*)(ph + j0);
            uint4 b = *(const uint4*)(pw_ + j0);
            u16 ta[8], tb[8];
            *(uint4*)ta = a; *(uint4*)tb = b;
            #pragma unroll
            for (int c = 0; c < 8; ++c) {
                bhl[q * 66 + j0 + c] = ta[c];
                bwl[q * 66 + j0 + c] = tb[c];
            }
        }
    }
    __syncthreads();

    // Q^T B-frags (loop-invariant)
    bf16x8 qf[2];
    #pragma unroll
    for (int hc = 0; hc < 2; ++hc) {
        u16* qv = (u16*)&qf[hc];
        #pragma unroll
        for (int j = 0; j < 8; ++j)
            qv[j] = Qt[(hc * 32 + quad * 8 + j) * 66 + wave * 16 + l15];
    }
    int qme = wave * 16 + l15;
    int qq = qb0 + qme; if (qq >= N) qq = N - 1;
    int qh = qq / W, qw = qq - qh * W;
    float bwreg[2][4];
    if constexpr (W == 32) {
        #pragma unroll
        for (int kc2 = 0; kc2 < 2; ++kc2)
            #pragma unroll
            for (int r = 0; r < 4; ++r) {
                int keyl = kc2 * 16 + quad * 4 + r;
                bwreg[kc2][r] = bf2f(bwl[qme * 66 + (qw - keyl + CTR)]);
            }
    }

    f32x4 of[4] = {};
    float lsum = 0.f;
    constexpr int NKT = (N + 31) / 32;

    for (int kt = 0; kt < NKT; ++kt) {
        int kb = kt * 32;
        __syncthreads();
        // K stage
        {
            int p = wave * 64 + lane;
            int key = p >> 3;
            int c8 = (p & 7) ^ (key & 7);
            int kc = kb + key; if (kc >= N) kc = N - 1;
            ldsload16(qkv + (tbase + kc) * 1152 + 384 + h * 64 + c8 * 8,
                      &Ks[wave * 512]);
        }
        // V stage transposed
        {
            int k = t & 31, ch0 = (t >> 5) * 8;
            int kc = kb + k; if (kc >= N) kc = N - 1;
            const u16* vp = qkv + (tbase + kc) * 1152 + 768 + h * 64 + ch0;
            uint4 vv = *(const uint4*)vp;
            u16 tmp[8]; *(uint4*)tmp = vv;
            #pragma unroll
            for (int c = 0; c < 8; ++c) Vt[(ch0 + c) * 40 + k] = tmp[c];
        }
        __syncthreads();

        // QK: S^T[key][q]
        f32x4 st[2] = {};
        #pragma unroll
        for (int hc = 0; hc < 2; ++hc) {
            #pragma unroll
            for (int kc2 = 0; kc2 < 2; ++kc2) {
                int key = kc2 * 16 + l15;
                int c8 = hc * 4 + quad;
                int p = key * 8 + (c8 ^ (key & 7));
                bf16x8 kf = *(const bf16x8*)&Ks[p * 8];
                st[kc2] = __builtin_amdgcn_mfma_f32_16x16x32_bf16(
                    kf, qf[hc], st[kc2], 0, 0, 0);
            }
        }
        // bias + exp -> P
        float bh_t = 0.f;
        if constexpr (W == 32) bh_t = bf2f(bhl[qme * 66 + (qh - (kb >> 5) + CTR)]);
        #pragma unroll
        for (int kc2 = 0; kc2 < 2; ++kc2) {
            #pragma unroll
            for (int r = 0; r < 4; ++r) {
                int keyl = kc2 * 16 + quad * 4 + r;
                int key = kb + keyl;
                float b;
                if constexpr (W == 32) {
                    b = bh_t + bwreg[kc2][r];
                } else {
                    int kk2 = (key < N) ? key : (N - 1);
                    int kh = kk2 / W, kw = kk2 - kh * W;
                    b = bf2f(bhl[qme * 66 + (qh - kh + CTR)]) +
                        bf2f(bwl[qme * 66 + (qw - kw + CTR)]);
                }
                float p = __expf(st[kc2][r] + b);
                if (key >= N) p = 0.f;
                lsum += p;
                Pb[wave][l15 * 40 + keyl] = f2bf(p);
            }
        }
        // PV: O^T += V^T . P^T
        bf16x8 pf = *(const bf16x8*)&Pb[wave][l15 * 40 + quad * 8];
        #pragma unroll
        for (int ca = 0; ca < 4; ++ca) {
            bf16x8 vf = *(const bf16x8*)&Vt[(ca * 16 + l15) * 40 + quad * 8];
            of[ca] = __builtin_amdgcn_mfma_f32_16x16x32_bf16(
                vf, pf, of[ca], 0, 0, 0);
        }
    }

    lsum += __shfl_xor(lsum, 16);
    lsum += __shfl_xor(lsum, 32);
    float inv = 1.f / lsum;
    int q = qb0 + qme;
    if (q < N) {
        u16* op = outb + (tbase + q) * 384 + h * 64;
        #pragma unroll
        for (int ca = 0; ca < 4; ++ca)
            #pragma unroll
            for (int r = 0; r < 4; ++r)
                op[ca * 16 + quad * 4 + r] = f2bf(of[ca][r] * inv);
    }
}

// ---------------- final NHWC -> NCHW ----------------
__global__ __launch_bounds__(256) void out_transpose_kernel(const float* __restrict__ y,
                                                            float* __restrict__ out) {
    size_t idx = (size_t)blockIdx.x * 256 + threadIdx.x;   // 4*384*1024
    if (idx >= (size_t)B_SZ * 384 * 1024) return;
    int g = (int)(idx % 1024);
    int c = (int)((idx / 1024) % 384);
    int b = (int)(idx / (1024 * 384));
    out[idx] = y[((size_t)b * 1024 + g) * 384 + c];
}

// ---------------- host ----------------
static inline void launch_gemm(const u16* A, const u16* W, const float* bias,
                               const float* res, float* outf, u16* outb,
                               int M, int N, int K, int act, hipStream_t s) {
    dim3 g(N / 128, M / 128);
    mfma_gemm<<<g, 256, 0, s>>>(A, W, bias, res, outf, outb, M, N, K, act);
}

extern "C" void kernel_launch(void* const* d_in, const int* in_sizes, int n_in,
                              void* d_out, int out_size, void* d_ws, size_t ws_size,
                              hipStream_t stream) {
    const float* x      = (const float*)d_in[0];
    const float* patchw = (const float*)d_in[1];
    const float* patchb = (const float*)d_in[2];
    const float* pos    = (const float*)d_in[3];
    const float* n1w    = (const float*)d_in[4];
    const float* n1b    = (const float*)d_in[5];
    const float* qkvw   = (const float*)d_in[6];
    const float* qkvb   = (const float*)d_in[7];
    const float* pw     = (const float*)d_in[8];
    const float* pb     = (const float*)d_in[9];
    const float* n2w    = (const float*)d_in[10];
    const float* n2b    = (const float*)d_in[11];
    const float* f1w    = (const float*)d_in[12];
    const float* f1b    = (const float*)d_in[13];
    const float* f2w    = (const float*)d_in[14];
    const float* f2b    = (const float*)d_in[15];
    const float* rph    = (const float*)d_in[16];
    const float* rpw    = (const float*)d_in[17];
    float* out = (float*)d_out;

    float* y   = (float*)d_ws;                  // 4096*384 f32
    u16* qkvx  = (u16*)(y + 1572864);           // 7168*1152 bf16
    u16* winb  = qkvx + 8257536;                // 7168*384 bf16
    u16* lnb   = winb + 2752512;                // 4096*384 bf16
    u16* attb  = lnb + 1572864;                 // 7168*384 bf16
    u16* unpb  = attb + 2752512;                // 4096*384 bf16
    u16* mlpb  = unpb + 1572864;                // 4096*1536 bf16
    u16* wb    = mlpb + 6291456;                // 10911744 bf16 weights
    u16* Dh    = wb + 10911744;                 // 1769472 bf16 (max 216*256*32 / 24*1024*64)
    u16* Dw    = Dh + 1769472;                  // 1769472 bf16
    u16* colb  = qkvx;                          // overlay: im2col buffer

    u16* wb_patch = wb;
    u16* wb_qkv   = wb + 294912;
    u16* wb_pw    = wb + 2949120;
    u16* wb_f1    = wb + 3833856;
    u16* wb_f2    = wb + 7372800;

    w2b_kernel<<<(294912 + 255) / 256, 256, 0, stream>>>(patchw, wb_patch, 294912);
    w2b_kernel<<<(2654208 + 255) / 256, 256, 0, stream>>>(qkvw, wb_qkv, 2654208);
    w2b_kernel<<<(884736 + 255) / 256, 256, 0, stream>>>(pw, wb_pw, 884736);
    w2b_kernel<<<(3538944 + 255) / 256, 256, 0, stream>>>(f1w, wb_f1, 3538944);
    w2b_kernel<<<(3538944 + 255) / 256, 256, 0, stream>>>(f2w, wb_f2, 3538944);

    {
        size_t tot = (size_t)NTOK * 768;
        im2col_kernel<<<(int)((tot + 255) / 256), 256, 0, stream>>>(x, colb);
        launch_gemm(colb, wb_patch, patchb, nullptr, y, nullptr, NTOK, 384, 768, 0, stream);
        add_pos_kernel<<<(1024 * 384 + 255) / 256, 256, 0, stream>>>(pos, y);
    }

    for (int i = 0; i < 6; ++i) {
        bool windowed = (i == 0 || i == 1 || i == 3 || i == 4);
        ln_kernel<<<NTOK, 64, 0, stream>>>(y, n1w + i * 384, n1b + i * 384, lnb);
        const float* rh = rph + (size_t)i * 63 * 64;
        const float* rw = rpw + (size_t)i * 63 * 64;
        if (windowed) {
            winpart_kernel<<<(MPAD * 384) / 256, 256, 0, stream>>>(lnb, winb);
            launch_gemm(winb, wb_qkv + (size_t)i * 442368, qkvb + i * 1152,
                        nullptr, nullptr, qkvx, MPAD, 1152, 384, 0, stream);
            relbias_mfma<32><<<dim3(NWIN * HEADS, 4), 256, 0, stream>>>(
                qkvx, rh, rw, Dh, Dw, WTOK, 27, 256);
            attn_mfma<WTOK, WS><<<dim3(NWIN * HEADS, 4), 256, 0, stream>>>(
                qkvx, Dh, Dw, attb);
            winunpart_kernel<<<(NTOK * 384) / 256, 256, 0, stream>>>(attb, unpb);
            launch_gemm(unpb, wb_pw + (size_t)i * 147456, pb + i * 384,
                        y, y, nullptr, NTOK, 384, 384, 0, stream);
        } else {
            launch_gemm(lnb, wb_qkv + (size_t)i * 442368, qkvb + i * 1152,
                        nullptr, nullptr, qkvx, NTOK, 1152, 384, 0, stream);
            relbias_mfma<64><<<dim3(B_SZ * HEADS, 16), 256, 0, stream>>>(
                qkvx, rh, rw, Dh, Dw, 1024, 63, 1024);
            attn_mfma<1024, 32><<<dim3(B_SZ * HEADS, 16), 256, 0, stream>>>(
                qkvx, Dh, Dw, attb);
            launch_gemm(attb, wb_pw + (size_t)i * 147456, pb + i * 384,
                        y, y, nullptr, NTOK, 384, 384, 0, stream);
        }
        ln_kernel<<<NTOK, 64, 0, stream>>>(y, n2w + i * 384, n2b + i * 384, lnb);
        launch_gemm(lnb, wb_f1 + (size_t)i * 589824, f1b + i * 1536,
                    nullptr, nullptr, mlpb, NTOK, 1536, 384, 1, stream);
        launch_gemm(mlpb, wb_f2 + (size_t)i * 589824, f2b + i * 384,
                    y, y, nullptr, NTOK, 384, 1536, 0, stream);
    }

    {
        size_t tot = (size_t)B_SZ * 384 * 1024;
        out_transpose_kernel<<<(int)((tot + 255) / 256), 256, 0, stream>>>(y, out);
    }
}

// Round 5
// 935.329 us; speedup vs baseline: 10.3036x; 1.3160x over previous
//
#include <hip/hip_runtime.h>
#include <math.h>

// ---------------- constants ----------------
#define B_SZ 4
#define DIM 384
#define HEADS 6
#define HD 64
#define NTOK 4096          // B*32*32
#define WS 14
#define NWIN 36            // B * 9
#define WTOK 196           // 14*14
#define PWTOK 7056         // 36*196
#define MPAD 7168          // padded rows for windowed qkv GEMM (56*128)

typedef unsigned short u16;
typedef __bf16 bf16_t;
typedef bf16_t bf16x8 __attribute__((ext_vector_type(8)));
typedef float f32x4 __attribute__((ext_vector_type(4)));

__device__ __forceinline__ float bf2f(unsigned u) { return __uint_as_float(u << 16); }
__device__ __forceinline__ u16 f2bf(float f) {
    unsigned u = __float_as_uint(f);
    unsigned r = (u + 0x7fffu + ((u >> 16) & 1u)) >> 16;
    return (u16)r;
}

// async global->LDS, 16B per lane, wave-uniform LDS base + lane*16
__device__ __forceinline__ void ldsload16(const u16* g, u16* l) {
    __builtin_amdgcn_global_load_lds(
        (const __attribute__((address_space(1))) unsigned int*)g,
        (__attribute__((address_space(3))) unsigned int*)l, 16, 0, 0);
}

__device__ __forceinline__ int swz(int r) { return (r ^ (r >> 2)) & 3; }

// ---------------- fp32 -> bf16 convert ----------------
__global__ __launch_bounds__(256) void w2b_kernel(const float* __restrict__ s,
                                                  u16* __restrict__ d, int n) {
    int i = blockIdx.x * 256 + threadIdx.x;
    if (i < n) d[i] = f2bf(s[i]);
}

// ---------------- im2col (bf16 out) ----------------
__global__ __launch_bounds__(256) void im2col_kernel(const float* __restrict__ x,
                                                     u16* __restrict__ col) {
    size_t idx = (size_t)blockIdx.x * 256 + threadIdx.x;
    if (idx >= (size_t)NTOK * 768) return;
    int kk = (int)(idx % 768);
    int p  = (int)(idx / 768);
    int b  = p / 1024;
    int ph = (p % 1024) / 32;
    int pw = p % 32;
    int c = kk / 256;
    int r = kk % 256;
    int i = r / 16, j = r % 16;
    col[idx] = f2bf(x[(size_t)b * 3 * 512 * 512 + (size_t)c * 512 * 512 +
                      (size_t)(ph * 16 + i) * 512 + (pw * 16 + j)]);
}

// ---------------- bicubic pos embed ----------------
__device__ inline float cubic_keys(float x) {
    x = fabsf(x);
    if (x <= 1.f) return ((1.5f * x - 2.5f) * x) * x + 1.f;
    if (x < 2.f)  return ((-0.5f * x + 2.5f) * x - 4.f) * x + 2.f;
    return 0.f;
}

__global__ __launch_bounds__(256) void add_pos_kernel(const float* __restrict__ pe,
                                                      float* __restrict__ y) {
    int idx = blockIdx.x * 256 + threadIdx.x;   // 1024*384
    if (idx >= 1024 * 384) return;
    int c = idx % 384;
    int g = idx / 384;
    int gy = g / 32, gx = g % 32;
    float wy[14], wx[14];
    float sy = (gy + 0.5f) * (14.f / 32.f) - 0.5f;
    float sx = (gx + 0.5f) * (14.f / 32.f) - 0.5f;
    float toty = 0.f, totx = 0.f;
    #pragma unroll
    for (int k = 0; k < 14; ++k) {
        wy[k] = cubic_keys(sy - (float)k); toty += wy[k];
        wx[k] = cubic_keys(sx - (float)k); totx += wx[k];
    }
    float val = 0.f;
    #pragma unroll 1
    for (int iy = 0; iy < 14; ++iy) {
        if (wy[iy] == 0.f) continue;
        float row = 0.f;
        for (int ix = 0; ix < 14; ++ix) {
            if (wx[ix] == 0.f) continue;
            row += wx[ix] * pe[(iy * 14 + ix) * 384 + c];
        }
        val += wy[iy] * row;
    }
    val /= (toty * totx);
    #pragma unroll
    for (int b = 0; b < B_SZ; ++b)
        y[((size_t)(b * 1024 + g)) * 384 + c] += val;
}

// ---------------- layernorm: fp32 in, bf16 out ----------------
__global__ __launch_bounds__(64) void ln_kernel(const float* __restrict__ x,
                                                const float* __restrict__ w,
                                                const float* __restrict__ b,
                                                u16* __restrict__ out) {
    int tok = blockIdx.x;
    int t = threadIdx.x;
    const float* xr = x + (size_t)tok * 384;
    float v[6];
    float s = 0.f;
    #pragma unroll
    for (int i = 0; i < 6; ++i) { v[i] = xr[t + 64 * i]; s += v[i]; }
    #pragma unroll
    for (int off = 32; off > 0; off >>= 1) s += __shfl_xor(s, off);
    float mean = s * (1.f / 384.f);
    float vs = 0.f;
    #pragma unroll
    for (int i = 0; i < 6; ++i) { float d = v[i] - mean; vs += d * d; }
    #pragma unroll
    for (int off = 32; off > 0; off >>= 1) vs += __shfl_xor(vs, off);
    float inv = rsqrtf(vs * (1.f / 384.f) + 1e-5f);
    u16* orow = out + (size_t)tok * 384;
    #pragma unroll
    for (int i = 0; i < 6; ++i) {
        int c = t + 64 * i;
        orow[c] = f2bf((v[i] - mean) * inv * w[c] + b[c]);
    }
}

// ---------------- window partition / unpartition (bf16) ----------------
__global__ __launch_bounds__(256) void winpart_kernel(const u16* __restrict__ xn,
                                                      u16* __restrict__ win) {
    size_t idx = (size_t)blockIdx.x * 256 + threadIdx.x;   // MPAD*384
    if (idx >= (size_t)MPAD * 384) return;
    int c = (int)(idx % 384);
    int tk = (int)(idx / 384);
    if (tk >= PWTOK) { win[idx] = 0; return; }
    int wtok = tk % WTOK;
    int w = tk / WTOK;
    int b = w / 9;
    int wy = (w % 9) / 3, wx = w % 3;
    int iy = wtok / WS, ix = wtok % WS;
    int gy = wy * WS + iy, gx = wx * WS + ix;
    u16 val = 0;
    if (gy < 32 && gx < 32)
        val = xn[((size_t)(b * 1024 + gy * 32 + gx)) * 384 + c];
    win[idx] = val;
}

__global__ __launch_bounds__(256) void winunpart_kernel(const u16* __restrict__ aout,
                                                        u16* __restrict__ out) {
    size_t idx = (size_t)blockIdx.x * 256 + threadIdx.x;   // 4096*384
    if (idx >= (size_t)NTOK * 384) return;
    int c = (int)(idx % 384);
    int tk = (int)(idx / 384);
    int b = tk / 1024;
    int g = tk % 1024;
    int gy = g / 32, gx = g % 32;
    int wy = gy / WS, iy = gy % WS;
    int wx = gx / WS, ix = gx % WS;
    int w = b * 9 + wy * 3 + wx;
    out[idx] = aout[((size_t)(w * WTOK + iy * WS + ix)) * 384 + c];
}

// ---------------- MFMA bf16 GEMM v2: BM=128, BN=64, BK=32, optional split-K ----
// grid (N/64, M/128, SK). Direct mode: outf/outb epilogue. Partial mode: outp.
__global__ __launch_bounds__(256) void mfma_gemm2(
        const u16* __restrict__ A, const u16* __restrict__ Wt,
        const float* __restrict__ bias, const float* __restrict__ res,
        float* __restrict__ outf, u16* __restrict__ outb,
        float* __restrict__ outp,
        int M, int N, int K, int act, int ksplit)
{
    __shared__ u16 As[4096];   // 128 rows x 32 cols
    __shared__ u16 Bs[2048];   // 64 rows x 32 cols
    int t = threadIdx.x;
    int lane = t & 63, wave = t >> 6;
    int wm = (wave >> 1) * 64, wn = (wave & 1) * 32;
    int m0 = blockIdx.y * 128, n0 = blockIdx.x * 64;
    int ks = blockIdx.z * ksplit, ke = ks + ksplit;

    int r0 = t >> 2,        c0 = ((t & 3) ^ swz(t >> 2)) * 8;
    int r1 = 64 + (t >> 2), c1 = ((t & 3) ^ swz(64 + (t >> 2))) * 8;
    const u16* a0 = A + (size_t)(m0 + r0) * K + c0;
    const u16* a1 = A + (size_t)(m0 + r1) * K + c1;
    const u16* b0 = Wt + (size_t)(n0 + r0) * K + c0;
    u16* asd0 = &As[wave * 512];
    u16* asd1 = &As[2048 + wave * 512];
    u16* bsd0 = &Bs[wave * 512];

    f32x4 acc[4][2] = {};
    int row_a = wm + (lane & 15);
    int row_b = wn + (lane & 15);
    int lq = lane >> 4;

    for (int k0 = ks; k0 < ke; k0 += 32) {
        ldsload16(a0 + k0, asd0);
        ldsload16(a1 + k0, asd1);
        ldsload16(b0 + k0, bsd0);
        __syncthreads();
        bf16x8 af[4], bfr[2];
        #pragma unroll
        for (int i = 0; i < 4; ++i) {
            int r = row_a + i * 16;
            af[i] = *(const bf16x8*)&As[r * 32 + ((lq ^ swz(r)) * 8)];
        }
        #pragma unroll
        for (int j = 0; j < 2; ++j) {
            int r = row_b + j * 16;
            bfr[j] = *(const bf16x8*)&Bs[r * 32 + ((lq ^ swz(r)) * 8)];
        }
        #pragma unroll
        for (int i = 0; i < 4; ++i)
            #pragma unroll
            for (int j = 0; j < 2; ++j)
                acc[i][j] = __builtin_amdgcn_mfma_f32_16x16x32_bf16(
                    af[i], bfr[j], acc[i][j], 0, 0, 0);
        __syncthreads();
    }

    int colq = lane & 15, rowq = (lane >> 4) * 4;
    if (outp) {
        float* pp = outp + (size_t)blockIdx.z * M * N;
        #pragma unroll
        for (int i = 0; i < 4; ++i) {
            #pragma unroll
            for (int rr = 0; rr < 4; ++rr) {
                int m = m0 + wm + i * 16 + rowq + rr;
                size_t mo = (size_t)m * N;
                #pragma unroll
                for (int j = 0; j < 2; ++j) {
                    int n = n0 + wn + j * 16 + colq;
                    pp[mo + n] = acc[i][j][rr];
                }
            }
        }
        return;
    }
    #pragma unroll
    for (int i = 0; i < 4; ++i) {
        #pragma unroll
        for (int rr = 0; rr < 4; ++rr) {
            int m = m0 + wm + i * 16 + rowq + rr;
            size_t mo = (size_t)m * N;
            #pragma unroll
            for (int j = 0; j < 2; ++j) {
                int n = n0 + wn + j * 16 + colq;
                float v = acc[i][j][rr] + bias[n];
                if (res)  v += res[mo + n];
                if (act)  v = 0.5f * v * (1.f + erff(v * 0.70710678118654752f));
                if (outf) outf[mo + n] = v;
                if (outb) outb[mo + n] = f2bf(v);
            }
        }
    }
}

// ---------------- split-K epilogue: y = sum_s P[s] + bias (+ y) ----------------
__global__ __launch_bounds__(256) void sk_epi_kernel(const float* __restrict__ P,
        const float* __restrict__ bias, float* __restrict__ y,
        int mn4, int n4, int addres)
{
    int i = blockIdx.x * 256 + threadIdx.x;
    if (i >= mn4) return;
    const float4* p = (const float4*)P;
    float4 v0 = p[i];
    float4 v1 = p[i + mn4];
    float4 v2 = p[i + 2 * mn4];
    float4 v3 = p[i + 3 * mn4];
    float4 b = ((const float4*)bias)[i % n4];
    float4 o;
    o.x = v0.x + v1.x + v2.x + v3.x + b.x;
    o.y = v0.y + v1.y + v2.y + v3.y + b.y;
    o.z = v0.z + v1.z + v2.z + v3.z + b.z;
    o.w = v0.w + v1.w + v2.w + v3.w + b.w;
    if (addres) {
        float4 r = ((const float4*)y)[i];
        o.x += r.x; o.y += r.y; o.z += r.z; o.w += r.w;
    }
    ((float4*)y)[i] = o;
}

// ---------------- rel-pos bias: batched MFMA GEMM ----------------
template<int JS>
__global__ __launch_bounds__(256) void relbias_mfma(const u16* __restrict__ qkv,
        const float* __restrict__ rh, const float* __restrict__ rw,
        u16* __restrict__ Dh, u16* __restrict__ Dw,
        int N, int L, int qstride)
{
    constexpr int DS = 2 * JS + 8;
    __shared__ u16 Qt[64 * 66];        // [c][q]
    __shared__ u16 Rt[2][JS * 72];     // [table][j][c]
    __shared__ u16 Dl[64 * DS];        // [q][table*JS + j]
    int t = threadIdx.x, lane = t & 63, wave = t >> 6;
    int quad = lane >> 4, l15 = lane & 15;
    int uh = blockIdx.x, qb0 = blockIdx.y * 64;
    int h = uh % HEADS, u = uh / HEADS;
    size_t tbase = (size_t)u * N;

    {
        int q = t & 63, ch0 = (t >> 6) * 16;
        int qc = qb0 + q; if (qc >= N) qc = N - 1;
        const u16* qp = qkv + (tbase + qc) * 1152 + h * 64 + ch0;
        uint4 a = *(const uint4*)qp;
        uint4 b = *(const uint4*)(qp + 8);
        u16 vals[16];
        *(uint4*)vals = a; *(uint4*)(vals + 8) = b;
        #pragma unroll
        for (int c = 0; c < 16; ++c)
            Qt[(ch0 + c) * 66 + q] = vals[c];
    }
    for (int idx = t; idx < 2 * JS * 8; idx += 256) {
        int table = idx >= JS * 8;
        int rem = idx - table * JS * 8;
        int j = rem >> 3, cc0 = (rem & 7) * 8;
        const float* src = (table ? rw : rh) + (size_t)j * 64 + cc0;
        u16 tmp[8];
        #pragma unroll
        for (int c = 0; c < 8; ++c) tmp[c] = (j < L) ? f2bf(src[c]) : (u16)0;
        *(uint4*)&Rt[table][j * 72 + cc0] = *(uint4*)tmp;
    }
    __syncthreads();

    constexpr int NMT = 2 * (JS / 16);
    for (int mt = wave; mt < NMT; mt += 4) {
        int table = mt / (JS / 16), jt = mt % (JS / 16);
        bf16x8 af0 = *(const bf16x8*)&Rt[table][(jt * 16 + l15) * 72 + quad * 8];
        bf16x8 af1 = *(const bf16x8*)&Rt[table][(jt * 16 + l15) * 72 + 32 + quad * 8];
        #pragma unroll
        for (int qt = 0; qt < 4; ++qt) {
            bf16x8 qf0, qf1;
            u16* p0 = (u16*)&qf0; u16* p1 = (u16*)&qf1;
            #pragma unroll
            for (int z = 0; z < 8; ++z) {
                p0[z] = Qt[(quad * 8 + z) * 66 + qt * 16 + l15];
                p1[z] = Qt[(32 + quad * 8 + z) * 66 + qt * 16 + l15];
            }
            f32x4 acc = {};
            acc = __builtin_amdgcn_mfma_f32_16x16x32_bf16(af0, qf0, acc, 0, 0, 0);
            acc = __builtin_amdgcn_mfma_f32_16x16x32_bf16(af1, qf1, acc, 0, 0, 0);
            #pragma unroll
            for (int r = 0; r < 4; ++r)
                Dl[(qt * 16 + l15) * DS + table * JS + jt * 16 + quad * 4 + r] =
                    f2bf(acc[r]);
        }
    }
    __syncthreads();

    constexpr int CHUNKS = 64 * (2 * JS) / 8;
    for (int ci = t; ci < CHUNKS; ci += 256) {
        int q = ci / (2 * JS / 8);
        int rem = ci % (2 * JS / 8);
        int table = rem >= (JS / 8);
        int j0 = (rem - table * (JS / 8)) * 8;
        uint4 v = *(const uint4*)&Dl[q * DS + table * JS + j0];
        u16* dst = (table ? Dw : Dh) + ((size_t)uh * qstride + qb0 + q) * JS + j0;
        *(uint4*)dst = v;
    }
}

// ---------------- MFMA flash attention (transposed products) ----------------
template<int N, int W>
__global__ __launch_bounds__(256) void attn_mfma(const u16* __restrict__ qkv,
        const u16* __restrict__ Dh, const u16* __restrict__ Dw,
        u16* __restrict__ outb)
{
    constexpr int JS = (W == 32) ? 64 : 32;
    constexpr int QSTRIDE = (W == 32) ? 1024 : 256;
    constexpr int CTR = W - 1;
    __shared__ u16 Ks[2048];          // 32 keys x 64 ch, 16B-chunk XOR-swizzled
    __shared__ u16 Vt[64 * 40];       // [ch][key]
    __shared__ u16 Pb[4][16 * 40];    // per-wave P [q][key]
    __shared__ u16 bhl[64 * 66];      // D rows bf16 [q][j]
    __shared__ u16 bwl[64 * 66];
    __shared__ u16 Qt[64 * 66];       // [ch][q], pre-scaled

    int t = threadIdx.x, lane = t & 63, wave = t >> 6;
    int quad = lane >> 4, l15 = lane & 15;
    int uh = blockIdx.x, qb0 = blockIdx.y * 64;
    int h = uh % HEADS, u = uh / HEADS;
    size_t tbase = (size_t)u * N;

    {
        int q = t & 63, ch0 = (t >> 6) * 16;
        int qc = qb0 + q;
        int qcc = (qc < N) ? qc : (N - 1);
        const u16* qp = qkv + (tbase + qcc) * 1152 + h * 64 + ch0;
        uint4 a = *(const uint4*)qp;
        uint4 b = *(const uint4*)(qp + 8);
        u16 vals[16];
        *(uint4*)vals = a; *(uint4*)(vals + 8) = b;
        #pragma unroll
        for (int c = 0; c < 16; ++c) {
            float f = (qc < N) ? bf2f(vals[c]) * 0.125f : 0.f;
            Qt[(ch0 + c) * 66 + q] = f2bf(f);
        }
    }
    {
        int q = t & 63, rep = t >> 6;
        int qc = qb0 + q; if (qc >= N) qc = N - 1;
        const u16* ph  = Dh + ((size_t)uh * QSTRIDE + qc) * JS;
        const u16* pw_ = Dw + ((size_t)uh * QSTRIDE + qc) * JS;
        #pragma unroll
        for (int g2 = 0; g2 < JS / 32; ++g2) {
            int j0 = rep * (JS / 4) + g2 * 8;
            uint4 a = *(const uint4*)(ph + j0);
            uint4 b = *(const uint4*)(pw_ + j0);
            u16 ta[8], tb[8];
            *(uint4*)ta = a; *(uint4*)tb = b;
            #pragma unroll
            for (int c = 0; c < 8; ++c) {
                bhl[q * 66 + j0 + c] = ta[c];
                bwl[q * 66 + j0 + c] = tb[c];
            }
        }
    }
    __syncthreads();

    bf16x8 qf[2];
    #pragma unroll
    for (int hc = 0; hc < 2; ++hc) {
        u16* qv = (u16*)&qf[hc];
        #pragma unroll
        for (int j = 0; j < 8; ++j)
            qv[j] = Qt[(hc * 32 + quad * 8 + j) * 66 + wave * 16 + l15];
    }
    int qme = wave * 16 + l15;
    int qq = qb0 + qme; if (qq >= N) qq = N - 1;
    int qh = qq / W, qw = qq - qh * W;
    float bwreg[2][4];
    if constexpr (W == 32) {
        #pragma unroll
        for (int kc2 = 0; kc2 < 2; ++kc2)
            #pragma unroll
            for (int r = 0; r < 4; ++r) {
                int keyl = kc2 * 16 + quad * 4 + r;
                bwreg[kc2][r] = bf2f(bwl[qme * 66 + (qw - keyl + CTR)]);
            }
    }

    f32x4 of[4] = {};
    float lsum = 0.f;
    constexpr int NKT = (N + 31) / 32;

    for (int kt = 0; kt < NKT; ++kt) {
        int kb = kt * 32;
        __syncthreads();
        {
            int p = wave * 64 + lane;
            int key = p >> 3;
            int c8 = (p & 7) ^ (key & 7);
            int kc = kb + key; if (kc >= N) kc = N - 1;
            ldsload16(qkv + (tbase + kc) * 1152 + 384 + h * 64 + c8 * 8,
                      &Ks[wave * 512]);
        }
        {
            int k = t & 31, ch0 = (t >> 5) * 8;
            int kc = kb + k; if (kc >= N) kc = N - 1;
            const u16* vp = qkv + (tbase + kc) * 1152 + 768 + h * 64 + ch0;
            uint4 vv = *(const uint4*)vp;
            u16 tmp[8]; *(uint4*)tmp = vv;
            #pragma unroll
            for (int c = 0; c < 8; ++c) Vt[(ch0 + c) * 40 + k] = tmp[c];
        }
        __syncthreads();

        f32x4 st[2] = {};
        #pragma unroll
        for (int hc = 0; hc < 2; ++hc) {
            #pragma unroll
            for (int kc2 = 0; kc2 < 2; ++kc2) {
                int key = kc2 * 16 + l15;
                int c8 = hc * 4 + quad;
                int p = key * 8 + (c8 ^ (key & 7));
                bf16x8 kf = *(const bf16x8*)&Ks[p * 8];
                st[kc2] = __builtin_amdgcn_mfma_f32_16x16x32_bf16(
                    kf, qf[hc], st[kc2], 0, 0, 0);
            }
        }
        float bh_t = 0.f;
        if constexpr (W == 32) bh_t = bf2f(bhl[qme * 66 + (qh - (kb >> 5) + CTR)]);
        #pragma unroll
        for (int kc2 = 0; kc2 < 2; ++kc2) {
            #pragma unroll
            for (int r = 0; r < 4; ++r) {
                int keyl = kc2 * 16 + quad * 4 + r;
                int key = kb + keyl;
                float b;
                if constexpr (W == 32) {
                    b = bh_t + bwreg[kc2][r];
                } else {
                    int kk2 = (key < N) ? key : (N - 1);
                    int kh = kk2 / W, kw = kk2 - kh * W;
                    b = bf2f(bhl[qme * 66 + (qh - kh + CTR)]) +
                        bf2f(bwl[qme * 66 + (qw - kw + CTR)]);
                }
                float p = __expf(st[kc2][r] + b);
                if (key >= N) p = 0.f;
                lsum += p;
                Pb[wave][l15 * 40 + keyl] = f2bf(p);
            }
        }
        bf16x8 pf = *(const bf16x8*)&Pb[wave][l15 * 40 + quad * 8];
        #pragma unroll
        for (int ca = 0; ca < 4; ++ca) {
            bf16x8 vf = *(const bf16x8*)&Vt[(ca * 16 + l15) * 40 + quad * 8];
            of[ca] = __builtin_amdgcn_mfma_f32_16x16x32_bf16(
                vf, pf, of[ca], 0, 0, 0);
        }
    }

    lsum += __shfl_xor(lsum, 16);
    lsum += __shfl_xor(lsum, 32);
    float inv = 1.f / lsum;
    int q = qb0 + qme;
    if (q < N) {
        u16* op = outb + (tbase + q) * 384 + h * 64;
        #pragma unroll
        for (int ca = 0; ca < 4; ++ca)
            #pragma unroll
            for (int r = 0; r < 4; ++r)
                op[ca * 16 + quad * 4 + r] = f2bf(of[ca][r] * inv);
    }
}

// ---------------- final NHWC -> NCHW ----------------
__global__ __launch_bounds__(256) void out_transpose_kernel(const float* __restrict__ y,
                                                            float* __restrict__ out) {
    size_t idx = (size_t)blockIdx.x * 256 + threadIdx.x;   // 4*384*1024
    if (idx >= (size_t)B_SZ * 384 * 1024) return;
    int g = (int)(idx % 1024);
    int c = (int)((idx / 1024) % 384);
    int b = (int)(idx / (1024 * 384));
    out[idx] = y[((size_t)b * 1024 + g) * 384 + c];
}

// ---------------- host helpers ----------------
static inline void launch_gemm(const u16* A, const u16* W, const float* bias,
                               const float* res, float* outf, u16* outb,
                               int M, int N, int K, int act, hipStream_t s) {
    dim3 g(N / 64, M / 128, 1);
    mfma_gemm2<<<g, 256, 0, s>>>(A, W, bias, res, outf, outb, nullptr,
                                 M, N, K, act, K);
}

static inline void launch_gemm_sk(const u16* A, const u16* W, float* P,
                                  int M, int N, int K, int SK, hipStream_t s) {
    dim3 g(N / 64, M / 128, SK);
    mfma_gemm2<<<g, 256, 0, s>>>(A, W, nullptr, nullptr, nullptr, nullptr, P,
                                 M, N, K, 0, K / SK);
}

static inline void launch_epi(const float* P, const float* bias, float* y,
                              int addres, hipStream_t s) {
    // M*N = 4096*384 -> 393216 float4
    sk_epi_kernel<<<1536, 256, 0, s>>>(P, bias, y, 393216, 96, addres);
}

extern "C" void kernel_launch(void* const* d_in, const int* in_sizes, int n_in,
                              void* d_out, int out_size, void* d_ws, size_t ws_size,
                              hipStream_t stream) {
    const float* x      = (const float*)d_in[0];
    const float* patchw = (const float*)d_in[1];
    const float* patchb = (const float*)d_in[2];
    const float* pos    = (const float*)d_in[3];
    const float* n1w    = (const float*)d_in[4];
    const float* n1b    = (const float*)d_in[5];
    const float* qkvw   = (const float*)d_in[6];
    const float* qkvb   = (const float*)d_in[7];
    const float* pw     = (const float*)d_in[8];
    const float* pb     = (const float*)d_in[9];
    const float* n2w    = (const float*)d_in[10];
    const float* n2b    = (const float*)d_in[11];
    const float* f1w    = (const float*)d_in[12];
    const float* f1b    = (const float*)d_in[13];
    const float* f2w    = (const float*)d_in[14];
    const float* f2b    = (const float*)d_in[15];
    const float* rph    = (const float*)d_in[16];
    const float* rpw    = (const float*)d_in[17];
    float* out = (float*)d_out;

    float* y   = (float*)d_ws;                  // 4096*384 f32
    u16* qkvx  = (u16*)(y + 1572864);           // 7168*1152 bf16
    u16* winb  = qkvx + 8257536;                // 7168*384 bf16
    u16* lnb   = winb + 2752512;                // 4096*384 bf16
    u16* attb  = lnb + 1572864;                 // 7168*384 bf16
    u16* unpb  = attb + 2752512;                // 4096*384 bf16
    u16* mlpb  = unpb + 1572864;                // 4096*1536 bf16
    u16* wb    = mlpb + 6291456;                // 10911744 bf16 weights
    u16* Dh    = wb + 10911744;                 // bf16 rel-bias D tables
    u16* Dw    = Dh + 1769472;
    u16* colb  = qkvx;                          // overlay: im2col buffer
    // split-K partial overlays (fp32, 4*4096*384 = 25165824 B each):
    //  - patch phase: winb..(winb+29.8MB region free: winb,lnb,attb,unpb,mlpb)
    //  - proj/fc2 phase: qkvx..(qkvx+25.2MB region free: qkvx,winb,lnb)
    float* P_patch = (float*)winb;
    float* P_pf    = (float*)qkvx;

    u16* wb_patch = wb;
    u16* wb_qkv   = wb + 294912;
    u16* wb_pw    = wb + 2949120;
    u16* wb_f1    = wb + 3833856;
    u16* wb_f2    = wb + 7372800;

    w2b_kernel<<<(294912 + 255) / 256, 256, 0, stream>>>(patchw, wb_patch, 294912);
    w2b_kernel<<<(2654208 + 255) / 256, 256, 0, stream>>>(qkvw, wb_qkv, 2654208);
    w2b_kernel<<<(884736 + 255) / 256, 256, 0, stream>>>(pw, wb_pw, 884736);
    w2b_kernel<<<(3538944 + 255) / 256, 256, 0, stream>>>(f1w, wb_f1, 3538944);
    w2b_kernel<<<(3538944 + 255) / 256, 256, 0, stream>>>(f2w, wb_f2, 3538944);

    {
        size_t tot = (size_t)NTOK * 768;
        im2col_kernel<<<(int)((tot + 255) / 256), 256, 0, stream>>>(x, colb);
        launch_gemm_sk(colb, wb_patch, P_patch, NTOK, 384, 768, 4, stream);
        launch_epi(P_patch, patchb, y, 0, stream);
        add_pos_kernel<<<(1024 * 384 + 255) / 256, 256, 0, stream>>>(pos, y);
    }

    for (int i = 0; i < 6; ++i) {
        bool windowed = (i == 0 || i == 1 || i == 3 || i == 4);
        ln_kernel<<<NTOK, 64, 0, stream>>>(y, n1w + i * 384, n1b + i * 384, lnb);
        const float* rh = rph + (size_t)i * 63 * 64;
        const float* rw = rpw + (size_t)i * 63 * 64;
        if (windowed) {
            winpart_kernel<<<(MPAD * 384) / 256, 256, 0, stream>>>(lnb, winb);
            launch_gemm(winb, wb_qkv + (size_t)i * 442368, qkvb + i * 1152,
                        nullptr, nullptr, qkvx, MPAD, 1152, 384, 0, stream);
            relbias_mfma<32><<<dim3(NWIN * HEADS, 4), 256, 0, stream>>>(
                qkvx, rh, rw, Dh, Dw, WTOK, 27, 256);
            attn_mfma<WTOK, WS><<<dim3(NWIN * HEADS, 4), 256, 0, stream>>>(
                qkvx, Dh, Dw, attb);
            winunpart_kernel<<<(NTOK * 384) / 256, 256, 0, stream>>>(attb, unpb);
            launch_gemm_sk(unpb, wb_pw + (size_t)i * 147456, P_pf,
                           NTOK, 384, 384, 4, stream);
            launch_epi(P_pf, pb + i * 384, y, 1, stream);
        } else {
            launch_gemm(lnb, wb_qkv + (size_t)i * 442368, qkvb + i * 1152,
                        nullptr, nullptr, qkvx, NTOK, 1152, 384, 0, stream);
            relbias_mfma<64><<<dim3(B_SZ * HEADS, 16), 256, 0, stream>>>(
                qkvx, rh, rw, Dh, Dw, 1024, 63, 1024);
            attn_mfma<1024, 32><<<dim3(B_SZ * HEADS, 16), 256, 0, stream>>>(
                qkvx, Dh, Dw, attb);
            launch_gemm_sk(attb, wb_pw + (size_t)i * 147456, P_pf,
                           NTOK, 384, 384, 4, stream);
            launch_epi(P_pf, pb + i * 384, y, 1, stream);
        }
        ln_kernel<<<NTOK, 64, 0, stream>>>(y, n2w + i * 384, n2b + i * 384, lnb);
        launch_gemm(lnb, wb_f1 + (size_t)i * 589824, f1b + i * 1536,
                    nullptr, nullptr, mlpb, NTOK, 1536, 384, 1, stream);
        launch_gemm_sk(mlpb, wb_f2 + (size_t)i * 589824, P_pf,
                       NTOK, 384, 1536, 4, stream);
        launch_epi(P_pf, f2b + i * 384, y, 1, stream);
    }

    {
        size_t tot = (size_t)B_SZ * 384 * 1024;
        out_transpose_kernel<<<(int)((tot + 255) / 256), 256, 0, stream>>>(y, out);
    }
}

// Round 6
// 859.516 us; speedup vs baseline: 11.2124x; 1.0882x over previous
//
#include <hip/hip_runtime.h>
#include <math.h>

// ---------------- constants ----------------
#define B_SZ 4
#define DIM 384
#define HEADS 6
#define HD 64
#define NTOK 4096          // B*32*32
#define WS 14
#define NWIN 36            // B * 9
#define WTOK 196           // 14*14
#define PWTOK 7056         // 36*196
#define MPAD 7168          // padded rows for windowed qkv GEMM (56*128)

typedef unsigned short u16;
typedef __bf16 bf16_t;
typedef bf16_t bf16x8 __attribute__((ext_vector_type(8)));
typedef float f32x4 __attribute__((ext_vector_type(4)));

__device__ __forceinline__ float bf2f(unsigned u) { return __uint_as_float(u << 16); }
__device__ __forceinline__ u16 f2bf(float f) {
    unsigned u = __float_as_uint(f);
    unsigned r = (u + 0x7fffu + ((u >> 16) & 1u)) >> 16;
    return (u16)r;
}

// async global->LDS, 16B per lane, wave-uniform LDS base + lane*16
__device__ __forceinline__ void ldsload16(const u16* g, u16* l) {
    __builtin_amdgcn_global_load_lds(
        (const __attribute__((address_space(1))) unsigned int*)g,
        (__attribute__((address_space(3))) unsigned int*)l, 16, 0, 0);
}

__device__ __forceinline__ int swz(int r) { return (r ^ (r >> 2)) & 3; }

// A-row gather: 0 = identity, 1 = window-partition (token<-lnb, pad->zp),
// 2 = window-unpartition (token<-attb window layout)
__device__ __forceinline__ const u16* arow(const u16* A, int K, int m,
                                           int gather, const u16* zp) {
    if (gather == 1) {
        if (m >= PWTOK) return zp;
        int w = m / WTOK, wt = m - w * WTOK;
        int b = w / 9, r = w - b * 9;
        int wy = r / 3, wx = r - wy * 3;
        int iy = wt / WS, ix = wt - iy * WS;
        int gy = wy * WS + iy, gx = wx * WS + ix;
        if (gy >= 32 || gx >= 32) return zp;
        return A + (size_t)(b * 1024 + gy * 32 + gx) * (size_t)K;
    } else if (gather == 2) {
        int b = m >> 10, g = m & 1023;
        int gy = g >> 5, gx = g & 31;
        int wy = gy / WS, iy = gy - wy * WS;
        int wx = gx / WS, ix = gx - wx * WS;
        int w = b * 9 + wy * 3 + wx;
        return A + (size_t)(w * WTOK + iy * WS + ix) * (size_t)K;
    }
    return A + (size_t)m * (size_t)K;
}

// ---------------- fp32 -> bf16 convert ----------------
__global__ __launch_bounds__(256) void w2b_kernel(const float* __restrict__ s,
                                                  u16* __restrict__ d, int n) {
    int i = blockIdx.x * 256 + threadIdx.x;
    if (i < n) d[i] = f2bf(s[i]);
}

// ---------------- im2col (bf16 out) ----------------
__global__ __launch_bounds__(256) void im2col_kernel(const float* __restrict__ x,
                                                     u16* __restrict__ col) {
    size_t idx = (size_t)blockIdx.x * 256 + threadIdx.x;
    if (idx >= (size_t)NTOK * 768) return;
    int kk = (int)(idx % 768);
    int p  = (int)(idx / 768);
    int b  = p / 1024;
    int ph = (p % 1024) / 32;
    int pw = p % 32;
    int c = kk / 256;
    int r = kk % 256;
    int i = r / 16, j = r % 16;
    col[idx] = f2bf(x[(size_t)b * 3 * 512 * 512 + (size_t)c * 512 * 512 +
                      (size_t)(ph * 16 + i) * 512 + (pw * 16 + j)]);
}

// ---------------- bicubic pos embed -> posr table; also zeroes zpage ---------
__device__ inline float cubic_keys(float x) {
    x = fabsf(x);
    if (x <= 1.f) return ((1.5f * x - 2.5f) * x) * x + 1.f;
    if (x < 2.f)  return ((-0.5f * x + 2.5f) * x - 4.f) * x + 2.f;
    return 0.f;
}

__global__ __launch_bounds__(256) void pos_resize_kernel(const float* __restrict__ pe,
                                                         float* __restrict__ posr,
                                                         unsigned* __restrict__ zpage) {
    int idx = blockIdx.x * 256 + threadIdx.x;   // 1024*384
    if (idx < 512) zpage[idx] = 0u;
    if (idx >= 1024 * 384) return;
    int c = idx % 384;
    int g = idx / 384;
    int gy = g / 32, gx = g % 32;
    float wy[14], wx[14];
    float sy = (gy + 0.5f) * (14.f / 32.f) - 0.5f;
    float sx = (gx + 0.5f) * (14.f / 32.f) - 0.5f;
    float toty = 0.f, totx = 0.f;
    #pragma unroll
    for (int k = 0; k < 14; ++k) {
        wy[k] = cubic_keys(sy - (float)k); toty += wy[k];
        wx[k] = cubic_keys(sx - (float)k); totx += wx[k];
    }
    float val = 0.f;
    #pragma unroll 1
    for (int iy = 0; iy < 14; ++iy) {
        if (wy[iy] == 0.f) continue;
        float row = 0.f;
        for (int ix = 0; ix < 14; ++ix) {
            if (wx[ix] == 0.f) continue;
            row += wx[ix] * pe[(iy * 14 + ix) * 384 + c];
        }
        val += wy[iy] * row;
    }
    posr[idx] = val / (toty * totx);
}

// ---------------- standalone layernorm (used once, layer-0 ln1) --------------
__global__ __launch_bounds__(64) void ln_kernel(const float* __restrict__ x,
                                                const float* __restrict__ w,
                                                const float* __restrict__ b,
                                                u16* __restrict__ out) {
    int tok = blockIdx.x;
    int t = threadIdx.x;
    const float* xr = x + (size_t)tok * 384;
    float v[6];
    float s = 0.f;
    #pragma unroll
    for (int i = 0; i < 6; ++i) { v[i] = xr[t + 64 * i]; s += v[i]; }
    #pragma unroll
    for (int off = 32; off > 0; off >>= 1) s += __shfl_xor(s, off);
    float mean = s * (1.f / 384.f);
    float vs = 0.f;
    #pragma unroll
    for (int i = 0; i < 6; ++i) { float d = v[i] - mean; vs += d * d; }
    #pragma unroll
    for (int off = 32; off > 0; off >>= 1) vs += __shfl_xor(vs, off);
    float inv = rsqrtf(vs * (1.f / 384.f) + 1e-5f);
    u16* orow = out + (size_t)tok * 384;
    #pragma unroll
    for (int i = 0; i < 6; ++i) {
        int c = t + 64 * i;
        orow[c] = f2bf((v[i] - mean) * inv * w[c] + b[c]);
    }
}

// ---------------- fused split-K epilogue + residual + (optional) LN ----------
// One wave per token. P has 4 slices of 4096*384 fp32.
__global__ __launch_bounds__(64) void epi_ln_kernel(const float* __restrict__ P,
        const float* __restrict__ bias, const float* __restrict__ posr,
        float* __restrict__ y, int addy,
        const float* __restrict__ lw, const float* __restrict__ lb,
        u16* __restrict__ lnout)
{
    int tok = blockIdx.x, t = threadIdx.x;
    size_t base = (size_t)tok * 384;
    float v[6];
    float s = 0.f;
    #pragma unroll
    for (int i = 0; i < 6; ++i) {
        int c = t + 64 * i;
        float val = P[base + c] + P[1572864 + base + c]
                  + P[2 * 1572864 + base + c] + P[3 * 1572864 + base + c]
                  + bias[c];
        if (posr) val += posr[(size_t)(tok & 1023) * 384 + c];
        if (addy) val += y[base + c];
        y[base + c] = val;
        v[i] = val; s += val;
    }
    if (!lnout) return;
    #pragma unroll
    for (int off = 32; off > 0; off >>= 1) s += __shfl_xor(s, off);
    float mean = s * (1.f / 384.f);
    float vs = 0.f;
    #pragma unroll
    for (int i = 0; i < 6; ++i) { float d = v[i] - mean; vs += d * d; }
    #pragma unroll
    for (int off = 32; off > 0; off >>= 1) vs += __shfl_xor(vs, off);
    float inv = rsqrtf(vs * (1.f / 384.f) + 1e-5f);
    u16* orow = lnout + base;
    #pragma unroll
    for (int i = 0; i < 6; ++i) {
        int c = t + 64 * i;
        orow[c] = f2bf((v[i] - mean) * inv * lw[c] + lb[c]);
    }
}

// ---------------- MFMA bf16 GEMM v2: BM=128, BN=64, BK=32, split-K, A-gather --
__global__ __launch_bounds__(256) void mfma_gemm2(
        const u16* __restrict__ A, const u16* __restrict__ Wt,
        const float* __restrict__ bias, const float* __restrict__ res,
        float* __restrict__ outf, u16* __restrict__ outb,
        float* __restrict__ outp,
        int M, int N, int K, int act, int ksplit,
        int gather, const u16* __restrict__ zpage)
{
    __shared__ u16 As[4096];   // 128 rows x 32 cols
    __shared__ u16 Bs[2048];   // 64 rows x 32 cols
    int t = threadIdx.x;
    int lane = t & 63, wave = t >> 6;
    int wm = (wave >> 1) * 64, wn = (wave & 1) * 32;
    int m0 = blockIdx.y * 128, n0 = blockIdx.x * 64;
    int ks = blockIdx.z * ksplit, ke = ks + ksplit;

    int r0 = t >> 2,        c0 = ((t & 3) ^ swz(t >> 2)) * 8;
    int r1 = 64 + (t >> 2), c1 = ((t & 3) ^ swz(64 + (t >> 2))) * 8;
    const u16* a0 = arow(A, K, m0 + r0, gather, zpage) + c0;
    const u16* a1 = arow(A, K, m0 + r1, gather, zpage) + c1;
    const u16* b0 = Wt + (size_t)(n0 + r0) * K + c0;
    u16* asd0 = &As[wave * 512];
    u16* asd1 = &As[2048 + wave * 512];
    u16* bsd0 = &Bs[wave * 512];

    f32x4 acc[4][2] = {};
    int row_a = wm + (lane & 15);
    int row_b = wn + (lane & 15);
    int lq = lane >> 4;

    for (int k0 = ks; k0 < ke; k0 += 32) {
        ldsload16(a0 + k0, asd0);
        ldsload16(a1 + k0, asd1);
        ldsload16(b0 + k0, bsd0);
        __syncthreads();
        bf16x8 af[4], bfr[2];
        #pragma unroll
        for (int i = 0; i < 4; ++i) {
            int r = row_a + i * 16;
            af[i] = *(const bf16x8*)&As[r * 32 + ((lq ^ swz(r)) * 8)];
        }
        #pragma unroll
        for (int j = 0; j < 2; ++j) {
            int r = row_b + j * 16;
            bfr[j] = *(const bf16x8*)&Bs[r * 32 + ((lq ^ swz(r)) * 8)];
        }
        #pragma unroll
        for (int i = 0; i < 4; ++i)
            #pragma unroll
            for (int j = 0; j < 2; ++j)
                acc[i][j] = __builtin_amdgcn_mfma_f32_16x16x32_bf16(
                    af[i], bfr[j], acc[i][j], 0, 0, 0);
        __syncthreads();
    }

    int colq = lane & 15, rowq = (lane >> 4) * 4;
    if (outp) {
        float* pp = outp + (size_t)blockIdx.z * M * N;
        #pragma unroll
        for (int i = 0; i < 4; ++i) {
            #pragma unroll
            for (int rr = 0; rr < 4; ++rr) {
                int m = m0 + wm + i * 16 + rowq + rr;
                size_t mo = (size_t)m * N;
                #pragma unroll
                for (int j = 0; j < 2; ++j) {
                    int n = n0 + wn + j * 16 + colq;
                    pp[mo + n] = acc[i][j][rr];
                }
            }
        }
        return;
    }
    #pragma unroll
    for (int i = 0; i < 4; ++i) {
        #pragma unroll
        for (int rr = 0; rr < 4; ++rr) {
            int m = m0 + wm + i * 16 + rowq + rr;
            size_t mo = (size_t)m * N;
            #pragma unroll
            for (int j = 0; j < 2; ++j) {
                int n = n0 + wn + j * 16 + colq;
                float v = acc[i][j][rr] + bias[n];
                if (res)  v += res[mo + n];
                if (act)  v = 0.5f * v * (1.f + erff(v * 0.70710678118654752f));
                if (outf) outf[mo + n] = v;
                if (outb) outb[mo + n] = f2bf(v);
            }
        }
    }
}

// ---------------- rel-pos bias: batched MFMA GEMM ----------------
template<int JS>
__global__ __launch_bounds__(256) void relbias_mfma(const u16* __restrict__ qkv,
        const float* __restrict__ rh, const float* __restrict__ rw,
        u16* __restrict__ Dh, u16* __restrict__ Dw,
        int N, int L, int qstride)
{
    constexpr int DS = 2 * JS + 8;
    __shared__ u16 Qt[64 * 66];        // [c][q]
    __shared__ u16 Rt[2][JS * 72];     // [table][j][c]
    __shared__ u16 Dl[64 * DS];        // [q][table*JS + j]
    int t = threadIdx.x, lane = t & 63, wave = t >> 6;
    int quad = lane >> 4, l15 = lane & 15;
    int uh = blockIdx.x, qb0 = blockIdx.y * 64;
    int h = uh % HEADS, u = uh / HEADS;
    size_t tbase = (size_t)u * N;

    {
        int q = t & 63, ch0 = (t >> 6) * 16;
        int qc = qb0 + q; if (qc >= N) qc = N - 1;
        const u16* qp = qkv + (tbase + qc) * 1152 + h * 64 + ch0;
        uint4 a = *(const uint4*)qp;
        uint4 b = *(const uint4*)(qp + 8);
        u16 vals[16];
        *(uint4*)vals = a; *(uint4*)(vals + 8) = b;
        #pragma unroll
        for (int c = 0; c < 16; ++c)
            Qt[(ch0 + c) * 66 + q] = vals[c];
    }
    for (int idx = t; idx < 2 * JS * 8; idx += 256) {
        int table = idx >= JS * 8;
        int rem = idx - table * JS * 8;
        int j = rem >> 3, cc0 = (rem & 7) * 8;
        const float* src = (table ? rw : rh) + (size_t)j * 64 + cc0;
        u16 tmp[8];
        #pragma unroll
        for (int c = 0; c < 8; ++c) tmp[c] = (j < L) ? f2bf(src[c]) : (u16)0;
        *(uint4*)&Rt[table][j * 72 + cc0] = *(uint4*)tmp;
    }
    __syncthreads();

    constexpr int NMT = 2 * (JS / 16);
    for (int mt = wave; mt < NMT; mt += 4) {
        int table = mt / (JS / 16), jt = mt % (JS / 16);
        bf16x8 af0 = *(const bf16x8*)&Rt[table][(jt * 16 + l15) * 72 + quad * 8];
        bf16x8 af1 = *(const bf16x8*)&Rt[table][(jt * 16 + l15) * 72 + 32 + quad * 8];
        #pragma unroll
        for (int qt = 0; qt < 4; ++qt) {
            bf16x8 qf0, qf1;
            u16* p0 = (u16*)&qf0; u16* p1 = (u16*)&qf1;
            #pragma unroll
            for (int z = 0; z < 8; ++z) {
                p0[z] = Qt[(quad * 8 + z) * 66 + qt * 16 + l15];
                p1[z] = Qt[(32 + quad * 8 + z) * 66 + qt * 16 + l15];
            }
            f32x4 acc = {};
            acc = __builtin_amdgcn_mfma_f32_16x16x32_bf16(af0, qf0, acc, 0, 0, 0);
            acc = __builtin_amdgcn_mfma_f32_16x16x32_bf16(af1, qf1, acc, 0, 0, 0);
            #pragma unroll
            for (int r = 0; r < 4; ++r)
                Dl[(qt * 16 + l15) * DS + table * JS + jt * 16 + quad * 4 + r] =
                    f2bf(acc[r]);
        }
    }
    __syncthreads();

    constexpr int CHUNKS = 64 * (2 * JS) / 8;
    for (int ci = t; ci < CHUNKS; ci += 256) {
        int q = ci / (2 * JS / 8);
        int rem = ci % (2 * JS / 8);
        int table = rem >= (JS / 8);
        int j0 = (rem - table * (JS / 8)) * 8;
        uint4 v = *(const uint4*)&Dl[q * DS + table * JS + j0];
        u16* dst = (table ? Dw : Dh) + ((size_t)uh * qstride + qb0 + q) * JS + j0;
        *(uint4*)dst = v;
    }
}

// ---------------- MFMA flash attention (transposed products) ----------------
template<int N, int W>
__global__ __launch_bounds__(256) void attn_mfma(const u16* __restrict__ qkv,
        const u16* __restrict__ Dh, const u16* __restrict__ Dw,
        u16* __restrict__ outb)
{
    constexpr int JS = (W == 32) ? 64 : 32;
    constexpr int QSTRIDE = (W == 32) ? 1024 : 256;
    constexpr int CTR = W - 1;
    __shared__ u16 Ks[2048];          // 32 keys x 64 ch, 16B-chunk XOR-swizzled
    __shared__ u16 Vt[64 * 40];       // [ch][key]
    __shared__ u16 Pb[4][16 * 40];    // per-wave P [q][key]
    __shared__ u16 bhl[64 * 66];      // D rows bf16 [q][j]
    __shared__ u16 bwl[64 * 66];
    __shared__ u16 Qt[64 * 66];       // [ch][q], pre-scaled

    int t = threadIdx.x, lane = t & 63, wave = t >> 6;
    int quad = lane >> 4, l15 = lane & 15;
    int uh = blockIdx.x, qb0 = blockIdx.y * 64;
    int h = uh % HEADS, u = uh / HEADS;
    size_t tbase = (size_t)u * N;

    {
        int q = t & 63, ch0 = (t >> 6) * 16;
        int qc = qb0 + q;
        int qcc = (qc < N) ? qc : (N - 1);
        const u16* qp = qkv + (tbase + qcc) * 1152 + h * 64 + ch0;
        uint4 a = *(const uint4*)qp;
        uint4 b = *(const uint4*)(qp + 8);
        u16 vals[16];
        *(uint4*)vals = a; *(uint4*)(vals + 8) = b;
        #pragma unroll
        for (int c = 0; c < 16; ++c) {
            float f = (qc < N) ? bf2f(vals[c]) * 0.125f : 0.f;
            Qt[(ch0 + c) * 66 + q] = f2bf(f);
        }
    }
    {
        int q = t & 63, rep = t >> 6;
        int qc = qb0 + q; if (qc >= N) qc = N - 1;
        const u16* ph  = Dh + ((size_t)uh * QSTRIDE + qc) * JS;
        const u16* pw_ = Dw + ((size_t)uh * QSTRIDE + qc) * JS;
        #pragma unroll
        for (int g2 = 0; g2 < JS / 32; ++g2) {
            int j0 = rep * (JS / 4) + g2 * 8;
            uint4 a = *(const uint4*)(ph + j0);
            uint4 b = *(const uint4*)(pw_ + j0);
            u16 ta[8], tb[8];
            *(uint4*)ta = a; *(uint4*)tb = b;
            #pragma unroll
            for (int c = 0; c < 8; ++c) {
                bhl[q * 66 + j0 + c] = ta[c];
                bwl[q * 66 + j0 + c] = tb[c];
            }
        }
    }
    __syncthreads();

    bf16x8 qf[2];
    #pragma unroll
    for (int hc = 0; hc < 2; ++hc) {
        u16* qv = (u16*)&qf[hc];
        #pragma unroll
        for (int j = 0; j < 8; ++j)
            qv[j] = Qt[(hc * 32 + quad * 8 + j) * 66 + wave * 16 + l15];
    }
    int qme = wave * 16 + l15;
    int qq = qb0 + qme; if (qq >= N) qq = N - 1;
    int qh = qq / W, qw = qq - qh * W;
    float bwreg[2][4];
    if constexpr (W == 32) {
        #pragma unroll
        for (int kc2 = 0; kc2 < 2; ++kc2)
            #pragma unroll
            for (int r = 0; r < 4; ++r) {
                int keyl = kc2 * 16 + quad * 4 + r;
                bwreg[kc2][r] = bf2f(bwl[qme * 66 + (qw - keyl + CTR)]);
            }
    }

    f32x4 of[4] = {};
    float lsum = 0.f;
    constexpr int NKT = (N + 31) / 32;

    for (int kt = 0; kt < NKT; ++kt) {
        int kb = kt * 32;
        __syncthreads();
        {
            int p = wave * 64 + lane;
            int key = p >> 3;
            int c8 = (p & 7) ^ (key & 7);
            int kc = kb + key; if (kc >= N) kc = N - 1;
            ldsload16(qkv + (tbase + kc) * 1152 + 384 + h * 64 + c8 * 8,
                      &Ks[wave * 512]);
        }
        {
            int k = t & 31, ch0 = (t >> 5) * 8;
            int kc = kb + k; if (kc >= N) kc = N - 1;
            const u16* vp = qkv + (tbase + kc) * 1152 + 768 + h * 64 + ch0;
            uint4 vv = *(const uint4*)vp;
            u16 tmp[8]; *(uint4*)tmp = vv;
            #pragma unroll
            for (int c = 0; c < 8; ++c) Vt[(ch0 + c) * 40 + k] = tmp[c];
        }
        __syncthreads();

        f32x4 st[2] = {};
        #pragma unroll
        for (int hc = 0; hc < 2; ++hc) {
            #pragma unroll
            for (int kc2 = 0; kc2 < 2; ++kc2) {
                int key = kc2 * 16 + l15;
                int c8 = hc * 4 + quad;
                int p = key * 8 + (c8 ^ (key & 7));
                bf16x8 kf = *(const bf16x8*)&Ks[p * 8];
                st[kc2] = __builtin_amdgcn_mfma_f32_16x16x32_bf16(
                    kf, qf[hc], st[kc2], 0, 0, 0);
            }
        }
        float bh_t = 0.f;
        if constexpr (W == 32) bh_t = bf2f(bhl[qme * 66 + (qh - (kb >> 5) + CTR)]);
        #pragma unroll
        for (int kc2 = 0; kc2 < 2; ++kc2) {
            #pragma unroll
            for (int r = 0; r < 4; ++r) {
                int keyl = kc2 * 16 + quad * 4 + r;
                int key = kb + keyl;
                float b;
                if constexpr (W == 32) {
                    b = bh_t + bwreg[kc2][r];
                } else {
                    int kk2 = (key < N) ? key : (N - 1);
                    int kh = kk2 / W, kw = kk2 - kh * W;
                    b = bf2f(bhl[qme * 66 + (qh - kh + CTR)]) +
                        bf2f(bwl[qme * 66 + (qw - kw + CTR)]);
                }
                float p = __expf(st[kc2][r] + b);
                if (key >= N) p = 0.f;
                lsum += p;
                Pb[wave][l15 * 40 + keyl] = f2bf(p);
            }
        }
        bf16x8 pf = *(const bf16x8*)&Pb[wave][l15 * 40 + quad * 8];
        #pragma unroll
        for (int ca = 0; ca < 4; ++ca) {
            bf16x8 vf = *(const bf16x8*)&Vt[(ca * 16 + l15) * 40 + quad * 8];
            of[ca] = __builtin_amdgcn_mfma_f32_16x16x32_bf16(
                vf, pf, of[ca], 0, 0, 0);
        }
    }

    lsum += __shfl_xor(lsum, 16);
    lsum += __shfl_xor(lsum, 32);
    float inv = 1.f / lsum;
    int q = qb0 + qme;
    if (q < N) {
        u16* op = outb + (tbase + q) * 384 + h * 64;
        #pragma unroll
        for (int ca = 0; ca < 4; ++ca)
            #pragma unroll
            for (int r = 0; r < 4; ++r)
                op[ca * 16 + quad * 4 + r] = f2bf(of[ca][r] * inv);
    }
}

// ---------------- final NHWC -> NCHW ----------------
__global__ __launch_bounds__(256) void out_transpose_kernel(const float* __restrict__ y,
                                                            float* __restrict__ out) {
    size_t idx = (size_t)blockIdx.x * 256 + threadIdx.x;   // 4*384*1024
    if (idx >= (size_t)B_SZ * 384 * 1024) return;
    int g = (int)(idx % 1024);
    int c = (int)((idx / 1024) % 384);
    int b = (int)(idx / (1024 * 384));
    out[idx] = y[((size_t)b * 1024 + g) * 384 + c];
}

// ---------------- host helpers ----------------
static inline void launch_gemm(const u16* A, const u16* W, const float* bias,
                               float* outf, u16* outb,
                               int M, int N, int K, int act, int gather,
                               const u16* zp, hipStream_t s) {
    dim3 g(N / 64, M / 128, 1);
    mfma_gemm2<<<g, 256, 0, s>>>(A, W, bias, nullptr, outf, outb, nullptr,
                                 M, N, K, act, K, gather, zp);
}

static inline void launch_gemm_sk(const u16* A, const u16* W, float* P,
                                  int M, int N, int K, int SK, int gather,
                                  const u16* zp, hipStream_t s) {
    dim3 g(N / 64, M / 128, SK);
    mfma_gemm2<<<g, 256, 0, s>>>(A, W, nullptr, nullptr, nullptr, nullptr, P,
                                 M, N, K, 0, K / SK, gather, zp);
}

extern "C" void kernel_launch(void* const* d_in, const int* in_sizes, int n_in,
                              void* d_out, int out_size, void* d_ws, size_t ws_size,
                              hipStream_t stream) {
    const float* x      = (const float*)d_in[0];
    const float* patchw = (const float*)d_in[1];
    const float* patchb = (const float*)d_in[2];
    const float* pos    = (const float*)d_in[3];
    const float* n1w    = (const float*)d_in[4];
    const float* n1b    = (const float*)d_in[5];
    const float* qkvw   = (const float*)d_in[6];
    const float* qkvb   = (const float*)d_in[7];
    const float* pw     = (const float*)d_in[8];
    const float* pb     = (const float*)d_in[9];
    const float* n2w    = (const float*)d_in[10];
    const float* n2b    = (const float*)d_in[11];
    const float* f1w    = (const float*)d_in[12];
    const float* f1b    = (const float*)d_in[13];
    const float* f2w    = (const float*)d_in[14];
    const float* f2b    = (const float*)d_in[15];
    const float* rph    = (const float*)d_in[16];
    const float* rpw    = (const float*)d_in[17];
    float* out = (float*)d_out;

    // workspace layout (~76 MB). Ordering chosen so split-K partial overlays
    // never cover live buffers:
    //  P_patch = attb.. (attb+mlpb+lnb+qkvx dead during patch GEMM)
    //  P_pf    = qkvx.. (qkvx+Dh+Dw+pad dead during proj/fc2 GEMMs; y/lnb/attb/mlpb outside)
    float* y   = (float*)d_ws;                  // 1,572,864 f32
    u16* attb  = (u16*)(y + 1572864);           // 2,752,512 u16
    u16* mlpb  = attb + 2752512;                // 6,291,456 u16
    u16* lnb   = mlpb + 6291456;                // 1,572,864 u16
    u16* qkvx  = lnb + 1572864;                 // 8,257,536 u16
    u16* Dh    = qkvx + 8257536;                // 1,769,472 u16
    u16* Dw    = Dh + 1769472;                  // 1,769,472 u16
    u16* pad_  = Dw + 1769472;                  //   786,432 u16 (split-K pad)
    u16* wb    = pad_ + 786432;                 // 10,911,744 u16 weights
    float* posr = (float*)(wb + 10911744);      //   393,216 f32
    u16* zpage = (u16*)(posr + 393216);         //     1,024 u16 (zeroed)

    u16* colb  = Dh;                            // overlay: im2col (6.3MB <= Dh+Dw)
    float* P_patch = (float*)attb;              // 25,165,824 B over attb+mlpb+lnb+qkvx[:3.9MB]
    float* P_pf    = (float*)qkvx;              // 25,165,824 B over qkvx+Dh+Dw+pad

    u16* wb_patch = wb;
    u16* wb_qkv   = wb + 294912;
    u16* wb_pw    = wb + 2949120;
    u16* wb_f1    = wb + 3833856;
    u16* wb_f2    = wb + 7372800;

    w2b_kernel<<<(294912 + 255) / 256, 256, 0, stream>>>(patchw, wb_patch, 294912);
    w2b_kernel<<<(2654208 + 255) / 256, 256, 0, stream>>>(qkvw, wb_qkv, 2654208);
    w2b_kernel<<<(884736 + 255) / 256, 256, 0, stream>>>(pw, wb_pw, 884736);
    w2b_kernel<<<(3538944 + 255) / 256, 256, 0, stream>>>(f1w, wb_f1, 3538944);
    w2b_kernel<<<(3538944 + 255) / 256, 256, 0, stream>>>(f2w, wb_f2, 3538944);
    pos_resize_kernel<<<1536, 256, 0, stream>>>(pos, posr, (unsigned*)zpage);

    {
        size_t tot = (size_t)NTOK * 768;
        im2col_kernel<<<(int)((tot + 255) / 256), 256, 0, stream>>>(x, colb);
        launch_gemm_sk(colb, wb_patch, P_patch, NTOK, 384, 768, 4, 0, zpage, stream);
        epi_ln_kernel<<<NTOK, 64, 0, stream>>>(P_patch, patchb, posr, y, 0,
                                               nullptr, nullptr, nullptr);
        ln_kernel<<<NTOK, 64, 0, stream>>>(y, n1w, n1b, lnb);   // layer-0 ln1
    }

    for (int i = 0; i < 6; ++i) {
        bool windowed = (i == 0 || i == 1 || i == 3 || i == 4);
        const float* rh = rph + (size_t)i * 63 * 64;
        const float* rw = rpw + (size_t)i * 63 * 64;
        if (windowed) {
            // qkv with fused window-partition gather (A = lnb, token space)
            launch_gemm(lnb, wb_qkv + (size_t)i * 442368, qkvb + i * 1152,
                        nullptr, qkvx, MPAD, 1152, 384, 0, 1, zpage, stream);
            relbias_mfma<32><<<dim3(NWIN * HEADS, 4), 256, 0, stream>>>(
                qkvx, rh, rw, Dh, Dw, WTOK, 27, 256);
            attn_mfma<WTOK, WS><<<dim3(NWIN * HEADS, 4), 256, 0, stream>>>(
                qkvx, Dh, Dw, attb);
            // proj with fused window-unpartition gather (A = attb window layout)
            launch_gemm_sk(attb, wb_pw + (size_t)i * 147456, P_pf,
                           NTOK, 384, 384, 4, 2, zpage, stream);
        } else {
            launch_gemm(lnb, wb_qkv + (size_t)i * 442368, qkvb + i * 1152,
                        nullptr, qkvx, NTOK, 1152, 384, 0, 0, zpage, stream);
            relbias_mfma<64><<<dim3(B_SZ * HEADS, 16), 256, 0, stream>>>(
                qkvx, rh, rw, Dh, Dw, 1024, 63, 1024);
            attn_mfma<1024, 32><<<dim3(B_SZ * HEADS, 16), 256, 0, stream>>>(
                qkvx, Dh, Dw, attb);
            launch_gemm_sk(attb, wb_pw + (size_t)i * 147456, P_pf,
                           NTOK, 384, 384, 4, 0, zpage, stream);
        }
        // proj epilogue + residual + ln2 (fused)
        epi_ln_kernel<<<NTOK, 64, 0, stream>>>(P_pf, pb + i * 384, nullptr, y, 1,
                                               n2w + i * 384, n2b + i * 384, lnb);
        launch_gemm(lnb, wb_f1 + (size_t)i * 589824, f1b + i * 1536,
                    nullptr, mlpb, NTOK, 1536, 384, 1, 0, zpage, stream);
        launch_gemm_sk(mlpb, wb_f2 + (size_t)i * 589824, P_pf,
                       NTOK, 384, 1536, 4, 0, zpage, stream);
        // fc2 epilogue + residual + next layer's ln1 (fused); last layer: no LN
        if (i < 5)
            epi_ln_kernel<<<NTOK, 64, 0, stream>>>(P_pf, f2b + i * 384, nullptr, y, 1,
                                                   n1w + (i + 1) * 384,
                                                   n1b + (i + 1) * 384, lnb);
        else
            epi_ln_kernel<<<NTOK, 64, 0, stream>>>(P_pf, f2b + i * 384, nullptr, y, 1,
                                                   nullptr, nullptr, nullptr);
    }

    {
        size_t tot = (size_t)B_SZ * 384 * 1024;
        out_transpose_kernel<<<(int)((tot + 255) / 256), 256, 0, stream>>>(y, out);
    }
}

// Round 7
// 836.480 us; speedup vs baseline: 11.5212x; 1.0275x over previous
//
#include <hip/hip_runtime.h>
#include <math.h>

// ---------------- constants ----------------
#define B_SZ 4
#define DIM 384
#define HEADS 6
#define HD 64
#define NTOK 4096          // B*32*32
#define WS 14
#define NWIN 36            // B * 9
#define WTOK 196           // 14*14
#define PWTOK 7056         // 36*196
#define MPAD 7168          // padded rows for windowed qkv GEMM (56*128)

typedef unsigned short u16;
typedef __bf16 bf16_t;
typedef bf16_t bf16x8 __attribute__((ext_vector_type(8)));
typedef float f32x4 __attribute__((ext_vector_type(4)));

__device__ __forceinline__ float bf2f(unsigned u) { return __uint_as_float(u << 16); }
__device__ __forceinline__ u16 f2bf(float f) {
    unsigned u = __float_as_uint(f);
    unsigned r = (u + 0x7fffu + ((u >> 16) & 1u)) >> 16;
    return (u16)r;
}

// async global->LDS, 16B per lane, wave-uniform LDS base + lane*16
__device__ __forceinline__ void ldsload16(const u16* g, u16* l) {
    __builtin_amdgcn_global_load_lds(
        (const __attribute__((address_space(1))) unsigned int*)g,
        (__attribute__((address_space(3))) unsigned int*)l, 16, 0, 0);
}

__device__ __forceinline__ int swz(int r) { return (r ^ (r >> 2)) & 3; }

// A-row gather: 0 = identity, 1 = window-partition (pad->zp), 2 = window-unpartition
__device__ __forceinline__ const u16* arow(const u16* A, int K, int m,
                                           int gather, const u16* zp) {
    if (gather == 1) {
        if (m >= PWTOK) return zp;
        int w = m / WTOK, wt = m - w * WTOK;
        int b = w / 9, r = w - b * 9;
        int wy = r / 3, wx = r - wy * 3;
        int iy = wt / WS, ix = wt - iy * WS;
        int gy = wy * WS + iy, gx = wx * WS + ix;
        if (gy >= 32 || gx >= 32) return zp;
        return A + (size_t)(b * 1024 + gy * 32 + gx) * (size_t)K;
    } else if (gather == 2) {
        int b = m >> 10, g = m & 1023;
        int gy = g >> 5, gx = g & 31;
        int wy = gy / WS, iy = gy - wy * WS;
        int wx = gx / WS, ix = gx - wx * WS;
        int w = b * 9 + wy * 3 + wx;
        return A + (size_t)(w * WTOK + iy * WS + ix) * (size_t)K;
    }
    return A + (size_t)m * (size_t)K;
}

// ---------------- all-weights fp32 -> bf16 convert (one dispatch) ------------
__global__ __launch_bounds__(256) void w2b_all_kernel(
        const float* __restrict__ p0, const float* __restrict__ p1,
        const float* __restrict__ p2, const float* __restrict__ p3,
        const float* __restrict__ p4, u16* __restrict__ d) {
    int i = blockIdx.x * 256 + threadIdx.x;
    const float* s; int off;
    if      (i <   294912) { s = p0; off = 0; }
    else if (i <  2949120) { s = p1; off = 294912; }
    else if (i <  3833856) { s = p2; off = 2949120; }
    else if (i <  7372800) { s = p3; off = 3833856; }
    else if (i < 10911744) { s = p4; off = 7372800; }
    else return;
    d[i] = f2bf(s[i - off]);
}

// ---------------- im2col (bf16 out) ----------------
__global__ __launch_bounds__(256) void im2col_kernel(const float* __restrict__ x,
                                                     u16* __restrict__ col) {
    size_t idx = (size_t)blockIdx.x * 256 + threadIdx.x;
    if (idx >= (size_t)NTOK * 768) return;
    int kk = (int)(idx % 768);
    int p  = (int)(idx / 768);
    int b  = p / 1024;
    int ph = (p % 1024) / 32;
    int pw = p % 32;
    int c = kk / 256;
    int r = kk % 256;
    int i = r / 16, j = r % 16;
    col[idx] = f2bf(x[(size_t)b * 3 * 512 * 512 + (size_t)c * 512 * 512 +
                      (size_t)(ph * 16 + i) * 512 + (pw * 16 + j)]);
}

// ---------------- bicubic pos embed -> posr table; also zeroes zpage ---------
__device__ inline float cubic_keys(float x) {
    x = fabsf(x);
    if (x <= 1.f) return ((1.5f * x - 2.5f) * x) * x + 1.f;
    if (x < 2.f)  return ((-0.5f * x + 2.5f) * x - 4.f) * x + 2.f;
    return 0.f;
}

__global__ __launch_bounds__(256) void pos_resize_kernel(const float* __restrict__ pe,
                                                         float* __restrict__ posr,
                                                         unsigned* __restrict__ zpage) {
    int idx = blockIdx.x * 256 + threadIdx.x;   // 1024*384
    if (idx < 512) zpage[idx] = 0u;
    if (idx >= 1024 * 384) return;
    int c = idx % 384;
    int g = idx / 384;
    int gy = g / 32, gx = g % 32;
    float wy[14], wx[14];
    float sy = (gy + 0.5f) * (14.f / 32.f) - 0.5f;
    float sx = (gx + 0.5f) * (14.f / 32.f) - 0.5f;
    float toty = 0.f, totx = 0.f;
    #pragma unroll
    for (int k = 0; k < 14; ++k) {
        wy[k] = cubic_keys(sy - (float)k); toty += wy[k];
        wx[k] = cubic_keys(sx - (float)k); totx += wx[k];
    }
    float val = 0.f;
    #pragma unroll 1
    for (int iy = 0; iy < 14; ++iy) {
        if (wy[iy] == 0.f) continue;
        float row = 0.f;
        for (int ix = 0; ix < 14; ++ix) {
            if (wx[ix] == 0.f) continue;
            row += wx[ix] * pe[(iy * 14 + ix) * 384 + c];
        }
        val += wy[iy] * row;
    }
    posr[idx] = val / (toty * totx);
}

// ---------------- fused split-K epilogue + residual + LN / NCHW-out ----------
// One wave per token. P has nsk slices of 4096*384 fp32.
__global__ __launch_bounds__(64) void epi_ln_kernel(const float* __restrict__ P,
        const float* __restrict__ bias, const float* __restrict__ posr,
        float* __restrict__ y, int addy, int nsk,
        const float* __restrict__ lw, const float* __restrict__ lb,
        u16* __restrict__ lnout, float* __restrict__ outT)
{
    int tok = blockIdx.x, t = threadIdx.x;
    size_t base = (size_t)tok * 384;
    float v[6];
    float s = 0.f;
    #pragma unroll
    for (int i = 0; i < 6; ++i) {
        int c = t + 64 * i;
        float val = bias[c];
        #pragma unroll 1
        for (int sk = 0; sk < nsk; ++sk)
            val += P[(size_t)sk * 1572864 + base + c];
        if (posr) val += posr[(size_t)(tok & 1023) * 384 + c];
        if (addy) val += y[base + c];
        v[i] = val; s += val;
    }
    if (outT) {   // final layer: write NCHW output directly, skip y/LN
        int b = tok >> 10, g = tok & 1023;
        #pragma unroll
        for (int i = 0; i < 6; ++i) {
            int c = t + 64 * i;
            outT[((size_t)(b * 384 + c)) * 1024 + g] = v[i];
        }
        return;
    }
    #pragma unroll
    for (int i = 0; i < 6; ++i) y[base + t + 64 * i] = v[i];
    if (!lnout) return;
    #pragma unroll
    for (int off = 32; off > 0; off >>= 1) s += __shfl_xor(s, off);
    float mean = s * (1.f / 384.f);
    float vs = 0.f;
    #pragma unroll
    for (int i = 0; i < 6; ++i) { float d = v[i] - mean; vs += d * d; }
    #pragma unroll
    for (int off = 32; off > 0; off >>= 1) vs += __shfl_xor(vs, off);
    float inv = rsqrtf(vs * (1.f / 384.f) + 1e-5f);
    u16* orow = lnout + base;
    #pragma unroll
    for (int i = 0; i < 6; ++i) {
        int c = t + 64 * i;
        orow[c] = f2bf((v[i] - mean) * inv * lw[c] + lb[c]);
    }
}

// ---------------- MFMA bf16 GEMM v2: BM=128, BN=64, BK=32, split-K, A-gather --
__global__ __launch_bounds__(256) void mfma_gemm2(
        const u16* __restrict__ A, const u16* __restrict__ Wt,
        const float* __restrict__ bias, const float* __restrict__ res,
        float* __restrict__ outf, u16* __restrict__ outb,
        float* __restrict__ outp,
        int M, int N, int K, int act, int ksplit,
        int gather, const u16* __restrict__ zpage)
{
    __shared__ u16 As[4096];   // 128 rows x 32 cols
    __shared__ u16 Bs[2048];   // 64 rows x 32 cols
    int t = threadIdx.x;
    int lane = t & 63, wave = t >> 6;
    int wm = (wave >> 1) * 64, wn = (wave & 1) * 32;
    int m0 = blockIdx.y * 128, n0 = blockIdx.x * 64;
    int ks = blockIdx.z * ksplit, ke = ks + ksplit;

    int r0 = t >> 2,        c0 = ((t & 3) ^ swz(t >> 2)) * 8;
    int r1 = 64 + (t >> 2), c1 = ((t & 3) ^ swz(64 + (t >> 2))) * 8;
    const u16* a0 = arow(A, K, m0 + r0, gather, zpage) + c0;
    const u16* a1 = arow(A, K, m0 + r1, gather, zpage) + c1;
    const u16* b0 = Wt + (size_t)(n0 + r0) * K + c0;
    u16* asd0 = &As[wave * 512];
    u16* asd1 = &As[2048 + wave * 512];
    u16* bsd0 = &Bs[wave * 512];

    f32x4 acc[4][2] = {};
    int row_a = wm + (lane & 15);
    int row_b = wn + (lane & 15);
    int lq = lane >> 4;

    for (int k0 = ks; k0 < ke; k0 += 32) {
        ldsload16(a0 + k0, asd0);
        ldsload16(a1 + k0, asd1);
        ldsload16(b0 + k0, bsd0);
        __syncthreads();
        bf16x8 af[4], bfr[2];
        #pragma unroll
        for (int i = 0; i < 4; ++i) {
            int r = row_a + i * 16;
            af[i] = *(const bf16x8*)&As[r * 32 + ((lq ^ swz(r)) * 8)];
        }
        #pragma unroll
        for (int j = 0; j < 2; ++j) {
            int r = row_b + j * 16;
            bfr[j] = *(const bf16x8*)&Bs[r * 32 + ((lq ^ swz(r)) * 8)];
        }
        #pragma unroll
        for (int i = 0; i < 4; ++i)
            #pragma unroll
            for (int j = 0; j < 2; ++j)
                acc[i][j] = __builtin_amdgcn_mfma_f32_16x16x32_bf16(
                    af[i], bfr[j], acc[i][j], 0, 0, 0);
        __syncthreads();
    }

    int colq = lane & 15, rowq = (lane >> 4) * 4;
    if (outp) {
        float* pp = outp + (size_t)blockIdx.z * M * N;
        #pragma unroll
        for (int i = 0; i < 4; ++i) {
            #pragma unroll
            for (int rr = 0; rr < 4; ++rr) {
                int m = m0 + wm + i * 16 + rowq + rr;
                size_t mo = (size_t)m * N;
                #pragma unroll
                for (int j = 0; j < 2; ++j) {
                    int n = n0 + wn + j * 16 + colq;
                    pp[mo + n] = acc[i][j][rr];
                }
            }
        }
        return;
    }
    #pragma unroll
    for (int i = 0; i < 4; ++i) {
        #pragma unroll
        for (int rr = 0; rr < 4; ++rr) {
            int m = m0 + wm + i * 16 + rowq + rr;
            size_t mo = (size_t)m * N;
            #pragma unroll
            for (int j = 0; j < 2; ++j) {
                int n = n0 + wn + j * 16 + colq;
                float v = acc[i][j][rr] + bias[n];
                if (res)  v += res[mo + n];
                if (act)  v = 0.5f * v * (1.f + erff(v * 0.70710678118654752f));
                if (outf) outf[mo + n] = v;
                if (outb) outb[mo + n] = f2bf(v);
            }
        }
    }
}

// ---------------- MFMA flash attention with fused rel-pos bias ---------------
// grid (units*HEADS, ceil(N/64)), block 256 (4 waves, 16 q each).
template<int N, int W>
__global__ __launch_bounds__(256) void attn_mfma(const u16* __restrict__ qkv,
        const float* __restrict__ rh, const float* __restrict__ rw,
        u16* __restrict__ outb)
{
    constexpr int JS = (W == 32) ? 64 : 32;   // padded table length
    constexpr int L  = (W == 32) ? 63 : 27;   // real table length
    constexpr int CTR = W - 1;
    __shared__ u16 KV[7168];   // Ks[0:2048] | Vt[2048:4608] | Pb[4608:7168]
    __shared__ u16 bhl[64 * 66];
    __shared__ u16 bwl[64 * 66];
    __shared__ u16 Qt[64 * 66];   // [ch][q], UNSCALED

    u16* Ks = KV;
    u16* Vt = KV + 2048;
    u16* Pb = KV + 4608;
    u16* Rt = KV;                 // prologue overlay, JS*72 <= 4608 u16

    int t = threadIdx.x, lane = t & 63, wave = t >> 6;
    int quad = lane >> 4, l15 = lane & 15;
    int uh = blockIdx.x, qb0 = blockIdx.y * 64;
    int h = uh % HEADS, u = uh / HEADS;
    size_t tbase = (size_t)u * N;

    // ---- stage Q^T (unscaled) ----
    {
        int q = t & 63, ch0 = (t >> 6) * 16;
        int qc = qb0 + q;
        int qcc = (qc < N) ? qc : (N - 1);
        const u16* qp = qkv + (tbase + qcc) * 1152 + h * 64 + ch0;
        uint4 a = *(const uint4*)qp;
        uint4 b = *(const uint4*)(qp + 8);
        u16 vals[16];
        *(uint4*)vals = a; *(uint4*)(vals + 8) = b;
        #pragma unroll
        for (int c = 0; c < 16; ++c)
            Qt[(ch0 + c) * 66 + q] = (qc < N) ? vals[c] : (u16)0;
    }

    // ---- fused rel-pos bias: D[q][j] = sum_c Q[q][c]*R[j][c], both tables ----
    #pragma unroll
    for (int table = 0; table < 2; ++table) {
        __syncthreads();   // Qt visible (t=0); Rt free of prev table's readers (t=1)
        const float* tab = table ? rw : rh;
        for (int idx = t; idx < JS * 8; idx += 256) {
            int j = idx >> 3, cc0 = (idx & 7) * 8;
            u16 tmp[8];
            if (j < L) {
                const float* src = tab + (size_t)j * 64 + cc0;
                #pragma unroll
                for (int c = 0; c < 8; ++c) tmp[c] = f2bf(src[c]);
            } else {
                #pragma unroll
                for (int c = 0; c < 8; ++c) tmp[c] = 0;
            }
            *(uint4*)&Rt[j * 72 + cc0] = *(uint4*)tmp;
        }
        __syncthreads();
        if (wave < JS / 16) {
            int jt = wave;
            bf16x8 af0 = *(const bf16x8*)&Rt[(jt * 16 + l15) * 72 + quad * 8];
            bf16x8 af1 = *(const bf16x8*)&Rt[(jt * 16 + l15) * 72 + 32 + quad * 8];
            u16* dst = table ? bwl : bhl;
            #pragma unroll
            for (int qt = 0; qt < 4; ++qt) {
                bf16x8 qf0, qf1;
                u16* p0 = (u16*)&qf0; u16* p1 = (u16*)&qf1;
                #pragma unroll
                for (int z = 0; z < 8; ++z) {
                    p0[z] = Qt[(quad * 8 + z) * 66 + qt * 16 + l15];
                    p1[z] = Qt[(32 + quad * 8 + z) * 66 + qt * 16 + l15];
                }
                f32x4 acc = {};
                acc = __builtin_amdgcn_mfma_f32_16x16x32_bf16(af0, qf0, acc, 0, 0, 0);
                acc = __builtin_amdgcn_mfma_f32_16x16x32_bf16(af1, qf1, acc, 0, 0, 0);
                #pragma unroll
                for (int r = 0; r < 4; ++r)
                    dst[(qt * 16 + l15) * 66 + jt * 16 + quad * 4 + r] = f2bf(acc[r]);
            }
        }
    }
    __syncthreads();   // bhl/bwl ready; Rt readers done before K-stage overwrites

    // Q^T B-frags (loop-invariant, unscaled; scale applied to scores)
    bf16x8 qf[2];
    #pragma unroll
    for (int hc = 0; hc < 2; ++hc) {
        u16* qv = (u16*)&qf[hc];
        #pragma unroll
        for (int j = 0; j < 8; ++j)
            qv[j] = Qt[(hc * 32 + quad * 8 + j) * 66 + wave * 16 + l15];
    }
    int qme = wave * 16 + l15;
    int qq = qb0 + qme; if (qq >= N) qq = N - 1;
    int qh = qq / W, qw = qq - qh * W;
    float bwreg[2][4];
    if constexpr (W == 32) {
        #pragma unroll
        for (int kc2 = 0; kc2 < 2; ++kc2)
            #pragma unroll
            for (int r = 0; r < 4; ++r) {
                int keyl = kc2 * 16 + quad * 4 + r;
                bwreg[kc2][r] = bf2f(bwl[qme * 66 + (qw - keyl + CTR)]);
            }
    }

    f32x4 of[4] = {};
    float lsum = 0.f;
    constexpr int NKT = (N + 31) / 32;

    for (int kt = 0; kt < NKT; ++kt) {
        int kb = kt * 32;
        __syncthreads();
        {
            int p = wave * 64 + lane;
            int key = p >> 3;
            int c8 = (p & 7) ^ (key & 7);
            int kc = kb + key; if (kc >= N) kc = N - 1;
            ldsload16(qkv + (tbase + kc) * 1152 + 384 + h * 64 + c8 * 8,
                      &Ks[wave * 512]);
        }
        {
            int k = t & 31, ch0 = (t >> 5) * 8;
            int kc = kb + k; if (kc >= N) kc = N - 1;
            const u16* vp = qkv + (tbase + kc) * 1152 + 768 + h * 64 + ch0;
            uint4 vv = *(const uint4*)vp;
            u16 tmp[8]; *(uint4*)tmp = vv;
            #pragma unroll
            for (int c = 0; c < 8; ++c) Vt[(ch0 + c) * 40 + k] = tmp[c];
        }
        __syncthreads();

        f32x4 st[2] = {};
        #pragma unroll
        for (int hc = 0; hc < 2; ++hc) {
            #pragma unroll
            for (int kc2 = 0; kc2 < 2; ++kc2) {
                int key = kc2 * 16 + l15;
                int c8 = hc * 4 + quad;
                int p = key * 8 + (c8 ^ (key & 7));
                bf16x8 kf = *(const bf16x8*)&Ks[p * 8];
                st[kc2] = __builtin_amdgcn_mfma_f32_16x16x32_bf16(
                    kf, qf[hc], st[kc2], 0, 0, 0);
            }
        }
        float bh_t = 0.f;
        if constexpr (W == 32) bh_t = bf2f(bhl[qme * 66 + (qh - (kb >> 5) + CTR)]);
        #pragma unroll
        for (int kc2 = 0; kc2 < 2; ++kc2) {
            #pragma unroll
            for (int r = 0; r < 4; ++r) {
                int keyl = kc2 * 16 + quad * 4 + r;
                int key = kb + keyl;
                float b;
                if constexpr (W == 32) {
                    b = bh_t + bwreg[kc2][r];
                } else {
                    int kk2 = (key < N) ? key : (N - 1);
                    int kh = kk2 / W, kw = kk2 - kh * W;
                    b = bf2f(bhl[qme * 66 + (qh - kh + CTR)]) +
                        bf2f(bwl[qme * 66 + (qw - kw + CTR)]);
                }
                float p = __expf(fmaf(st[kc2][r], 0.125f, b));
                if (key >= N) p = 0.f;
                lsum += p;
                Pb[wave * 640 + l15 * 40 + keyl] = f2bf(p);
            }
        }
        bf16x8 pf = *(const bf16x8*)&Pb[wave * 640 + l15 * 40 + quad * 8];
        #pragma unroll
        for (int ca = 0; ca < 4; ++ca) {
            bf16x8 vf = *(const bf16x8*)&Vt[(ca * 16 + l15) * 40 + quad * 8];
            of[ca] = __builtin_amdgcn_mfma_f32_16x16x32_bf16(
                vf, pf, of[ca], 0, 0, 0);
        }
    }

    lsum += __shfl_xor(lsum, 16);
    lsum += __shfl_xor(lsum, 32);
    float inv = 1.f / lsum;
    int q = qb0 + qme;
    if (q < N) {
        u16* op = outb + (tbase + q) * 384 + h * 64;
        #pragma unroll
        for (int ca = 0; ca < 4; ++ca)
            #pragma unroll
            for (int r = 0; r < 4; ++r)
                op[ca * 16 + quad * 4 + r] = f2bf(of[ca][r] * inv);
    }
}

// ---------------- host helpers ----------------
static inline void launch_gemm(const u16* A, const u16* W, const float* bias,
                               float* outf, u16* outb,
                               int M, int N, int K, int act, int gather,
                               const u16* zp, hipStream_t s) {
    dim3 g(N / 64, M / 128, 1);
    mfma_gemm2<<<g, 256, 0, s>>>(A, W, bias, nullptr, outf, outb, nullptr,
                                 M, N, K, act, K, gather, zp);
}

static inline void launch_gemm_sk(const u16* A, const u16* W, float* P,
                                  int M, int N, int K, int SK, int gather,
                                  const u16* zp, hipStream_t s) {
    dim3 g(N / 64, M / 128, SK);
    mfma_gemm2<<<g, 256, 0, s>>>(A, W, nullptr, nullptr, nullptr, nullptr, P,
                                 M, N, K, 0, K / SK, gather, zp);
}

extern "C" void kernel_launch(void* const* d_in, const int* in_sizes, int n_in,
                              void* d_out, int out_size, void* d_ws, size_t ws_size,
                              hipStream_t stream) {
    const float* x      = (const float*)d_in[0];
    const float* patchw = (const float*)d_in[1];
    const float* patchb = (const float*)d_in[2];
    const float* pos    = (const float*)d_in[3];
    const float* n1w    = (const float*)d_in[4];
    const float* n1b    = (const float*)d_in[5];
    const float* qkvw   = (const float*)d_in[6];
    const float* qkvb   = (const float*)d_in[7];
    const float* pw     = (const float*)d_in[8];
    const float* pb     = (const float*)d_in[9];
    const float* n2w    = (const float*)d_in[10];
    const float* n2b    = (const float*)d_in[11];
    const float* f1w    = (const float*)d_in[12];
    const float* f1b    = (const float*)d_in[13];
    const float* f2w    = (const float*)d_in[14];
    const float* f2b    = (const float*)d_in[15];
    const float* rph    = (const float*)d_in[16];
    const float* rpw    = (const float*)d_in[17];
    float* out = (float*)d_out;

    // workspace layout. Split-K partial overlays cover only dead buffers:
    //  P_patch = attb.. (attb+mlpb dead during patch GEMM)
    //  P_pf    = qkvx.. (qkvx + reserve dead during proj/fc2; y/lnb/attb/mlpb outside)
    float* y   = (float*)d_ws;                  // 1,572,864 f32
    u16* attb  = (u16*)(y + 1572864);           // 2,752,512 u16
    u16* mlpb  = attb + 2752512;                // 6,291,456 u16
    u16* lnb   = mlpb + 6291456;                // 1,572,864 u16
    u16* qkvx  = lnb + 1572864;                 // 8,257,536 u16
    u16* rsrv  = qkvx + 8257536;                // 4,325,376 u16 (P_pf overlay tail)
    u16* wb    = rsrv + 4325376;                // 10,911,744 u16 weights
    float* posr = (float*)(wb + 10911744);      //   393,216 f32
    u16* zpage = (u16*)(posr + 393216);         //     1,024 u16 (zeroed)

    u16* colb  = rsrv;                          // overlay: im2col (6.3MB > 8.65MB rsrv OK? 6,291,456 B <= 8,650,752 B)
    float* P_patch = (float*)attb;              // 2 slices = 12.6MB over attb+mlpb
    float* P_pf    = (float*)qkvx;              // up to 4 slices = 25.2MB over qkvx+rsrv

    u16* wb_patch = wb;
    u16* wb_qkv   = wb + 294912;
    u16* wb_pw    = wb + 2949120;
    u16* wb_f1    = wb + 3833856;
    u16* wb_f2    = wb + 7372800;

    w2b_all_kernel<<<(10911744 + 255) / 256, 256, 0, stream>>>(
        patchw, qkvw, pw, f1w, f2w, wb);
    pos_resize_kernel<<<1536, 256, 0, stream>>>(pos, posr, (unsigned*)zpage);

    {
        size_t tot = (size_t)NTOK * 768;
        im2col_kernel<<<(int)((tot + 255) / 256), 256, 0, stream>>>(x, colb);
        launch_gemm_sk(colb, wb_patch, P_patch, NTOK, 384, 768, 2, 0, zpage, stream);
        // patch epilogue + pos-embed + layer-0 ln1 (fused)
        epi_ln_kernel<<<NTOK, 64, 0, stream>>>(P_patch, patchb, posr, y, 0, 2,
                                               n1w, n1b, lnb, nullptr);
    }

    for (int i = 0; i < 6; ++i) {
        bool windowed = (i == 0 || i == 1 || i == 3 || i == 4);
        const float* rh = rph + (size_t)i * 63 * 64;
        const float* rw = rpw + (size_t)i * 63 * 64;
        if (windowed) {
            launch_gemm(lnb, wb_qkv + (size_t)i * 442368, qkvb + i * 1152,
                        nullptr, qkvx, MPAD, 1152, 384, 0, 1, zpage, stream);
            attn_mfma<WTOK, WS><<<dim3(NWIN * HEADS, 4), 256, 0, stream>>>(
                qkvx, rh, rw, attb);
            launch_gemm_sk(attb, wb_pw + (size_t)i * 147456, P_pf,
                           NTOK, 384, 384, 2, 2, zpage, stream);
        } else {
            launch_gemm(lnb, wb_qkv + (size_t)i * 442368, qkvb + i * 1152,
                        nullptr, qkvx, NTOK, 1152, 384, 0, 0, zpage, stream);
            attn_mfma<1024, 32><<<dim3(B_SZ * HEADS, 16), 256, 0, stream>>>(
                qkvx, rh, rw, attb);
            launch_gemm_sk(attb, wb_pw + (size_t)i * 147456, P_pf,
                           NTOK, 384, 384, 2, 0, zpage, stream);
        }
        // proj epilogue + residual + ln2 (fused)
        epi_ln_kernel<<<NTOK, 64, 0, stream>>>(P_pf, pb + i * 384, nullptr, y, 1, 2,
                                               n2w + i * 384, n2b + i * 384, lnb,
                                               nullptr);
        launch_gemm(lnb, wb_f1 + (size_t)i * 589824, f1b + i * 1536,
                    nullptr, mlpb, NTOK, 1536, 384, 1, 0, zpage, stream);
        launch_gemm_sk(mlpb, wb_f2 + (size_t)i * 589824, P_pf,
                       NTOK, 384, 1536, 4, 0, zpage, stream);
        // fc2 epilogue + residual + next ln1; last layer writes NCHW out directly
        if (i < 5)
            epi_ln_kernel<<<NTOK, 64, 0, stream>>>(P_pf, f2b + i * 384, nullptr, y,
                                                   1, 4, n1w + (i + 1) * 384,
                                                   n1b + (i + 1) * 384, lnb, nullptr);
        else
            epi_ln_kernel<<<NTOK, 64, 0, stream>>>(P_pf, f2b + i * 384, nullptr, y,
                                                   1, 4, nullptr, nullptr, nullptr,
                                                   out);
    }
}

// Round 8
// 797.800 us; speedup vs baseline: 12.0798x; 1.0485x over previous
//
#include <hip/hip_runtime.h>
#include <math.h>

// ---------------- constants ----------------
#define B_SZ 4
#define DIM 384
#define HEADS 6
#define HD 64
#define NTOK 4096          // B*32*32
#define WS 14
#define NWIN 36            // B * 9
#define WTOK 196           // 14*14

typedef unsigned short u16;
typedef __bf16 bf16_t;
typedef bf16_t bf16x8 __attribute__((ext_vector_type(8)));
typedef float f32x4 __attribute__((ext_vector_type(4)));

__device__ __forceinline__ float bf2f(unsigned u) { return __uint_as_float(u << 16); }
__device__ __forceinline__ u16 f2bf(float f) {
    unsigned u = __float_as_uint(f);
    unsigned r = (u + 0x7fffu + ((u >> 16) & 1u)) >> 16;
    return (u16)r;
}

// async global->LDS, 16B per lane, wave-uniform LDS base + lane*16
__device__ __forceinline__ void ldsload16(const u16* g, u16* l) {
    __builtin_amdgcn_global_load_lds(
        (const __attribute__((address_space(1))) unsigned int*)g,
        (__attribute__((address_space(3))) unsigned int*)l, 16, 0, 0);
}

__device__ __forceinline__ int swz(int r) { return (r ^ (r >> 2)) & 3; }

// ---------------- all-weights + qkv-bias fp32 -> bf16 (one dispatch) ---------
__global__ __launch_bounds__(256) void w2b_all_kernel(
        const float* __restrict__ p0, const float* __restrict__ p1,
        const float* __restrict__ p2, const float* __restrict__ p3,
        const float* __restrict__ p4, const float* __restrict__ p5,
        u16* __restrict__ d) {
    int i = blockIdx.x * 256 + threadIdx.x;
    const float* s; int off;
    if      (i <   294912) { s = p0; off = 0; }
    else if (i <  2949120) { s = p1; off = 294912; }
    else if (i <  3833856) { s = p2; off = 2949120; }
    else if (i <  7372800) { s = p3; off = 3833856; }
    else if (i < 10911744) { s = p4; off = 7372800; }
    else if (i < 10918656) { s = p5; off = 10911744; }
    else return;
    d[i] = f2bf(s[i - off]);
}

// ---------------- im2col (bf16 out) ----------------
__global__ __launch_bounds__(256) void im2col_kernel(const float* __restrict__ x,
                                                     u16* __restrict__ col) {
    size_t idx = (size_t)blockIdx.x * 256 + threadIdx.x;
    if (idx >= (size_t)NTOK * 768) return;
    int kk = (int)(idx % 768);
    int p  = (int)(idx / 768);
    int b  = p / 1024;
    int ph = (p % 1024) / 32;
    int pw = p % 32;
    int c = kk / 256;
    int r = kk % 256;
    int i = r / 16, j = r % 16;
    col[idx] = f2bf(x[(size_t)b * 3 * 512 * 512 + (size_t)c * 512 * 512 +
                      (size_t)(ph * 16 + i) * 512 + (pw * 16 + j)]);
}

// ---------------- bicubic pos embed -> posr table ----------------
__device__ inline float cubic_keys(float x) {
    x = fabsf(x);
    if (x <= 1.f) return ((1.5f * x - 2.5f) * x) * x + 1.f;
    if (x < 2.f)  return ((-0.5f * x + 2.5f) * x - 4.f) * x + 2.f;
    return 0.f;
}

__global__ __launch_bounds__(256) void pos_resize_kernel(const float* __restrict__ pe,
                                                         float* __restrict__ posr) {
    int idx = blockIdx.x * 256 + threadIdx.x;   // 1024*384
    if (idx >= 1024 * 384) return;
    int c = idx % 384;
    int g = idx / 384;
    int gy = g / 32, gx = g % 32;
    float wy[14], wx[14];
    float sy = (gy + 0.5f) * (14.f / 32.f) - 0.5f;
    float sx = (gx + 0.5f) * (14.f / 32.f) - 0.5f;
    float toty = 0.f, totx = 0.f;
    #pragma unroll
    for (int k = 0; k < 14; ++k) {
        wy[k] = cubic_keys(sy - (float)k); toty += wy[k];
        wx[k] = cubic_keys(sx - (float)k); totx += wx[k];
    }
    float val = 0.f;
    #pragma unroll 1
    for (int iy = 0; iy < 14; ++iy) {
        if (wy[iy] == 0.f) continue;
        float row = 0.f;
        for (int ix = 0; ix < 14; ++ix) {
            if (wx[ix] == 0.f) continue;
            row += wx[ix] * pe[(iy * 14 + ix) * 384 + c];
        }
        val += wy[iy] * row;
    }
    posr[idx] = val / (toty * totx);
}

// ---------------- fused split-K epilogue + residual + LN / NCHW-out ----------
__global__ __launch_bounds__(64) void epi_ln_kernel(const float* __restrict__ P,
        const float* __restrict__ bias, const float* __restrict__ posr,
        float* __restrict__ y, int addy, int nsk,
        const float* __restrict__ lw, const float* __restrict__ lb,
        u16* __restrict__ lnout, float* __restrict__ outT)
{
    int tok = blockIdx.x, t = threadIdx.x;
    size_t base = (size_t)tok * 384;
    float v[6];
    float s = 0.f;
    #pragma unroll
    for (int i = 0; i < 6; ++i) {
        int c = t + 64 * i;
        float val = bias[c];
        #pragma unroll 1
        for (int sk = 0; sk < nsk; ++sk)
            val += P[(size_t)sk * 1572864 + base + c];
        if (posr) val += posr[(size_t)(tok & 1023) * 384 + c];
        if (addy) val += y[base + c];
        v[i] = val; s += val;
    }
    if (outT) {   // final layer: write NCHW output directly
        int b = tok >> 10, g = tok & 1023;
        #pragma unroll
        for (int i = 0; i < 6; ++i) {
            int c = t + 64 * i;
            outT[((size_t)(b * 384 + c)) * 1024 + g] = v[i];
        }
        return;
    }
    #pragma unroll
    for (int i = 0; i < 6; ++i) y[base + t + 64 * i] = v[i];
    if (!lnout) return;
    #pragma unroll
    for (int off = 32; off > 0; off >>= 1) s += __shfl_xor(s, off);
    float mean = s * (1.f / 384.f);
    float vs = 0.f;
    #pragma unroll
    for (int i = 0; i < 6; ++i) { float d = v[i] - mean; vs += d * d; }
    #pragma unroll
    for (int off = 32; off > 0; off >>= 1) vs += __shfl_xor(vs, off);
    float inv = rsqrtf(vs * (1.f / 384.f) + 1e-5f);
    u16* orow = lnout + base;
    #pragma unroll
    for (int i = 0; i < 6; ++i) {
        int c = t + 64 * i;
        orow[c] = f2bf((v[i] - mean) * inv * lw[c] + lb[c]);
    }
}

// ---------------- MFMA bf16 GEMM v3: BM=128, BN=64, BK=64, split-K -----------
__global__ __launch_bounds__(256) void mfma_gemm3(
        const u16* __restrict__ A, const u16* __restrict__ Wt,
        const float* __restrict__ bias,
        float* __restrict__ outf, u16* __restrict__ outb,
        float* __restrict__ outp,
        int M, int N, int K, int act, int ksplit)
{
    __shared__ u16 As[8192];   // two halves of 128 rows x 32 cols
    __shared__ u16 Bs[4096];   // two halves of 64 rows x 32 cols
    int t = threadIdx.x;
    int lane = t & 63, wave = t >> 6;
    int wm = (wave >> 1) * 64, wn = (wave & 1) * 32;
    int m0 = blockIdx.y * 128, n0 = blockIdx.x * 64;
    int ks = blockIdx.z * ksplit, ke = ks + ksplit;

    int r0 = t >> 2,        c0 = ((t & 3) ^ swz(t >> 2)) * 8;
    int r1 = 64 + (t >> 2), c1 = ((t & 3) ^ swz(64 + (t >> 2))) * 8;
    const u16* a0 = A + (size_t)(m0 + r0) * K + c0;
    const u16* a1 = A + (size_t)(m0 + r1) * K + c1;
    const u16* b0 = Wt + (size_t)(n0 + r0) * K + c0;
    u16* asd0 = &As[wave * 512];
    u16* asd1 = &As[2048 + wave * 512];
    u16* bsd0 = &Bs[wave * 512];

    f32x4 acc[4][2] = {};
    int row_a = wm + (lane & 15);
    int row_b = wn + (lane & 15);
    int lq = lane >> 4;

    for (int k0 = ks; k0 < ke; k0 += 64) {
        ldsload16(a0 + k0, asd0);
        ldsload16(a1 + k0, asd1);
        ldsload16(b0 + k0, bsd0);
        ldsload16(a0 + k0 + 32, asd0 + 4096);
        ldsload16(a1 + k0 + 32, asd1 + 4096);
        ldsload16(b0 + k0 + 32, bsd0 + 2048);
        __syncthreads();
        #pragma unroll
        for (int hf = 0; hf < 2; ++hf) {
            bf16x8 af[4], bfr[2];
            #pragma unroll
            for (int i = 0; i < 4; ++i) {
                int r = row_a + i * 16;
                af[i] = *(const bf16x8*)&As[hf * 4096 + r * 32 + ((lq ^ swz(r)) * 8)];
            }
            #pragma unroll
            for (int j = 0; j < 2; ++j) {
                int r = row_b + j * 16;
                bfr[j] = *(const bf16x8*)&Bs[hf * 2048 + r * 32 + ((lq ^ swz(r)) * 8)];
            }
            #pragma unroll
            for (int i = 0; i < 4; ++i)
                #pragma unroll
                for (int j = 0; j < 2; ++j)
                    acc[i][j] = __builtin_amdgcn_mfma_f32_16x16x32_bf16(
                        af[i], bfr[j], acc[i][j], 0, 0, 0);
        }
        __syncthreads();
    }

    int colq = lane & 15, rowq = (lane >> 4) * 4;
    if (outp) {
        float* pp = outp + (size_t)blockIdx.z * M * N;
        #pragma unroll
        for (int i = 0; i < 4; ++i) {
            #pragma unroll
            for (int rr = 0; rr < 4; ++rr) {
                int m = m0 + wm + i * 16 + rowq + rr;
                size_t mo = (size_t)m * N;
                #pragma unroll
                for (int j = 0; j < 2; ++j) {
                    int n = n0 + wn + j * 16 + colq;
                    pp[mo + n] = acc[i][j][rr];
                }
            }
        }
        return;
    }
    #pragma unroll
    for (int i = 0; i < 4; ++i) {
        #pragma unroll
        for (int rr = 0; rr < 4; ++rr) {
            int m = m0 + wm + i * 16 + rowq + rr;
            size_t mo = (size_t)m * N;
            #pragma unroll
            for (int j = 0; j < 2; ++j) {
                int n = n0 + wn + j * 16 + colq;
                float v = acc[i][j][rr] + bias[n];
                if (act)  v = 0.5f * v * (1.f + erff(v * 0.70710678118654752f));
                if (outf) outf[mo + n] = v;
                if (outb) outb[mo + n] = f2bf(v);
            }
        }
    }
}

// ---------------- MFMA flash attention, fused rel-pos bias + window gather ---
// grid (units*HEADS, ceil(N/64)), block 256 (4 waves, 16 q each).
// W==32: global (qkv token layout, N=1024). W==14: windowed — qkv token layout,
// window mapping computed in-kernel, padded positions read qkb bias row,
// output written directly in token layout (no unpartition).
template<int N, int W>
__global__ __launch_bounds__(256) void attn_mfma(const u16* __restrict__ qkv,
        const u16* __restrict__ qkb, const float* __restrict__ rh,
        const float* __restrict__ rw, u16* __restrict__ outb)
{
    constexpr int JS = (W == 32) ? 64 : 32;   // padded table length
    constexpr int L  = (W == 32) ? 63 : 27;   // real table length
    constexpr int CTR = W - 1;
    __shared__ u16 KV[7168];   // Ks[0:2048] | Vt[2048:4608] | Pb[4608:7168]
    __shared__ u16 bhl[64 * 66];
    __shared__ u16 bwl[64 * 66];
    __shared__ u16 Qt[64 * 66];   // [ch][q], UNSCALED

    u16* Ks = KV;
    u16* Vt = KV + 2048;
    u16* Pb = KV + 4608;
    u16* Rt = KV;                 // prologue overlay, JS*72 <= 4608 u16

    int t = threadIdx.x, lane = t & 63, wave = t >> 6;
    int quad = lane >> 4, l15 = lane & 15;
    int uh = blockIdx.x, qb0 = blockIdx.y * 64;
    int h = uh % HEADS, u = uh / HEADS;
    size_t tbase = (size_t)u * 1024;   // only used for W==32 (u = batch)
    // window decode (W==14): u = window index
    int wb_ = u / 9, wr = u - wb_ * 9;
    int wy = wr / 3, wx = wr - wy * 3;

    // map window-local token -> qkv row pointer (or bias row)
    auto rowptr = [&](int lq) -> const u16* {
        if constexpr (W == 32) {
            return qkv + (tbase + lq) * 1152;
        } else {
            int iy = lq / WS, ix = lq - iy * WS;
            int gy = wy * WS + iy, gx = wx * WS + ix;
            if (gy < 32 || gx < 32) {
                if (gy < 32 && gx < 32)
                    return qkv + (size_t)(wb_ * 1024 + gy * 32 + gx) * 1152;
            }
            return qkb;
        }
    };

    // ---- stage Q^T (unscaled) ----
    {
        int q = t & 63, ch0 = (t >> 6) * 16;
        int qc = qb0 + q; if (qc >= N) qc = N - 1;
        const u16* qp = rowptr(qc) + h * 64 + ch0;
        uint4 a = *(const uint4*)qp;
        uint4 b = *(const uint4*)(qp + 8);
        u16 vals[16];
        *(uint4*)vals = a; *(uint4*)(vals + 8) = b;
        #pragma unroll
        for (int c = 0; c < 16; ++c)
            Qt[(ch0 + c) * 66 + q] = ((qb0 + q) < N) ? vals[c] : (u16)0;
    }

    // ---- fused rel-pos bias D = Q . R^T (both tables) ----
    #pragma unroll
    for (int table = 0; table < 2; ++table) {
        __syncthreads();
        const float* tab = table ? rw : rh;
        for (int idx = t; idx < JS * 8; idx += 256) {
            int j = idx >> 3, cc0 = (idx & 7) * 8;
            u16 tmp[8];
            if (j < L) {
                const float* src = tab + (size_t)j * 64 + cc0;
                #pragma unroll
                for (int c = 0; c < 8; ++c) tmp[c] = f2bf(src[c]);
            } else {
                #pragma unroll
                for (int c = 0; c < 8; ++c) tmp[c] = 0;
            }
            *(uint4*)&Rt[j * 72 + cc0] = *(uint4*)tmp;
        }
        __syncthreads();
        if (wave < JS / 16) {
            int jt = wave;
            bf16x8 af0 = *(const bf16x8*)&Rt[(jt * 16 + l15) * 72 + quad * 8];
            bf16x8 af1 = *(const bf16x8*)&Rt[(jt * 16 + l15) * 72 + 32 + quad * 8];
            u16* dst = table ? bwl : bhl;
            #pragma unroll
            for (int qt = 0; qt < 4; ++qt) {
                bf16x8 qf0, qf1;
                u16* p0 = (u16*)&qf0; u16* p1 = (u16*)&qf1;
                #pragma unroll
                for (int z = 0; z < 8; ++z) {
                    p0[z] = Qt[(quad * 8 + z) * 66 + qt * 16 + l15];
                    p1[z] = Qt[(32 + quad * 8 + z) * 66 + qt * 16 + l15];
                }
                f32x4 acc = {};
                acc = __builtin_amdgcn_mfma_f32_16x16x32_bf16(af0, qf0, acc, 0, 0, 0);
                acc = __builtin_amdgcn_mfma_f32_16x16x32_bf16(af1, qf1, acc, 0, 0, 0);
                #pragma unroll
                for (int r = 0; r < 4; ++r)
                    dst[(qt * 16 + l15) * 66 + jt * 16 + quad * 4 + r] = f2bf(acc[r]);
            }
        }
    }
    __syncthreads();

    // Q^T B-frags (loop-invariant; scale applied to scores)
    bf16x8 qf[2];
    #pragma unroll
    for (int hc = 0; hc < 2; ++hc) {
        u16* qv = (u16*)&qf[hc];
        #pragma unroll
        for (int j = 0; j < 8; ++j)
            qv[j] = Qt[(hc * 32 + quad * 8 + j) * 66 + wave * 16 + l15];
    }
    int qme = wave * 16 + l15;
    int qq = qb0 + qme; if (qq >= N) qq = N - 1;
    int qh = qq / W, qw = qq - qh * W;
    float bwreg[2][4];
    if constexpr (W == 32) {
        #pragma unroll
        for (int kc2 = 0; kc2 < 2; ++kc2)
            #pragma unroll
            for (int r = 0; r < 4; ++r) {
                int keyl = kc2 * 16 + quad * 4 + r;
                bwreg[kc2][r] = bf2f(bwl[qme * 66 + (qw - keyl + CTR)]);
            }
    }

    f32x4 of[4] = {};
    float lsum = 0.f;
    constexpr int NKT = (N + 31) / 32;

    for (int kt = 0; kt < NKT; ++kt) {
        int kb = kt * 32;
        __syncthreads();
        {
            int p = wave * 64 + lane;
            int key = p >> 3;
            int c8 = (p & 7) ^ (key & 7);
            int kc = kb + key; if (kc >= N) kc = N - 1;
            ldsload16(rowptr(kc) + 384 + h * 64 + c8 * 8, &Ks[wave * 512]);
        }
        {
            int k = t & 31, ch0 = (t >> 5) * 8;
            int kc = kb + k; if (kc >= N) kc = N - 1;
            const u16* vp = rowptr(kc) + 768 + h * 64 + ch0;
            uint4 vv = *(const uint4*)vp;
            u16 tmp[8]; *(uint4*)tmp = vv;
            #pragma unroll
            for (int c = 0; c < 8; ++c) Vt[(ch0 + c) * 40 + k] = tmp[c];
        }
        __syncthreads();

        f32x4 st[2] = {};
        #pragma unroll
        for (int hc = 0; hc < 2; ++hc) {
            #pragma unroll
            for (int kc2 = 0; kc2 < 2; ++kc2) {
                int key = kc2 * 16 + l15;
                int c8 = hc * 4 + quad;
                int p = key * 8 + (c8 ^ (key & 7));
                bf16x8 kf = *(const bf16x8*)&Ks[p * 8];
                st[kc2] = __builtin_amdgcn_mfma_f32_16x16x32_bf16(
                    kf, qf[hc], st[kc2], 0, 0, 0);
            }
        }
        float bh_t = 0.f;
        if constexpr (W == 32) bh_t = bf2f(bhl[qme * 66 + (qh - (kb >> 5) + CTR)]);
        #pragma unroll
        for (int kc2 = 0; kc2 < 2; ++kc2) {
            #pragma unroll
            for (int r = 0; r < 4; ++r) {
                int keyl = kc2 * 16 + quad * 4 + r;
                int key = kb + keyl;
                float b;
                if constexpr (W == 32) {
                    b = bh_t + bwreg[kc2][r];
                } else {
                    int kk2 = (key < N) ? key : (N - 1);
                    int kh = kk2 / W, kw = kk2 - kh * W;
                    b = bf2f(bhl[qme * 66 + (qh - kh + CTR)]) +
                        bf2f(bwl[qme * 66 + (qw - kw + CTR)]);
                }
                float p = __expf(fmaf(st[kc2][r], 0.125f, b));
                if (key >= N) p = 0.f;
                lsum += p;
                Pb[wave * 640 + l15 * 40 + keyl] = f2bf(p);
            }
        }
        bf16x8 pf = *(const bf16x8*)&Pb[wave * 640 + l15 * 40 + quad * 8];
        #pragma unroll
        for (int ca = 0; ca < 4; ++ca) {
            bf16x8 vf = *(const bf16x8*)&Vt[(ca * 16 + l15) * 40 + quad * 8];
            of[ca] = __builtin_amdgcn_mfma_f32_16x16x32_bf16(
                vf, pf, of[ca], 0, 0, 0);
        }
    }

    lsum += __shfl_xor(lsum, 16);
    lsum += __shfl_xor(lsum, 32);
    float inv = 1.f / lsum;
    int q = qb0 + qme;
    if (q < N) {
        u16* op;
        if constexpr (W == 32) {
            op = outb + (tbase + q) * 384 + h * 64;
        } else {
            int iy = q / WS, ix = q - iy * WS;
            int gy = wy * WS + iy, gx = wx * WS + ix;
            if (gy >= 32 || gx >= 32) return;   // padded query: discard
            op = outb + (size_t)(wb_ * 1024 + gy * 32 + gx) * 384 + h * 64;
        }
        #pragma unroll
        for (int ca = 0; ca < 4; ++ca)
            #pragma unroll
            for (int r = 0; r < 4; ++r)
                op[ca * 16 + quad * 4 + r] = f2bf(of[ca][r] * inv);
    }
}

// ---------------- host helpers ----------------
static inline void launch_gemm(const u16* A, const u16* W, const float* bias,
                               float* outf, u16* outb,
                               int M, int N, int K, int act, hipStream_t s) {
    dim3 g(N / 64, M / 128, 1);
    mfma_gemm3<<<g, 256, 0, s>>>(A, W, bias, outf, outb, nullptr, M, N, K, act, K);
}

static inline void launch_gemm_sk(const u16* A, const u16* W, float* P,
                                  int M, int N, int K, int SK, hipStream_t s) {
    dim3 g(N / 64, M / 128, SK);
    mfma_gemm3<<<g, 256, 0, s>>>(A, W, nullptr, nullptr, nullptr, P,
                                 M, N, K, 0, K / SK);
}

extern "C" void kernel_launch(void* const* d_in, const int* in_sizes, int n_in,
                              void* d_out, int out_size, void* d_ws, size_t ws_size,
                              hipStream_t stream) {
    const float* x      = (const float*)d_in[0];
    const float* patchw = (const float*)d_in[1];
    const float* patchb = (const float*)d_in[2];
    const float* pos    = (const float*)d_in[3];
    const float* n1w    = (const float*)d_in[4];
    const float* n1b    = (const float*)d_in[5];
    const float* qkvw   = (const float*)d_in[6];
    const float* qkvb   = (const float*)d_in[7];
    const float* pw     = (const float*)d_in[8];
    const float* pb     = (const float*)d_in[9];
    const float* n2w    = (const float*)d_in[10];
    const float* n2b    = (const float*)d_in[11];
    const float* f1w    = (const float*)d_in[12];
    const float* f1b    = (const float*)d_in[13];
    const float* f2w    = (const float*)d_in[14];
    const float* f2b    = (const float*)d_in[15];
    const float* rph    = (const float*)d_in[16];
    const float* rpw    = (const float*)d_in[17];
    float* out = (float*)d_out;

    // workspace layout. Split-K overlays cover only dead buffers:
    //  P_patch = attb..mlpb (dead during patch GEMM), 2 slices
    //  P_pf    = qkvx..rsrv (dead during proj/fc2), up to 4 slices
    float* y   = (float*)d_ws;                  // 1,572,864 f32
    u16* attb  = (u16*)(y + 1572864);           // 1,572,864 u16 (token layout)
    u16* mlpb  = attb + 1572864;                // 6,291,456 u16
    u16* lnb   = mlpb + 6291456;                // 1,572,864 u16
    u16* qkvx  = lnb + 1572864;                 // 4,718,592 u16 (4096x1152)
    u16* rsrv  = qkvx + 4718592;                // 7,864,320 u16
    u16* wb    = rsrv + 7864320;                // 10,918,656 u16 (weights + qkv bias)
    float* posr = (float*)(wb + 10918656);      //   393,216 f32

    u16* colb  = rsrv;                          // overlay: im2col 3,145,728 u16
    float* P_patch = (float*)attb;              // 2 slices = 12.6MB over attb+mlpb
    float* P_pf    = (float*)qkvx;              // 4 slices = 25.2MB over qkvx+rsrv

    u16* wb_patch = wb;
    u16* wb_qkv   = wb + 294912;
    u16* wb_pw    = wb + 2949120;
    u16* wb_f1    = wb + 3833856;
    u16* wb_f2    = wb + 7372800;
    u16* wqb      = wb + 10911744;              // bf16 qkv bias, 6 x 1152

    w2b_all_kernel<<<(10918656 + 255) / 256, 256, 0, stream>>>(
        patchw, qkvw, pw, f1w, f2w, qkvb, wb);
    pos_resize_kernel<<<1536, 256, 0, stream>>>(pos, posr);

    {
        size_t tot = (size_t)NTOK * 768;
        im2col_kernel<<<(int)((tot + 255) / 256), 256, 0, stream>>>(x, colb);
        launch_gemm_sk(colb, wb_patch, P_patch, NTOK, 384, 768, 2, stream);
        epi_ln_kernel<<<NTOK, 64, 0, stream>>>(P_patch, patchb, posr, y, 0, 2,
                                               n1w, n1b, lnb, nullptr);
    }

    for (int i = 0; i < 6; ++i) {
        bool windowed = (i == 0 || i == 1 || i == 3 || i == 4);
        const float* rh = rph + (size_t)i * 63 * 64;
        const float* rw = rpw + (size_t)i * 63 * 64;
        // qkv GEMM: token layout for both paths (M=4096)
        launch_gemm(lnb, wb_qkv + (size_t)i * 442368, qkvb + i * 1152,
                    nullptr, qkvx, NTOK, 1152, 384, 0, stream);
        if (windowed) {
            attn_mfma<WTOK, WS><<<dim3(NWIN * HEADS, 4), 256, 0, stream>>>(
                qkvx, wqb + i * 1152, rh, rw, attb);
        } else {
            attn_mfma<1024, 32><<<dim3(B_SZ * HEADS, 16), 256, 0, stream>>>(
                qkvx, wqb + i * 1152, rh, rw, attb);
        }
        launch_gemm_sk(attb, wb_pw + (size_t)i * 147456, P_pf,
                       NTOK, 384, 384, 2, stream);
        epi_ln_kernel<<<NTOK, 64, 0, stream>>>(P_pf, pb + i * 384, nullptr, y, 1, 2,
                                               n2w + i * 384, n2b + i * 384, lnb,
                                               nullptr);
        launch_gemm(lnb, wb_f1 + (size_t)i * 589824, f1b + i * 1536,
                    nullptr, mlpb, NTOK, 1536, 384, 1, stream);
        launch_gemm_sk(mlpb, wb_f2 + (size_t)i * 589824, P_pf,
                       NTOK, 384, 1536, 4, stream);
        if (i < 5)
            epi_ln_kernel<<<NTOK, 64, 0, stream>>>(P_pf, f2b + i * 384, nullptr, y,
                                                   1, 4, n1w + (i + 1) * 384,
                                                   n1b + (i + 1) * 384, lnb, nullptr);
        else
            epi_ln_kernel<<<NTOK, 64, 0, stream>>>(P_pf, f2b + i * 384, nullptr, y,
                                                   1, 4, nullptr, nullptr, nullptr,
                                                   out);
    }
}

// Round 9
// 775.558 us; speedup vs baseline: 12.4262x; 1.0287x over previous
//
#include <hip/hip_runtime.h>
#include <math.h>

// ---------------- constants ----------------
#define B_SZ 4
#define DIM 384
#define HEADS 6
#define HD 64
#define NTOK 4096          // B*32*32
#define WS 14
#define NWIN 36            // B * 9
#define WTOK 196           // 14*14

typedef unsigned short u16;
typedef __bf16 bf16_t;
typedef bf16_t bf16x8 __attribute__((ext_vector_type(8)));
typedef float f32x4 __attribute__((ext_vector_type(4)));

__device__ __forceinline__ float bf2f(unsigned u) { return __uint_as_float(u << 16); }
__device__ __forceinline__ u16 f2bf(float f) {
    unsigned u = __float_as_uint(f);
    unsigned r = (u + 0x7fffu + ((u >> 16) & 1u)) >> 16;
    return (u16)r;
}

// async global->LDS, 16B per lane, wave-uniform LDS base + lane*16
__device__ __forceinline__ void ldsload16(const u16* g, u16* l) {
    __builtin_amdgcn_global_load_lds(
        (const __attribute__((address_space(1))) unsigned int*)g,
        (__attribute__((address_space(3))) unsigned int*)l, 16, 0, 0);
}

__device__ __forceinline__ int swz(int r) { return (r ^ (r >> 2)) & 3; }

// ---------------- bicubic helper ----------------
__device__ inline float cubic_keys(float x) {
    x = fabsf(x);
    if (x <= 1.f) return ((1.5f * x - 2.5f) * x) * x + 1.f;
    if (x < 2.f)  return ((-0.5f * x + 2.5f) * x - 4.f) * x + 2.f;
    return 0.f;
}

// ---------------- one-shot setup: weights->bf16, pos resize, im2col ----------
// ranges: [0,10918656) weights+qkvb  [.., +393216) posr  [.., +3145728) im2col
__global__ __launch_bounds__(256) void setup_kernel(
        const float* __restrict__ p0, const float* __restrict__ p1,
        const float* __restrict__ p2, const float* __restrict__ p3,
        const float* __restrict__ p4, const float* __restrict__ p5,
        u16* __restrict__ wb, const float* __restrict__ pe,
        float* __restrict__ posr, const float* __restrict__ x,
        u16* __restrict__ col) {
    int i = blockIdx.x * 256 + threadIdx.x;
    if (i < 10918656) {
        const float* s; int off;
        if      (i <   294912) { s = p0; off = 0; }
        else if (i <  2949120) { s = p1; off = 294912; }
        else if (i <  3833856) { s = p2; off = 2949120; }
        else if (i <  7372800) { s = p3; off = 3833856; }
        else if (i < 10911744) { s = p4; off = 7372800; }
        else                   { s = p5; off = 10911744; }
        wb[i] = f2bf(s[i - off]);
        return;
    }
    i -= 10918656;
    if (i < 393216) {
        int c = i % 384;
        int g = i / 384;
        int gy = g / 32, gx = g % 32;
        float wy[14], wx[14];
        float sy = (gy + 0.5f) * (14.f / 32.f) - 0.5f;
        float sx = (gx + 0.5f) * (14.f / 32.f) - 0.5f;
        float toty = 0.f, totx = 0.f;
        #pragma unroll
        for (int k = 0; k < 14; ++k) {
            wy[k] = cubic_keys(sy - (float)k); toty += wy[k];
            wx[k] = cubic_keys(sx - (float)k); totx += wx[k];
        }
        float val = 0.f;
        #pragma unroll 1
        for (int iy = 0; iy < 14; ++iy) {
            if (wy[iy] == 0.f) continue;
            float row = 0.f;
            for (int ix = 0; ix < 14; ++ix) {
                if (wx[ix] == 0.f) continue;
                row += wx[ix] * pe[(iy * 14 + ix) * 384 + c];
            }
            val += wy[iy] * row;
        }
        posr[i] = val / (toty * totx);
        return;
    }
    i -= 393216;
    {
        int kk = i % 768;
        int p  = i / 768;
        int b  = p / 1024;
        int ph = (p % 1024) / 32;
        int pw = p % 32;
        int c = kk / 256;
        int r = kk % 256;
        int ii = r / 16, j = r % 16;
        col[i] = f2bf(x[(size_t)b * 3 * 512 * 512 + (size_t)c * 512 * 512 +
                        (size_t)(ph * 16 + ii) * 512 + (pw * 16 + j)]);
    }
}

// ---------------- fused split-K epilogue + residual + LN / NCHW-out ----------
__global__ __launch_bounds__(64) void epi_ln_kernel(const float* __restrict__ P,
        const float* __restrict__ bias, const float* __restrict__ posr,
        float* __restrict__ y, int addy, int nsk,
        const float* __restrict__ lw, const float* __restrict__ lb,
        u16* __restrict__ lnout, float* __restrict__ outT)
{
    int tok = blockIdx.x, t = threadIdx.x;
    size_t base = (size_t)tok * 384;
    float v[6];
    float s = 0.f;
    #pragma unroll
    for (int i = 0; i < 6; ++i) {
        int c = t + 64 * i;
        float val = bias[c];
        #pragma unroll 1
        for (int sk = 0; sk < nsk; ++sk)
            val += P[(size_t)sk * 1572864 + base + c];
        if (posr) val += posr[(size_t)(tok & 1023) * 384 + c];
        if (addy) val += y[base + c];
        v[i] = val; s += val;
    }
    if (outT) {   // final layer: write NCHW output directly
        int b = tok >> 10, g = tok & 1023;
        #pragma unroll
        for (int i = 0; i < 6; ++i) {
            int c = t + 64 * i;
            outT[((size_t)(b * 384 + c)) * 1024 + g] = v[i];
        }
        return;
    }
    #pragma unroll
    for (int i = 0; i < 6; ++i) y[base + t + 64 * i] = v[i];
    if (!lnout) return;
    #pragma unroll
    for (int off = 32; off > 0; off >>= 1) s += __shfl_xor(s, off);
    float mean = s * (1.f / 384.f);
    float vs = 0.f;
    #pragma unroll
    for (int i = 0; i < 6; ++i) { float d = v[i] - mean; vs += d * d; }
    #pragma unroll
    for (int off = 32; off > 0; off >>= 1) vs += __shfl_xor(vs, off);
    float inv = rsqrtf(vs * (1.f / 384.f) + 1e-5f);
    u16* orow = lnout + base;
    #pragma unroll
    for (int i = 0; i < 6; ++i) {
        int c = t + 64 * i;
        orow[c] = f2bf((v[i] - mean) * inv * lw[c] + lb[c]);
    }
}

// ---------------- MFMA bf16 GEMM v3: BM=128, BN=64, BK=64, split-K -----------
__global__ __launch_bounds__(256) void mfma_gemm3(
        const u16* __restrict__ A, const u16* __restrict__ Wt,
        const float* __restrict__ bias,
        float* __restrict__ outf, u16* __restrict__ outb,
        float* __restrict__ outp,
        int M, int N, int K, int act, int ksplit)
{
    __shared__ u16 As[8192];   // two halves of 128 rows x 32 cols
    __shared__ u16 Bs[4096];   // two halves of 64 rows x 32 cols
    int t = threadIdx.x;
    int lane = t & 63, wave = t >> 6;
    int wm = (wave >> 1) * 64, wn = (wave & 1) * 32;
    int m0 = blockIdx.y * 128, n0 = blockIdx.x * 64;
    int ks = blockIdx.z * ksplit, ke = ks + ksplit;

    int r0 = t >> 2,        c0 = ((t & 3) ^ swz(t >> 2)) * 8;
    int r1 = 64 + (t >> 2), c1 = ((t & 3) ^ swz(64 + (t >> 2))) * 8;
    const u16* a0 = A + (size_t)(m0 + r0) * K + c0;
    const u16* a1 = A + (size_t)(m0 + r1) * K + c1;
    const u16* b0 = Wt + (size_t)(n0 + r0) * K + c0;
    u16* asd0 = &As[wave * 512];
    u16* asd1 = &As[2048 + wave * 512];
    u16* bsd0 = &Bs[wave * 512];

    f32x4 acc[4][2] = {};
    int row_a = wm + (lane & 15);
    int row_b = wn + (lane & 15);
    int lq = lane >> 4;

    for (int k0 = ks; k0 < ke; k0 += 64) {
        ldsload16(a0 + k0, asd0);
        ldsload16(a1 + k0, asd1);
        ldsload16(b0 + k0, bsd0);
        ldsload16(a0 + k0 + 32, asd0 + 4096);
        ldsload16(a1 + k0 + 32, asd1 + 4096);
        ldsload16(b0 + k0 + 32, bsd0 + 2048);
        __syncthreads();
        #pragma unroll
        for (int hf = 0; hf < 2; ++hf) {
            bf16x8 af[4], bfr[2];
            #pragma unroll
            for (int i = 0; i < 4; ++i) {
                int r = row_a + i * 16;
                af[i] = *(const bf16x8*)&As[hf * 4096 + r * 32 + ((lq ^ swz(r)) * 8)];
            }
            #pragma unroll
            for (int j = 0; j < 2; ++j) {
                int r = row_b + j * 16;
                bfr[j] = *(const bf16x8*)&Bs[hf * 2048 + r * 32 + ((lq ^ swz(r)) * 8)];
            }
            #pragma unroll
            for (int i = 0; i < 4; ++i)
                #pragma unroll
                for (int j = 0; j < 2; ++j)
                    acc[i][j] = __builtin_amdgcn_mfma_f32_16x16x32_bf16(
                        af[i], bfr[j], acc[i][j], 0, 0, 0);
        }
        __syncthreads();
    }

    int colq = lane & 15, rowq = (lane >> 4) * 4;
    if (outp) {
        float* pp = outp + (size_t)blockIdx.z * M * N;
        #pragma unroll
        for (int i = 0; i < 4; ++i) {
            #pragma unroll
            for (int rr = 0; rr < 4; ++rr) {
                int m = m0 + wm + i * 16 + rowq + rr;
                size_t mo = (size_t)m * N;
                #pragma unroll
                for (int j = 0; j < 2; ++j) {
                    int n = n0 + wn + j * 16 + colq;
                    pp[mo + n] = acc[i][j][rr];
                }
            }
        }
        return;
    }
    #pragma unroll
    for (int i = 0; i < 4; ++i) {
        #pragma unroll
        for (int rr = 0; rr < 4; ++rr) {
            int m = m0 + wm + i * 16 + rowq + rr;
            size_t mo = (size_t)m * N;
            #pragma unroll
            for (int j = 0; j < 2; ++j) {
                int n = n0 + wn + j * 16 + colq;
                float v = acc[i][j][rr] + bias[n];
                if (act)  v = 0.5f * v * (1.f + erff(v * 0.70710678118654752f));
                if (outf) outf[mo + n] = v;
                if (outb) outb[mo + n] = f2bf(v);
            }
        }
    }
}

// ---------------- MFMA flash attention: fused bias, window gather, dbuf ------
// grid (units*HEADS, ceil(N/64)), block 256 (4 waves, 16 q each).
template<int N, int W>
__global__ __launch_bounds__(256) void attn_mfma(const u16* __restrict__ qkv,
        const u16* __restrict__ qkb, const float* __restrict__ rh,
        const float* __restrict__ rw, u16* __restrict__ outb)
{
    constexpr int JS = (W == 32) ? 64 : 32;   // padded table length
    constexpr int L  = (W == 32) ? 63 : 27;   // real table length
    constexpr int CTR = W - 1;
    __shared__ u16 KV[11776];  // Ks[2][2048] | Vt[2][2560] | Pb[2560]
    __shared__ u16 bhl[64 * 66];
    __shared__ u16 bwl[64 * 66];
    __shared__ u16 Qt[64 * 66];   // [ch][q], UNSCALED

    u16* Pb = KV + 9216;
    u16* Rt = KV;                 // prologue overlay, JS*72 <= 4608 u16

    int t = threadIdx.x, lane = t & 63, wave = t >> 6;
    int quad = lane >> 4, l15 = lane & 15;
    int uh = blockIdx.x, qb0 = blockIdx.y * 64;
    int h = uh % HEADS, u = uh / HEADS;
    size_t tbase = (size_t)u * 1024;   // only used for W==32 (u = batch)
    int wb_ = u / 9, wr = u - wb_ * 9; // window decode (W==14)
    int wy = wr / 3, wx = wr - wy * 3;

    auto rowptr = [&](int lq2) -> const u16* {
        if constexpr (W == 32) {
            return qkv + (tbase + lq2) * 1152;
        } else {
            int iy = lq2 / WS, ix = lq2 - iy * WS;
            int gy = wy * WS + iy, gx = wx * WS + ix;
            if (gy < 32 && gx < 32)
                return qkv + (size_t)(wb_ * 1024 + gy * 32 + gx) * 1152;
            return qkb;
        }
    };

    // ---- stage Q^T (unscaled) ----
    {
        int q = t & 63, ch0 = (t >> 6) * 16;
        int qc = qb0 + q; if (qc >= N) qc = N - 1;
        const u16* qp = rowptr(qc) + h * 64 + ch0;
        uint4 a = *(const uint4*)qp;
        uint4 b = *(const uint4*)(qp + 8);
        u16 vals[16];
        *(uint4*)vals = a; *(uint4*)(vals + 8) = b;
        #pragma unroll
        for (int c = 0; c < 16; ++c)
            Qt[(ch0 + c) * 66 + q] = ((qb0 + q) < N) ? vals[c] : (u16)0;
    }

    // ---- fused rel-pos bias D = Q . R^T (both tables) ----
    #pragma unroll
    for (int table = 0; table < 2; ++table) {
        __syncthreads();
        const float* tab = table ? rw : rh;
        for (int idx = t; idx < JS * 8; idx += 256) {
            int j = idx >> 3, cc0 = (idx & 7) * 8;
            u16 tmp[8];
            if (j < L) {
                const float* src = tab + (size_t)j * 64 + cc0;
                #pragma unroll
                for (int c = 0; c < 8; ++c) tmp[c] = f2bf(src[c]);
            } else {
                #pragma unroll
                for (int c = 0; c < 8; ++c) tmp[c] = 0;
            }
            *(uint4*)&Rt[j * 72 + cc0] = *(uint4*)tmp;
        }
        __syncthreads();
        if (wave < JS / 16) {
            int jt = wave;
            bf16x8 af0 = *(const bf16x8*)&Rt[(jt * 16 + l15) * 72 + quad * 8];
            bf16x8 af1 = *(const bf16x8*)&Rt[(jt * 16 + l15) * 72 + 32 + quad * 8];
            u16* dst = table ? bwl : bhl;
            #pragma unroll
            for (int qt = 0; qt < 4; ++qt) {
                bf16x8 qf0, qf1;
                u16* p0 = (u16*)&qf0; u16* p1 = (u16*)&qf1;
                #pragma unroll
                for (int z = 0; z < 8; ++z) {
                    p0[z] = Qt[(quad * 8 + z) * 66 + qt * 16 + l15];
                    p1[z] = Qt[(32 + quad * 8 + z) * 66 + qt * 16 + l15];
                }
                f32x4 acc = {};
                acc = __builtin_amdgcn_mfma_f32_16x16x32_bf16(af0, qf0, acc, 0, 0, 0);
                acc = __builtin_amdgcn_mfma_f32_16x16x32_bf16(af1, qf1, acc, 0, 0, 0);
                #pragma unroll
                for (int r = 0; r < 4; ++r)
                    dst[(qt * 16 + l15) * 66 + jt * 16 + quad * 4 + r] = f2bf(acc[r]);
            }
        }
    }
    __syncthreads();   // bhl/bwl ready; Rt readers done before tile-0 staging

    // ---- stage tile 0 into buffer 0 ----
    constexpr int NKT = (N + 31) / 32;
    {
        int pch = wave * 64 + lane;
        int key = pch >> 3;
        int c8 = (pch & 7) ^ (key & 7);
        int kc = key; if (kc >= N) kc = N - 1;
        ldsload16(rowptr(kc) + 384 + h * 64 + c8 * 8, KV + wave * 512);
        int k = t & 31, ch0v = (t >> 5) * 8;
        uint4 vv = *(const uint4*)(rowptr(k) + 768 + h * 64 + ch0v);
        u16 tmp[8]; *(uint4*)tmp = vv;
        u16* vdst = KV + 4096;
        #pragma unroll
        for (int c = 0; c < 8; ++c) vdst[(ch0v + c) * 40 + k] = tmp[c];
    }

    // Q^T B-frags (loop-invariant; scale applied to scores)
    bf16x8 qf[2];
    #pragma unroll
    for (int hc = 0; hc < 2; ++hc) {
        u16* qv = (u16*)&qf[hc];
        #pragma unroll
        for (int j = 0; j < 8; ++j)
            qv[j] = Qt[(hc * 32 + quad * 8 + j) * 66 + wave * 16 + l15];
    }
    int qme = wave * 16 + l15;
    int qq = qb0 + qme; if (qq >= N) qq = N - 1;
    int qh = qq / W, qw = qq - qh * W;
    float bwreg[2][4];
    if constexpr (W == 32) {
        #pragma unroll
        for (int kc2 = 0; kc2 < 2; ++kc2)
            #pragma unroll
            for (int r = 0; r < 4; ++r) {
                int keyl = kc2 * 16 + quad * 4 + r;
                bwreg[kc2][r] = bf2f(bwl[qme * 66 + (qw - keyl + CTR)]);
            }
    }

    f32x4 of[4] = {};
    float lsum = 0.f;
    __syncthreads();   // tile 0 staged (vmcnt drained)

    for (int kt = 0; kt < NKT; ++kt) {
        int kb = kt * 32;
        int p = kt & 1;
        const u16* ksp = KV + p * 2048;
        const u16* vtp = KV + 4096 + p * 2560;
        bool pref = (kt + 1 < NKT);
        uint4 vpref;
        int kpf = t & 31, ch0v = (t >> 5) * 8;
        if (pref) {   // prefetch tile kt+1: K via async LDS, V into regs
            int kb2 = kb + 32;
            int pch = wave * 64 + lane;
            int key = pch >> 3;
            int c8 = (pch & 7) ^ (key & 7);
            int kc = kb2 + key; if (kc >= N) kc = N - 1;
            ldsload16(rowptr(kc) + 384 + h * 64 + c8 * 8,
                      KV + (1 - p) * 2048 + wave * 512);
            int kcv = kb2 + kpf; if (kcv >= N) kcv = N - 1;
            vpref = *(const uint4*)(rowptr(kcv) + 768 + h * 64 + ch0v);
        }

        // ---- compute tile kt ----
        f32x4 st[2] = {};
        #pragma unroll
        for (int hc = 0; hc < 2; ++hc) {
            #pragma unroll
            for (int kc2 = 0; kc2 < 2; ++kc2) {
                int key = kc2 * 16 + l15;
                int c8 = hc * 4 + quad;
                int pp = key * 8 + (c8 ^ (key & 7));
                bf16x8 kf = *(const bf16x8*)&ksp[pp * 8];
                st[kc2] = __builtin_amdgcn_mfma_f32_16x16x32_bf16(
                    kf, qf[hc], st[kc2], 0, 0, 0);
            }
        }
        float bh_t = 0.f;
        if constexpr (W == 32) bh_t = bf2f(bhl[qme * 66 + (qh - (kb >> 5) + CTR)]);
        #pragma unroll
        for (int kc2 = 0; kc2 < 2; ++kc2) {
            #pragma unroll
            for (int r = 0; r < 4; ++r) {
                int keyl = kc2 * 16 + quad * 4 + r;
                int key = kb + keyl;
                float b;
                if constexpr (W == 32) {
                    b = bh_t + bwreg[kc2][r];
                } else {
                    int kk2 = (key < N) ? key : (N - 1);
                    int kh = kk2 / W, kw = kk2 - kh * W;
                    b = bf2f(bhl[qme * 66 + (qh - kh + CTR)]) +
                        bf2f(bwl[qme * 66 + (qw - kw + CTR)]);
                }
                float pv = __expf(fmaf(st[kc2][r], 0.125f, b));
                if (key >= N) pv = 0.f;
                lsum += pv;
                Pb[wave * 640 + l15 * 40 + keyl] = f2bf(pv);
            }
        }
        bf16x8 pf = *(const bf16x8*)&Pb[wave * 640 + l15 * 40 + quad * 8];
        #pragma unroll
        for (int ca = 0; ca < 4; ++ca) {
            bf16x8 vf = *(const bf16x8*)&vtp[(ca * 16 + l15) * 40 + quad * 8];
            of[ca] = __builtin_amdgcn_mfma_f32_16x16x32_bf16(
                vf, pf, of[ca], 0, 0, 0);
        }

        if (pref) {   // commit V prefetch to LDS, then barrier
            u16 tmp[8]; *(uint4*)tmp = vpref;
            u16* vdst = KV + 4096 + (1 - p) * 2560;
            #pragma unroll
            for (int c = 0; c < 8; ++c) vdst[(ch0v + c) * 40 + kpf] = tmp[c];
            __syncthreads();
        }
    }

    lsum += __shfl_xor(lsum, 16);
    lsum += __shfl_xor(lsum, 32);
    float inv = 1.f / lsum;
    int q = qb0 + qme;
    if (q < N) {
        u16* op;
        if constexpr (W == 32) {
            op = outb + (tbase + q) * 384 + h * 64;
        } else {
            int iy = q / WS, ix = q - iy * WS;
            int gy = wy * WS + iy, gx = wx * WS + ix;
            if (gy >= 32 || gx >= 32) return;   // padded query: discard
            op = outb + (size_t)(wb_ * 1024 + gy * 32 + gx) * 384 + h * 64;
        }
        #pragma unroll
        for (int ca = 0; ca < 4; ++ca)
            #pragma unroll
            for (int r = 0; r < 4; ++r)
                op[ca * 16 + quad * 4 + r] = f2bf(of[ca][r] * inv);
    }
}

// ---------------- host helpers ----------------
static inline void launch_gemm(const u16* A, const u16* W, const float* bias,
                               float* outf, u16* outb,
                               int M, int N, int K, int act, hipStream_t s) {
    dim3 g(N / 64, M / 128, 1);
    mfma_gemm3<<<g, 256, 0, s>>>(A, W, bias, outf, outb, nullptr, M, N, K, act, K);
}

static inline void launch_gemm_sk(const u16* A, const u16* W, float* P,
                                  int M, int N, int K, int SK, hipStream_t s) {
    dim3 g(N / 64, M / 128, SK);
    mfma_gemm3<<<g, 256, 0, s>>>(A, W, nullptr, nullptr, nullptr, P,
                                 M, N, K, 0, K / SK);
}

extern "C" void kernel_launch(void* const* d_in, const int* in_sizes, int n_in,
                              void* d_out, int out_size, void* d_ws, size_t ws_size,
                              hipStream_t stream) {
    const float* x      = (const float*)d_in[0];
    const float* patchw = (const float*)d_in[1];
    const float* patchb = (const float*)d_in[2];
    const float* pos    = (const float*)d_in[3];
    const float* n1w    = (const float*)d_in[4];
    const float* n1b    = (const float*)d_in[5];
    const float* qkvw   = (const float*)d_in[6];
    const float* qkvb   = (const float*)d_in[7];
    const float* pw     = (const float*)d_in[8];
    const float* pb     = (const float*)d_in[9];
    const float* n2w    = (const float*)d_in[10];
    const float* n2b    = (const float*)d_in[11];
    const float* f1w    = (const float*)d_in[12];
    const float* f1b    = (const float*)d_in[13];
    const float* f2w    = (const float*)d_in[14];
    const float* f2b    = (const float*)d_in[15];
    const float* rph    = (const float*)d_in[16];
    const float* rpw    = (const float*)d_in[17];
    float* out = (float*)d_out;

    // workspace layout. Split-K overlays cover only dead buffers:
    //  P_patch = attb..mlpb (dead during patch GEMM), 2 slices
    //  P_pf    = qkvx..rsrv (dead during proj/fc2), 2 slices
    float* y   = (float*)d_ws;                  // 1,572,864 f32
    u16* attb  = (u16*)(y + 1572864);           // 1,572,864 u16 (token layout)
    u16* mlpb  = attb + 1572864;                // 6,291,456 u16
    u16* lnb   = mlpb + 6291456;                // 1,572,864 u16
    u16* qkvx  = lnb + 1572864;                 // 4,718,592 u16 (4096x1152)
    u16* rsrv  = qkvx + 4718592;                // 7,864,320 u16
    u16* wb    = rsrv + 7864320;                // 10,918,656 u16 (weights + qkv bias)
    float* posr = (float*)(wb + 10918656);      //   393,216 f32

    u16* colb  = rsrv;                          // overlay: im2col 3,145,728 u16
    float* P_patch = (float*)attb;              // 2 slices = 12.6MB over attb+mlpb
    float* P_pf    = (float*)qkvx;              // 2 slices = 12.6MB over qkvx+rsrv[:1.6M]

    u16* wb_patch = wb;
    u16* wb_qkv   = wb + 294912;
    u16* wb_pw    = wb + 2949120;
    u16* wb_f1    = wb + 3833856;
    u16* wb_f2    = wb + 7372800;
    u16* wqb      = wb + 10911744;              // bf16 qkv bias, 6 x 1152

    setup_kernel<<<(14457600 + 255) / 256, 256, 0, stream>>>(
        patchw, qkvw, pw, f1w, f2w, qkvb, wb, pos, posr, x, colb);

    launch_gemm_sk(colb, wb_patch, P_patch, NTOK, 384, 768, 2, stream);
    epi_ln_kernel<<<NTOK, 64, 0, stream>>>(P_patch, patchb, posr, y, 0, 2,
                                           n1w, n1b, lnb, nullptr);

    for (int i = 0; i < 6; ++i) {
        bool windowed = (i == 0 || i == 1 || i == 3 || i == 4);
        const float* rh = rph + (size_t)i * 63 * 64;
        const float* rw = rpw + (size_t)i * 63 * 64;
        launch_gemm(lnb, wb_qkv + (size_t)i * 442368, qkvb + i * 1152,
                    nullptr, qkvx, NTOK, 1152, 384, 0, stream);
        if (windowed) {
            attn_mfma<WTOK, WS><<<dim3(NWIN * HEADS, 4), 256, 0, stream>>>(
                qkvx, wqb + i * 1152, rh, rw, attb);
        } else {
            attn_mfma<1024, 32><<<dim3(B_SZ * HEADS, 16), 256, 0, stream>>>(
                qkvx, wqb + i * 1152, rh, rw, attb);
        }
        launch_gemm_sk(attb, wb_pw + (size_t)i * 147456, P_pf,
                       NTOK, 384, 384, 2, stream);
        epi_ln_kernel<<<NTOK, 64, 0, stream>>>(P_pf, pb + i * 384, nullptr, y, 1, 2,
                                               n2w + i * 384, n2b + i * 384, lnb,
                                               nullptr);
        launch_gemm(lnb, wb_f1 + (size_t)i * 589824, f1b + i * 1536,
                    nullptr, mlpb, NTOK, 1536, 384, 1, stream);
        launch_gemm_sk(mlpb, wb_f2 + (size_t)i * 589824, P_pf,
                       NTOK, 384, 1536, 2, stream);
        if (i < 5)
            epi_ln_kernel<<<NTOK, 64, 0, stream>>>(P_pf, f2b + i * 384, nullptr, y,
                                                   1, 2, n1w + (i + 1) * 384,
                                                   n1b + (i + 1) * 384, lnb, nullptr);
        else
            epi_ln_kernel<<<NTOK, 64, 0, stream>>>(P_pf, f2b + i * 384, nullptr, y,
                                                   1, 2, nullptr, nullptr, nullptr,
                                                   out);
    }
}

// Round 10
// 762.646 us; speedup vs baseline: 12.6366x; 1.0169x over previous
//
#include <hip/hip_runtime.h>
#include <math.h>

// ---------------- constants ----------------
#define B_SZ 4
#define DIM 384
#define HEADS 6
#define HD 64
#define NTOK 4096          // B*32*32
#define WS 14
#define NWIN 36            // B * 9
#define WTOK 196           // 14*14

typedef unsigned short u16;
typedef __bf16 bf16_t;
typedef bf16_t bf16x8 __attribute__((ext_vector_type(8)));
typedef float f32x4 __attribute__((ext_vector_type(4)));

__device__ __forceinline__ float bf2f(unsigned u) { return __uint_as_float(u << 16); }
__device__ __forceinline__ u16 f2bf(float f) {
    unsigned u = __float_as_uint(f);
    unsigned r = (u + 0x7fffu + ((u >> 16) & 1u)) >> 16;
    return (u16)r;
}

// async global->LDS, 16B per lane, wave-uniform LDS base + lane*16
__device__ __forceinline__ void ldsload16(const u16* g, u16* l) {
    __builtin_amdgcn_global_load_lds(
        (const __attribute__((address_space(1))) unsigned int*)g,
        (__attribute__((address_space(3))) unsigned int*)l, 16, 0, 0);
}

__device__ __forceinline__ int swz(int r) { return (r ^ (r >> 2)) & 3; }

// ---------------- bicubic helper ----------------
__device__ inline float cubic_keys(float x) {
    x = fabsf(x);
    if (x <= 1.f) return ((1.5f * x - 2.5f) * x) * x + 1.f;
    if (x < 2.f)  return ((-0.5f * x + 2.5f) * x - 4.f) * x + 2.f;
    return 0.f;
}

// ---------------- one-shot setup (x4 vectorized) -----------------------------
// element ranges: [0,10918656) weights+qkvb | [..,+393216) posr | [..,+3145728) im2col
// all boundaries divisible by 4 -> a thread's 4 elements never straddle.
__global__ __launch_bounds__(256) void setup_kernel(
        const float* __restrict__ p0, const float* __restrict__ p1,
        const float* __restrict__ p2, const float* __restrict__ p3,
        const float* __restrict__ p4, const float* __restrict__ p5,
        u16* __restrict__ wb, const float* __restrict__ pe,
        float* __restrict__ posr, const float* __restrict__ x,
        u16* __restrict__ col) {
    int i = (blockIdx.x * 256 + threadIdx.x) * 4;
    if (i < 10918656) {
        const float* s; int off;
        if      (i <   294912) { s = p0; off = 0; }
        else if (i <  2949120) { s = p1; off = 294912; }
        else if (i <  3833856) { s = p2; off = 2949120; }
        else if (i <  7372800) { s = p3; off = 3833856; }
        else if (i < 10911744) { s = p4; off = 7372800; }
        else                   { s = p5; off = 10911744; }
        float4 v = *(const float4*)(s + (i - off));
        u16 o[4] = { f2bf(v.x), f2bf(v.y), f2bf(v.z), f2bf(v.w) };
        *(uint2*)(wb + i) = *(const uint2*)o;
        return;
    }
    i -= 10918656;
    if (i < 393216) {
        int c = i % 384;          // c%4==0
        int g = i / 384;
        int gy = g / 32, gx = g % 32;
        float wy[14], wx[14];
        float sy = (gy + 0.5f) * (14.f / 32.f) - 0.5f;
        float sx = (gx + 0.5f) * (14.f / 32.f) - 0.5f;
        float toty = 0.f, totx = 0.f;
        #pragma unroll
        for (int k = 0; k < 14; ++k) {
            wy[k] = cubic_keys(sy - (float)k); toty += wy[k];
            wx[k] = cubic_keys(sx - (float)k); totx += wx[k];
        }
        float4 acc = {0.f, 0.f, 0.f, 0.f};
        #pragma unroll 1
        for (int iy = 0; iy < 14; ++iy) {
            if (wy[iy] == 0.f) continue;
            float4 row = {0.f, 0.f, 0.f, 0.f};
            for (int ix = 0; ix < 14; ++ix) {
                if (wx[ix] == 0.f) continue;
                float4 pv = *(const float4*)(pe + (iy * 14 + ix) * 384 + c);
                row.x += wx[ix] * pv.x; row.y += wx[ix] * pv.y;
                row.z += wx[ix] * pv.z; row.w += wx[ix] * pv.w;
            }
            acc.x += wy[iy] * row.x; acc.y += wy[iy] * row.y;
            acc.z += wy[iy] * row.z; acc.w += wy[iy] * row.w;
        }
        float inv = 1.f / (toty * totx);
        acc.x *= inv; acc.y *= inv; acc.z *= inv; acc.w *= inv;
        *(float4*)(posr + i) = acc;
        return;
    }
    i -= 393216;
    if (i < 3145728) {
        int kk = i % 768;         // kk%4==0
        int p  = i / 768;
        int b  = p / 1024;
        int ph = (p % 1024) / 32;
        int pw = p % 32;
        int c = kk / 256;
        int r = kk % 256;
        int ii = r / 16, j = r % 16;   // j%4==0, j+3<16
        float4 v = *(const float4*)(x + (size_t)b * 3 * 512 * 512 +
                                    (size_t)c * 512 * 512 +
                                    (size_t)(ph * 16 + ii) * 512 + (pw * 16 + j));
        u16 o[4] = { f2bf(v.x), f2bf(v.y), f2bf(v.z), f2bf(v.w) };
        *(uint2*)(col + i) = *(const uint2*)o;
    }
}

// ---------------- fused split-K epilogue + residual + LN / NCHW-out ----------
__global__ __launch_bounds__(64) void epi_ln_kernel(const float* __restrict__ P,
        const float* __restrict__ bias, const float* __restrict__ posr,
        float* __restrict__ y, int addy, int nsk,
        const float* __restrict__ lw, const float* __restrict__ lb,
        u16* __restrict__ lnout, float* __restrict__ outT)
{
    int tok = blockIdx.x, t = threadIdx.x;
    size_t base = (size_t)tok * 384;
    float v[6];
    float s = 0.f;
    #pragma unroll
    for (int i = 0; i < 6; ++i) {
        int c = t + 64 * i;
        float val = bias[c];
        #pragma unroll 1
        for (int sk = 0; sk < nsk; ++sk)
            val += P[(size_t)sk * 1572864 + base + c];
        if (posr) val += posr[(size_t)(tok & 1023) * 384 + c];
        if (addy) val += y[base + c];
        v[i] = val; s += val;
    }
    if (outT) {   // final layer: write NCHW output directly
        int b = tok >> 10, g = tok & 1023;
        #pragma unroll
        for (int i = 0; i < 6; ++i) {
            int c = t + 64 * i;
            outT[((size_t)(b * 384 + c)) * 1024 + g] = v[i];
        }
        return;
    }
    #pragma unroll
    for (int i = 0; i < 6; ++i) y[base + t + 64 * i] = v[i];
    if (!lnout) return;
    #pragma unroll
    for (int off = 32; off > 0; off >>= 1) s += __shfl_xor(s, off);
    float mean = s * (1.f / 384.f);
    float vs = 0.f;
    #pragma unroll
    for (int i = 0; i < 6; ++i) { float d = v[i] - mean; vs += d * d; }
    #pragma unroll
    for (int off = 32; off > 0; off >>= 1) vs += __shfl_xor(vs, off);
    float inv = rsqrtf(vs * (1.f / 384.f) + 1e-5f);
    u16* orow = lnout + base;
    #pragma unroll
    for (int i = 0; i < 6; ++i) {
        int c = t + 64 * i;
        orow[c] = f2bf((v[i] - mean) * inv * lw[c] + lb[c]);
    }
}

// ---------------- MFMA bf16 GEMM v4: BM=128, BN=64, BK=64, split-K, dbuf -----
__global__ __launch_bounds__(256) void mfma_gemm4(
        const u16* __restrict__ A, const u16* __restrict__ Wt,
        const float* __restrict__ bias,
        float* __restrict__ outf, u16* __restrict__ outb,
        float* __restrict__ outp,
        int M, int N, int K, int act, int ksplit)
{
    __shared__ u16 As[2][8192];   // per buf: 128 rows x 32 cols x 2 k-halves
    __shared__ u16 Bs[2][4096];
    int t = threadIdx.x;
    int lane = t & 63, wave = t >> 6;
    int wm = (wave >> 1) * 64, wn = (wave & 1) * 32;
    int m0 = blockIdx.y * 128, n0 = blockIdx.x * 64;
    int ks = blockIdx.z * ksplit;

    int r0 = t >> 2,        c0 = ((t & 3) ^ swz(t >> 2)) * 8;
    int r1 = 64 + (t >> 2), c1 = ((t & 3) ^ swz(64 + (t >> 2))) * 8;
    const u16* a0 = A + (size_t)(m0 + r0) * K + c0;
    const u16* a1 = A + (size_t)(m0 + r1) * K + c1;
    const u16* b0 = Wt + (size_t)(n0 + r0) * K + c0;

    auto stage = [&](int k0, int buf) {
        ldsload16(a0 + k0,      &As[buf][wave * 512]);
        ldsload16(a1 + k0,      &As[buf][2048 + wave * 512]);
        ldsload16(b0 + k0,      &Bs[buf][wave * 512]);
        ldsload16(a0 + k0 + 32, &As[buf][4096 + wave * 512]);
        ldsload16(a1 + k0 + 32, &As[buf][6144 + wave * 512]);
        ldsload16(b0 + k0 + 32, &Bs[buf][2048 + wave * 512]);
    };

    f32x4 acc[4][2] = {};
    int row_a = wm + (lane & 15);
    int row_b = wn + (lane & 15);
    int lq = lane >> 4;
    int nchunks = ksplit / 64;

    stage(ks, 0);
    __syncthreads();

    for (int ci = 0; ci < nchunks; ++ci) {
        int p = ci & 1;
        bool pref = (ci + 1 < nchunks);
        if (pref) stage(ks + (ci + 1) * 64, 1 - p);
        #pragma unroll
        for (int hf = 0; hf < 2; ++hf) {
            bf16x8 af[4], bfr[2];
            #pragma unroll
            for (int i = 0; i < 4; ++i) {
                int r = row_a + i * 16;
                af[i] = *(const bf16x8*)&As[p][hf * 4096 + r * 32 + ((lq ^ swz(r)) * 8)];
            }
            #pragma unroll
            for (int j = 0; j < 2; ++j) {
                int r = row_b + j * 16;
                bfr[j] = *(const bf16x8*)&Bs[p][hf * 2048 + r * 32 + ((lq ^ swz(r)) * 8)];
            }
            #pragma unroll
            for (int i = 0; i < 4; ++i)
                #pragma unroll
                for (int j = 0; j < 2; ++j)
                    acc[i][j] = __builtin_amdgcn_mfma_f32_16x16x32_bf16(
                        af[i], bfr[j], acc[i][j], 0, 0, 0);
        }
        if (pref) __syncthreads();
    }

    int colq = lane & 15, rowq = (lane >> 4) * 4;
    if (outp) {
        float* pp = outp + (size_t)blockIdx.z * M * N;
        #pragma unroll
        for (int i = 0; i < 4; ++i) {
            #pragma unroll
            for (int rr = 0; rr < 4; ++rr) {
                int m = m0 + wm + i * 16 + rowq + rr;
                size_t mo = (size_t)m * N;
                #pragma unroll
                for (int j = 0; j < 2; ++j) {
                    int n = n0 + wn + j * 16 + colq;
                    pp[mo + n] = acc[i][j][rr];
                }
            }
        }
        return;
    }
    #pragma unroll
    for (int i = 0; i < 4; ++i) {
        #pragma unroll
        for (int rr = 0; rr < 4; ++rr) {
            int m = m0 + wm + i * 16 + rowq + rr;
            size_t mo = (size_t)m * N;
            #pragma unroll
            for (int j = 0; j < 2; ++j) {
                int n = n0 + wn + j * 16 + colq;
                float v = acc[i][j][rr] + bias[n];
                if (act)  v = 0.5f * v * (1.f + erff(v * 0.70710678118654752f));
                if (outf) outf[mo + n] = v;
                if (outb) outb[mo + n] = f2bf(v);
            }
        }
    }
}

// ---------------- MFMA flash attention: fused bias, window gather, dbuf ------
// grid (units*HEADS, ceil(N/64)), block 256 (4 waves, 16 q each).
template<int N, int W>
__global__ __launch_bounds__(256) void attn_mfma(const u16* __restrict__ qkv,
        const u16* __restrict__ qkb, const float* __restrict__ rh,
        const float* __restrict__ rw, u16* __restrict__ outb)
{
    constexpr int JS = (W == 32) ? 64 : 32;   // padded table length
    constexpr int L  = (W == 32) ? 63 : 27;   // real table length
    constexpr int CTR = W - 1;
    __shared__ u16 KV[11776];  // Ks[2][2048] | Vt[2][2560] | Pb[2560]
    __shared__ u16 bhl[64 * 66];
    __shared__ u16 bwl[64 * 66];
    __shared__ u16 Qt[64 * 66];   // [ch][q], UNSCALED

    u16* Pb = KV + 9216;
    u16* Rt = KV;                 // prologue overlay, JS*72 <= 4608 u16

    int t = threadIdx.x, lane = t & 63, wave = t >> 6;
    int quad = lane >> 4, l15 = lane & 15;
    int uh = blockIdx.x, qb0 = blockIdx.y * 64;
    int h = uh % HEADS, u = uh / HEADS;
    size_t tbase = (size_t)u * 1024;   // only used for W==32 (u = batch)
    int wb_ = u / 9, wr = u - wb_ * 9; // window decode (W==14)
    int wy = wr / 3, wx = wr - wy * 3;

    auto rowptr = [&](int lq2) -> const u16* {
        if constexpr (W == 32) {
            return qkv + (tbase + lq2) * 1152;
        } else {
            int iy = lq2 / WS, ix = lq2 - iy * WS;
            int gy = wy * WS + iy, gx = wx * WS + ix;
            if (gy < 32 && gx < 32)
                return qkv + (size_t)(wb_ * 1024 + gy * 32 + gx) * 1152;
            return qkb;
        }
    };

    // ---- stage Q^T (unscaled) ----
    {
        int q = t & 63, ch0 = (t >> 6) * 16;
        int qc = qb0 + q; if (qc >= N) qc = N - 1;
        const u16* qp = rowptr(qc) + h * 64 + ch0;
        uint4 a = *(const uint4*)qp;
        uint4 b = *(const uint4*)(qp + 8);
        u16 vals[16];
        *(uint4*)vals = a; *(uint4*)(vals + 8) = b;
        #pragma unroll
        for (int c = 0; c < 16; ++c)
            Qt[(ch0 + c) * 66 + q] = ((qb0 + q) < N) ? vals[c] : (u16)0;
    }

    // ---- fused rel-pos bias D = Q . R^T (both tables) ----
    #pragma unroll
    for (int table = 0; table < 2; ++table) {
        __syncthreads();
        const float* tab = table ? rw : rh;
        for (int idx = t; idx < JS * 8; idx += 256) {
            int j = idx >> 3, cc0 = (idx & 7) * 8;
            u16 tmp[8];
            if (j < L) {
                const float* src = tab + (size_t)j * 64 + cc0;
                #pragma unroll
                for (int c = 0; c < 8; ++c) tmp[c] = f2bf(src[c]);
            } else {
                #pragma unroll
                for (int c = 0; c < 8; ++c) tmp[c] = 0;
            }
            *(uint4*)&Rt[j * 72 + cc0] = *(uint4*)tmp;
        }
        __syncthreads();
        if (wave < JS / 16) {
            int jt = wave;
            bf16x8 af0 = *(const bf16x8*)&Rt[(jt * 16 + l15) * 72 + quad * 8];
            bf16x8 af1 = *(const bf16x8*)&Rt[(jt * 16 + l15) * 72 + 32 + quad * 8];
            u16* dst = table ? bwl : bhl;
            #pragma unroll
            for (int qt = 0; qt < 4; ++qt) {
                bf16x8 qf0, qf1;
                u16* p0 = (u16*)&qf0; u16* p1 = (u16*)&qf1;
                #pragma unroll
                for (int z = 0; z < 8; ++z) {
                    p0[z] = Qt[(quad * 8 + z) * 66 + qt * 16 + l15];
                    p1[z] = Qt[(32 + quad * 8 + z) * 66 + qt * 16 + l15];
                }
                f32x4 acc = {};
                acc = __builtin_amdgcn_mfma_f32_16x16x32_bf16(af0, qf0, acc, 0, 0, 0);
                acc = __builtin_amdgcn_mfma_f32_16x16x32_bf16(af1, qf1, acc, 0, 0, 0);
                #pragma unroll
                for (int r = 0; r < 4; ++r)
                    dst[(qt * 16 + l15) * 66 + jt * 16 + quad * 4 + r] = f2bf(acc[r]);
            }
        }
    }
    __syncthreads();   // bhl/bwl ready; Rt readers done before tile-0 staging

    // ---- stage tile 0 into buffer 0 ----
    constexpr int NKT = (N + 31) / 32;
    {
        int pch = wave * 64 + lane;
        int key = pch >> 3;
        int c8 = (pch & 7) ^ (key & 7);
        int kc = key; if (kc >= N) kc = N - 1;
        ldsload16(rowptr(kc) + 384 + h * 64 + c8 * 8, KV + wave * 512);
        int k = t & 31, ch0v = (t >> 5) * 8;
        uint4 vv = *(const uint4*)(rowptr(k) + 768 + h * 64 + ch0v);
        u16 tmp[8]; *(uint4*)tmp = vv;
        u16* vdst = KV + 4096;
        #pragma unroll
        for (int c = 0; c < 8; ++c) vdst[(ch0v + c) * 40 + k] = tmp[c];
    }

    // Q^T B-frags (loop-invariant; scale applied to scores)
    bf16x8 qf[2];
    #pragma unroll
    for (int hc = 0; hc < 2; ++hc) {
        u16* qv = (u16*)&qf[hc];
        #pragma unroll
        for (int j = 0; j < 8; ++j)
            qv[j] = Qt[(hc * 32 + quad * 8 + j) * 66 + wave * 16 + l15];
    }
    int qme = wave * 16 + l15;
    int qq = qb0 + qme; if (qq >= N) qq = N - 1;
    int qh = qq / W, qw = qq - qh * W;
    float bwreg[2][4];
    if constexpr (W == 32) {
        #pragma unroll
        for (int kc2 = 0; kc2 < 2; ++kc2)
            #pragma unroll
            for (int r = 0; r < 4; ++r) {
                int keyl = kc2 * 16 + quad * 4 + r;
                bwreg[kc2][r] = bf2f(bwl[qme * 66 + (qw - keyl + CTR)]);
            }
    }

    f32x4 of[4] = {};
    float lsum = 0.f;
    __syncthreads();   // tile 0 staged (vmcnt drained)

    for (int kt = 0; kt < NKT; ++kt) {
        int kb = kt * 32;
        int p = kt & 1;
        const u16* ksp = KV + p * 2048;
        const u16* vtp = KV + 4096 + p * 2560;
        bool pref = (kt + 1 < NKT);
        uint4 vpref;
        int kpf = t & 31, ch0v = (t >> 5) * 8;
        if (pref) {   // prefetch tile kt+1: K via async LDS, V into regs
            int kb2 = kb + 32;
            int pch = wave * 64 + lane;
            int key = pch >> 3;
            int c8 = (pch & 7) ^ (key & 7);
            int kc = kb2 + key; if (kc >= N) kc = N - 1;
            ldsload16(rowptr(kc) + 384 + h * 64 + c8 * 8,
                      KV + (1 - p) * 2048 + wave * 512);
            int kcv = kb2 + kpf; if (kcv >= N) kcv = N - 1;
            vpref = *(const uint4*)(rowptr(kcv) + 768 + h * 64 + ch0v);
        }

        // ---- compute tile kt ----
        f32x4 st[2] = {};
        #pragma unroll
        for (int hc = 0; hc < 2; ++hc) {
            #pragma unroll
            for (int kc2 = 0; kc2 < 2; ++kc2) {
                int key = kc2 * 16 + l15;
                int c8 = hc * 4 + quad;
                int pp = key * 8 + (c8 ^ (key & 7));
                bf16x8 kf = *(const bf16x8*)&ksp[pp * 8];
                st[kc2] = __builtin_amdgcn_mfma_f32_16x16x32_bf16(
                    kf, qf[hc], st[kc2], 0, 0, 0);
            }
        }
        float bh_t = 0.f;
        if constexpr (W == 32) bh_t = bf2f(bhl[qme * 66 + (qh - (kb >> 5) + CTR)]);
        #pragma unroll
        for (int kc2 = 0; kc2 < 2; ++kc2) {
            #pragma unroll
            for (int r = 0; r < 4; ++r) {
                int keyl = kc2 * 16 + quad * 4 + r;
                int key = kb + keyl;
                float b;
                if constexpr (W == 32) {
                    b = bh_t + bwreg[kc2][r];
                } else {
                    int kk2 = (key < N) ? key : (N - 1);
                    int kh = kk2 / W, kw = kk2 - kh * W;
                    b = bf2f(bhl[qme * 66 + (qh - kh + CTR)]) +
                        bf2f(bwl[qme * 66 + (qw - kw + CTR)]);
                }
                float pv = __expf(fmaf(st[kc2][r], 0.125f, b));
                if (key >= N) pv = 0.f;
                lsum += pv;
                Pb[wave * 640 + l15 * 40 + keyl] = f2bf(pv);
            }
        }
        bf16x8 pf = *(const bf16x8*)&Pb[wave * 640 + l15 * 40 + quad * 8];
        #pragma unroll
        for (int ca = 0; ca < 4; ++ca) {
            bf16x8 vf = *(const bf16x8*)&vtp[(ca * 16 + l15) * 40 + quad * 8];
            of[ca] = __builtin_amdgcn_mfma_f32_16x16x32_bf16(
                vf, pf, of[ca], 0, 0, 0);
        }

        if (pref) {   // commit V prefetch to LDS, then barrier
            u16 tmp[8]; *(uint4*)tmp = vpref;
            u16* vdst = KV + 4096 + (1 - p) * 2560;
            #pragma unroll
            for (int c = 0; c < 8; ++c) vdst[(ch0v + c) * 40 + kpf] = tmp[c];
            __syncthreads();
        }
    }

    lsum += __shfl_xor(lsum, 16);
    lsum += __shfl_xor(lsum, 32);
    float inv = 1.f / lsum;
    int q = qb0 + qme;
    if (q < N) {
        u16* op;
        if constexpr (W == 32) {
            op = outb + (tbase + q) * 384 + h * 64;
        } else {
            int iy = q / WS, ix = q - iy * WS;
            int gy = wy * WS + iy, gx = wx * WS + ix;
            if (gy >= 32 || gx >= 32) return;   // padded query: discard
            op = outb + (size_t)(wb_ * 1024 + gy * 32 + gx) * 384 + h * 64;
        }
        #pragma unroll
        for (int ca = 0; ca < 4; ++ca)
            #pragma unroll
            for (int r = 0; r < 4; ++r)
                op[ca * 16 + quad * 4 + r] = f2bf(of[ca][r] * inv);
    }
}

// ---------------- host helpers ----------------
static inline void launch_gemm(const u16* A, const u16* W, const float* bias,
                               float* outf, u16* outb,
                               int M, int N, int K, int act, hipStream_t s) {
    dim3 g(N / 64, M / 128, 1);
    mfma_gemm4<<<g, 256, 0, s>>>(A, W, bias, outf, outb, nullptr, M, N, K, act, K);
}

static inline void launch_gemm_sk(const u16* A, const u16* W, float* P,
                                  int M, int N, int K, int SK, hipStream_t s) {
    dim3 g(N / 64, M / 128, SK);
    mfma_gemm4<<<g, 256, 0, s>>>(A, W, nullptr, nullptr, nullptr, P,
                                 M, N, K, 0, K / SK);
}

extern "C" void kernel_launch(void* const* d_in, const int* in_sizes, int n_in,
                              void* d_out, int out_size, void* d_ws, size_t ws_size,
                              hipStream_t stream) {
    const float* x      = (const float*)d_in[0];
    const float* patchw = (const float*)d_in[1];
    const float* patchb = (const float*)d_in[2];
    const float* pos    = (const float*)d_in[3];
    const float* n1w    = (const float*)d_in[4];
    const float* n1b    = (const float*)d_in[5];
    const float* qkvw   = (const float*)d_in[6];
    const float* qkvb   = (const float*)d_in[7];
    const float* pw     = (const float*)d_in[8];
    const float* pb     = (const float*)d_in[9];
    const float* n2w    = (const float*)d_in[10];
    const float* n2b    = (const float*)d_in[11];
    const float* f1w    = (const float*)d_in[12];
    const float* f1b    = (const float*)d_in[13];
    const float* f2w    = (const float*)d_in[14];
    const float* f2b    = (const float*)d_in[15];
    const float* rph    = (const float*)d_in[16];
    const float* rpw    = (const float*)d_in[17];
    float* out = (float*)d_out;

    // workspace layout. Split-K overlays cover only dead buffers:
    //  P_patch = attb..mlpb (dead during patch GEMM), 2 slices
    //  P_pf    = qkvx..rsrv (dead during proj/fc2), 2 slices
    float* y   = (float*)d_ws;                  // 1,572,864 f32
    u16* attb  = (u16*)(y + 1572864);           // 1,572,864 u16 (token layout)
    u16* mlpb  = attb + 1572864;                // 6,291,456 u16
    u16* lnb   = mlpb + 6291456;                // 1,572,864 u16
    u16* qkvx  = lnb + 1572864;                 // 4,718,592 u16 (4096x1152)
    u16* rsrv  = qkvx + 4718592;                // 7,864,320 u16
    u16* wb    = rsrv + 7864320;                // 10,918,656 u16 (weights + qkv bias)
    float* posr = (float*)(wb + 10918656);      //   393,216 f32

    u16* colb  = rsrv;                          // overlay: im2col 3,145,728 u16
    float* P_patch = (float*)attb;              // 2 slices = 12.6MB over attb+mlpb
    float* P_pf    = (float*)qkvx;              // 2 slices = 12.6MB over qkvx+rsrv[:1.6M]

    u16* wb_patch = wb;
    u16* wb_qkv   = wb + 294912;
    u16* wb_pw    = wb + 2949120;
    u16* wb_f1    = wb + 3833856;
    u16* wb_f2    = wb + 7372800;
    u16* wqb      = wb + 10911744;              // bf16 qkv bias, 6 x 1152

    setup_kernel<<<(14457600 / 4 + 255) / 256, 256, 0, stream>>>(
        patchw, qkvw, pw, f1w, f2w, qkvb, wb, pos, posr, x, colb);

    launch_gemm_sk(colb, wb_patch, P_patch, NTOK, 384, 768, 2, stream);
    epi_ln_kernel<<<NTOK, 64, 0, stream>>>(P_patch, patchb, posr, y, 0, 2,
                                           n1w, n1b, lnb, nullptr);

    for (int i = 0; i < 6; ++i) {
        bool windowed = (i == 0 || i == 1 || i == 3 || i == 4);
        const float* rh = rph + (size_t)i * 63 * 64;
        const float* rw = rpw + (size_t)i * 63 * 64;
        launch_gemm(lnb, wb_qkv + (size_t)i * 442368, qkvb + i * 1152,
                    nullptr, qkvx, NTOK, 1152, 384, 0, stream);
        if (windowed) {
            attn_mfma<WTOK, WS><<<dim3(NWIN * HEADS, 4), 256, 0, stream>>>(
                qkvx, wqb + i * 1152, rh, rw, attb);
        } else {
            attn_mfma<1024, 32><<<dim3(B_SZ * HEADS, 16), 256, 0, stream>>>(
                qkvx, wqb + i * 1152, rh, rw, attb);
        }
        launch_gemm_sk(attb, wb_pw + (size_t)i * 147456, P_pf,
                       NTOK, 384, 384, 2, stream);
        epi_ln_kernel<<<NTOK, 64, 0, stream>>>(P_pf, pb + i * 384, nullptr, y, 1, 2,
                                               n2w + i * 384, n2b + i * 384, lnb,
                                               nullptr);
        launch_gemm(lnb, wb_f1 + (size_t)i * 589824, f1b + i * 1536,
                    nullptr, mlpb, NTOK, 1536, 384, 1, stream);
        launch_gemm_sk(mlpb, wb_f2 + (size_t)i * 589824, P_pf,
                       NTOK, 384, 1536, 2, stream);
        if (i < 5)
            epi_ln_kernel<<<NTOK, 64, 0, stream>>>(P_pf, f2b + i * 384, nullptr, y,
                                                   1, 2, n1w + (i + 1) * 384,
                                                   n1b + (i + 1) * 384, lnb, nullptr);
        else
            epi_ln_kernel<<<NTOK, 64, 0, stream>>>(P_pf, f2b + i * 384, nullptr, y,
                                                   1, 2, nullptr, nullptr, nullptr,
                                                   out);
    }
}

// Round 11
// 753.568 us; speedup vs baseline: 12.7888x; 1.0120x over previous
//
#include <hip/hip_runtime.h>
#include <hip/hip_bf16.h>
#include <math.h>

// ---------------- constants ----------------
#define B_SZ 4
#define DIM 384
#define HEADS 6
#define HD 64
#define NTOK 4096          // B*32*32
#define WS 14
#define NWIN 36            // B * 9
#define WTOK 196           // 14*14

typedef unsigned short u16;
typedef __bf16 bf16_t;
typedef bf16_t bf16x8 __attribute__((ext_vector_type(8)));
typedef float f32x4 __attribute__((ext_vector_type(4)));

__device__ __forceinline__ float bf2f(unsigned u) { return __uint_as_float(u << 16); }
__device__ __forceinline__ u16 f2bf(float f) {
    unsigned u = __float_as_uint(f);
    unsigned r = (u + 0x7fffu + ((u >> 16) & 1u)) >> 16;
    return (u16)r;
}
// packed RNE f32x2 -> bf16x2 (hardware v_cvt_pk_bf16_f32 on gfx950)
__device__ __forceinline__ unsigned pk2bf(float a, float b) {
    __hip_bfloat162 h = __float22bfloat162_rn(make_float2(a, b));
    unsigned r; __builtin_memcpy(&r, &h, 4); return r;
}

// async global->LDS, 16B per lane, wave-uniform LDS base + lane*16
__device__ __forceinline__ void ldsload16(const u16* g, u16* l) {
    __builtin_amdgcn_global_load_lds(
        (const __attribute__((address_space(1))) unsigned int*)g,
        (__attribute__((address_space(3))) unsigned int*)l, 16, 0, 0);
}

__device__ __forceinline__ int swz(int r) { return (r ^ (r >> 2)) & 3; }

// ---------------- bicubic helper ----------------
__device__ inline float cubic_keys(float x) {
    x = fabsf(x);
    if (x <= 1.f) return ((1.5f * x - 2.5f) * x) * x + 1.f;
    if (x < 2.f)  return ((-0.5f * x + 2.5f) * x - 4.f) * x + 2.f;
    return 0.f;
}

// ---------------- one-shot setup (x4 vectorized) -----------------------------
__global__ __launch_bounds__(256) void setup_kernel(
        const float* __restrict__ p0, const float* __restrict__ p1,
        const float* __restrict__ p2, const float* __restrict__ p3,
        const float* __restrict__ p4, const float* __restrict__ p5,
        u16* __restrict__ wb, const float* __restrict__ pe,
        float* __restrict__ posr, const float* __restrict__ x,
        u16* __restrict__ col) {
    int i = (blockIdx.x * 256 + threadIdx.x) * 4;
    if (i < 10918656) {
        const float* s; int off;
        if      (i <   294912) { s = p0; off = 0; }
        else if (i <  2949120) { s = p1; off = 294912; }
        else if (i <  3833856) { s = p2; off = 2949120; }
        else if (i <  7372800) { s = p3; off = 3833856; }
        else if (i < 10911744) { s = p4; off = 7372800; }
        else                   { s = p5; off = 10911744; }
        float4 v = *(const float4*)(s + (i - off));
        u16 o[4] = { f2bf(v.x), f2bf(v.y), f2bf(v.z), f2bf(v.w) };
        *(uint2*)(wb + i) = *(const uint2*)o;
        return;
    }
    i -= 10918656;
    if (i < 393216) {
        int c = i % 384;
        int g = i / 384;
        int gy = g / 32, gx = g % 32;
        float wy[14], wx[14];
        float sy = (gy + 0.5f) * (14.f / 32.f) - 0.5f;
        float sx = (gx + 0.5f) * (14.f / 32.f) - 0.5f;
        float toty = 0.f, totx = 0.f;
        #pragma unroll
        for (int k = 0; k < 14; ++k) {
            wy[k] = cubic_keys(sy - (float)k); toty += wy[k];
            wx[k] = cubic_keys(sx - (float)k); totx += wx[k];
        }
        float4 acc = {0.f, 0.f, 0.f, 0.f};
        #pragma unroll 1
        for (int iy = 0; iy < 14; ++iy) {
            if (wy[iy] == 0.f) continue;
            float4 row = {0.f, 0.f, 0.f, 0.f};
            for (int ix = 0; ix < 14; ++ix) {
                if (wx[ix] == 0.f) continue;
                float4 pv = *(const float4*)(pe + (iy * 14 + ix) * 384 + c);
                row.x += wx[ix] * pv.x; row.y += wx[ix] * pv.y;
                row.z += wx[ix] * pv.z; row.w += wx[ix] * pv.w;
            }
            acc.x += wy[iy] * row.x; acc.y += wy[iy] * row.y;
            acc.z += wy[iy] * row.z; acc.w += wy[iy] * row.w;
        }
        float inv = 1.f / (toty * totx);
        acc.x *= inv; acc.y *= inv; acc.z *= inv; acc.w *= inv;
        *(float4*)(posr + i) = acc;
        return;
    }
    i -= 393216;
    if (i < 3145728) {
        int kk = i % 768;
        int p  = i / 768;
        int b  = p / 1024;
        int ph = (p % 1024) / 32;
        int pw = p % 32;
        int c = kk / 256;
        int r = kk % 256;
        int ii = r / 16, j = r % 16;
        float4 v = *(const float4*)(x + (size_t)b * 3 * 512 * 512 +
                                    (size_t)c * 512 * 512 +
                                    (size_t)(ph * 16 + ii) * 512 + (pw * 16 + j));
        u16 o[4] = { f2bf(v.x), f2bf(v.y), f2bf(v.z), f2bf(v.w) };
        *(uint2*)(col + i) = *(const uint2*)o;
    }
}

// ---------------- fused split-K epilogue + residual + LN / NCHW-out ----------
__global__ __launch_bounds__(64) void epi_ln_kernel(const float* __restrict__ P,
        const float* __restrict__ bias, const float* __restrict__ posr,
        float* __restrict__ y, int addy, int nsk,
        const float* __restrict__ lw, const float* __restrict__ lb,
        u16* __restrict__ lnout, float* __restrict__ outT)
{
    int tok = blockIdx.x, t = threadIdx.x;
    size_t base = (size_t)tok * 384;
    float v[6];
    float s = 0.f;
    #pragma unroll
    for (int i = 0; i < 6; ++i) {
        int c = t + 64 * i;
        float val = bias[c];
        #pragma unroll 1
        for (int sk = 0; sk < nsk; ++sk)
            val += P[(size_t)sk * 1572864 + base + c];
        if (posr) val += posr[(size_t)(tok & 1023) * 384 + c];
        if (addy) val += y[base + c];
        v[i] = val; s += val;
    }
    if (outT) {
        int b = tok >> 10, g = tok & 1023;
        #pragma unroll
        for (int i = 0; i < 6; ++i) {
            int c = t + 64 * i;
            outT[((size_t)(b * 384 + c)) * 1024 + g] = v[i];
        }
        return;
    }
    #pragma unroll
    for (int i = 0; i < 6; ++i) y[base + t + 64 * i] = v[i];
    if (!lnout) return;
    #pragma unroll
    for (int off = 32; off > 0; off >>= 1) s += __shfl_xor(s, off);
    float mean = s * (1.f / 384.f);
    float vs = 0.f;
    #pragma unroll
    for (int i = 0; i < 6; ++i) { float d = v[i] - mean; vs += d * d; }
    #pragma unroll
    for (int off = 32; off > 0; off >>= 1) vs += __shfl_xor(vs, off);
    float inv = rsqrtf(vs * (1.f / 384.f) + 1e-5f);
    u16* orow = lnout + base;
    #pragma unroll
    for (int i = 0; i < 6; ++i) {
        int c = t + 64 * i;
        orow[c] = f2bf((v[i] - mean) * inv * lw[c] + lb[c]);
    }
}

// ---------------- MFMA bf16 GEMM v4: BM=128, BN=64, BK=64, split-K, dbuf -----
__global__ __launch_bounds__(256) void mfma_gemm4(
        const u16* __restrict__ A, const u16* __restrict__ Wt,
        const float* __restrict__ bias,
        float* __restrict__ outf, u16* __restrict__ outb,
        float* __restrict__ outp,
        int M, int N, int K, int act, int ksplit)
{
    __shared__ u16 As[2][8192];
    __shared__ u16 Bs[2][4096];
    int t = threadIdx.x;
    int lane = t & 63, wave = t >> 6;
    int wm = (wave >> 1) * 64, wn = (wave & 1) * 32;
    int m0 = blockIdx.y * 128, n0 = blockIdx.x * 64;
    int ks = blockIdx.z * ksplit;

    int r0 = t >> 2,        c0 = ((t & 3) ^ swz(t >> 2)) * 8;
    int r1 = 64 + (t >> 2), c1 = ((t & 3) ^ swz(64 + (t >> 2))) * 8;
    const u16* a0 = A + (size_t)(m0 + r0) * K + c0;
    const u16* a1 = A + (size_t)(m0 + r1) * K + c1;
    const u16* b0 = Wt + (size_t)(n0 + r0) * K + c0;

    auto stage = [&](int k0, int buf) {
        ldsload16(a0 + k0,      &As[buf][wave * 512]);
        ldsload16(a1 + k0,      &As[buf][2048 + wave * 512]);
        ldsload16(b0 + k0,      &Bs[buf][wave * 512]);
        ldsload16(a0 + k0 + 32, &As[buf][4096 + wave * 512]);
        ldsload16(a1 + k0 + 32, &As[buf][6144 + wave * 512]);
        ldsload16(b0 + k0 + 32, &Bs[buf][2048 + wave * 512]);
    };

    f32x4 acc[4][2] = {};
    int row_a = wm + (lane & 15);
    int row_b = wn + (lane & 15);
    int lq = lane >> 4;
    int nchunks = ksplit / 64;

    stage(ks, 0);
    __syncthreads();

    for (int ci = 0; ci < nchunks; ++ci) {
        int p = ci & 1;
        bool pref = (ci + 1 < nchunks);
        if (pref) stage(ks + (ci + 1) * 64, 1 - p);
        #pragma unroll
        for (int hf = 0; hf < 2; ++hf) {
            bf16x8 af[4], bfr[2];
            #pragma unroll
            for (int i = 0; i < 4; ++i) {
                int r = row_a + i * 16;
                af[i] = *(const bf16x8*)&As[p][hf * 4096 + r * 32 + ((lq ^ swz(r)) * 8)];
            }
            #pragma unroll
            for (int j = 0; j < 2; ++j) {
                int r = row_b + j * 16;
                bfr[j] = *(const bf16x8*)&Bs[p][hf * 2048 + r * 32 + ((lq ^ swz(r)) * 8)];
            }
            #pragma unroll
            for (int i = 0; i < 4; ++i)
                #pragma unroll
                for (int j = 0; j < 2; ++j)
                    acc[i][j] = __builtin_amdgcn_mfma_f32_16x16x32_bf16(
                        af[i], bfr[j], acc[i][j], 0, 0, 0);
        }
        if (pref) __syncthreads();
    }

    int colq = lane & 15, rowq = (lane >> 4) * 4;
    if (outp) {
        float* pp = outp + (size_t)blockIdx.z * M * N;
        #pragma unroll
        for (int i = 0; i < 4; ++i) {
            #pragma unroll
            for (int rr = 0; rr < 4; ++rr) {
                int m = m0 + wm + i * 16 + rowq + rr;
                size_t mo = (size_t)m * N;
                #pragma unroll
                for (int j = 0; j < 2; ++j) {
                    int n = n0 + wn + j * 16 + colq;
                    pp[mo + n] = acc[i][j][rr];
                }
            }
        }
        return;
    }
    #pragma unroll
    for (int i = 0; i < 4; ++i) {
        #pragma unroll
        for (int rr = 0; rr < 4; ++rr) {
            int m = m0 + wm + i * 16 + rowq + rr;
            size_t mo = (size_t)m * N;
            #pragma unroll
            for (int j = 0; j < 2; ++j) {
                int n = n0 + wn + j * 16 + colq;
                float v = acc[i][j][rr] + bias[n];
                if (act)  v = 0.5f * v * (1.f + erff(v * 0.70710678118654752f));
                if (outf) outf[mo + n] = v;
                if (outb) outb[mo + n] = f2bf(v);
            }
        }
    }
}

// ---------------- MFMA flash attention ---------------------------------------
// W==32: global, grid (24, 16, 2) -- key-split 2, unnormalized partials out.
// W==14: windowed, grid (216, 4, 1) -- direct bf16 out, incremental coords.
template<int N, int W>
__global__ __launch_bounds__(256) void attn_mfma(const u16* __restrict__ qkv,
        const u16* __restrict__ qkb, const float* __restrict__ rh,
        const float* __restrict__ rw, u16* __restrict__ outb,
        float* __restrict__ opart, float* __restrict__ lpart)
{
    constexpr int JS = (W == 32) ? 64 : 32;
    constexpr int L  = (W == 32) ? 63 : 27;
    constexpr int CTR = W - 1;
    constexpr int KSPAN = (W == 32) ? 512 : 224;
    constexpr int NKT = KSPAN / 32;
    __shared__ u16 KV[11776];  // Ks[2][2048] | Vt[2][2560] | Pb[2560]
    __shared__ u16 bhl[64 * 66];
    __shared__ u16 bwl[64 * 66];
    __shared__ u16 Qt[64 * 66];

    u16* Pb = KV + 9216;
    u16* Rt = KV;

    int t = threadIdx.x, lane = t & 63, wave = t >> 6;
    int quad = lane >> 4, l15 = lane & 15;
    int uh = blockIdx.x, qb0 = blockIdx.y * 64;
    int z = (W == 32) ? blockIdx.z : 0;
    int kstart = z * KSPAN;
    int h = uh % HEADS, u = uh / HEADS;
    size_t tbase = (size_t)u * 1024;
    int wb_ = u / 9, wr = u - wb_ * 9;
    int wy = wr / 3, wx = wr - wy * 3;

    auto tok14 = [&](int iy, int ix) -> const u16* {
        int gy = wy * WS + iy, gx = wx * WS + ix;
        if (gy < 32 && gx < 32)
            return qkv + (size_t)(wb_ * 1024 + gy * 32 + gx) * 1152;
        return qkb;
    };
    auto rowptr = [&](int lq2) -> const u16* {   // div-based, prologue only
        if constexpr (W == 32) {
            return qkv + (tbase + lq2) * 1152;
        } else {
            int iy = lq2 / WS, ix = lq2 - iy * WS;
            return tok14(iy, ix);
        }
    };

    // ---- stage Q^T (unscaled) ----
    {
        int q = t & 63, ch0 = (t >> 6) * 16;
        int qc = qb0 + q; if (qc >= N) qc = N - 1;
        const u16* qp = rowptr(qc) + h * 64 + ch0;
        uint4 a = *(const uint4*)qp;
        uint4 b = *(const uint4*)(qp + 8);
        u16 vals[16];
        *(uint4*)vals = a; *(uint4*)(vals + 8) = b;
        #pragma unroll
        for (int c = 0; c < 16; ++c)
            Qt[(ch0 + c) * 66 + q] = ((qb0 + q) < N) ? vals[c] : (u16)0;
    }

    // ---- fused rel-pos bias D = Q . R^T (both tables) ----
    #pragma unroll
    for (int table = 0; table < 2; ++table) {
        __syncthreads();
        const float* tab = table ? rw : rh;
        for (int idx = t; idx < JS * 8; idx += 256) {
            int j = idx >> 3, cc0 = (idx & 7) * 8;
            u16 tmp[8];
            if (j < L) {
                const float* src = tab + (size_t)j * 64 + cc0;
                #pragma unroll
                for (int c = 0; c < 8; ++c) tmp[c] = f2bf(src[c]);
            } else {
                #pragma unroll
                for (int c = 0; c < 8; ++c) tmp[c] = 0;
            }
            *(uint4*)&Rt[j * 72 + cc0] = *(uint4*)tmp;
        }
        __syncthreads();
        if (wave < JS / 16) {
            int jt = wave;
            bf16x8 af0 = *(const bf16x8*)&Rt[(jt * 16 + l15) * 72 + quad * 8];
            bf16x8 af1 = *(const bf16x8*)&Rt[(jt * 16 + l15) * 72 + 32 + quad * 8];
            u16* dst = table ? bwl : bhl;
            #pragma unroll
            for (int qt = 0; qt < 4; ++qt) {
                bf16x8 qf0, qf1;
                u16* p0 = (u16*)&qf0; u16* p1 = (u16*)&qf1;
                #pragma unroll
                for (int zz = 0; zz < 8; ++zz) {
                    p0[zz] = Qt[(quad * 8 + zz) * 66 + qt * 16 + l15];
                    p1[zz] = Qt[(32 + quad * 8 + zz) * 66 + qt * 16 + l15];
                }
                f32x4 acc = {};
                acc = __builtin_amdgcn_mfma_f32_16x16x32_bf16(af0, qf0, acc, 0, 0, 0);
                acc = __builtin_amdgcn_mfma_f32_16x16x32_bf16(af1, qf1, acc, 0, 0, 0);
                #pragma unroll
                for (int r = 0; r < 4; ++r)
                    dst[(qt * 16 + l15) * 66 + jt * 16 + quad * 4 + r] = f2bf(acc[r]);
            }
        }
    }
    __syncthreads();

    // ---- per-lane staging coordinates (incremental for W==14) ----
    int skey = (wave * 64 + lane) >> 3;             // K-stage key (0..31)
    int sc8  = ((wave * 64 + lane) & 7) ^ (skey & 7);
    int vkey = t & 31, vch0 = (t >> 5) * 8;         // V-stage key/ch
    int siy = 0, six = 0, viy = 0, vix = 0;
    if constexpr (W != 32) {
        int k0 = kstart + skey;   // kstart==0
        siy = k0 / WS; six = k0 - siy * WS;
        int k1 = kstart + vkey;
        viy = k1 / WS; vix = k1 - viy * WS;
    }
    auto adv = [](int& iy, int& ix) { ix += 4; iy += 2; if (ix >= WS) { ix -= WS; ++iy; } };

    // ---- stage tile 0 into buffer 0 ----
    {
        const u16* kp = (W == 32) ? qkv + (tbase + kstart + skey) * 1152
                                  : tok14(siy, six);
        ldsload16(kp + 384 + h * 64 + sc8 * 8, KV + wave * 512);
        const u16* vp = (W == 32) ? qkv + (tbase + kstart + vkey) * 1152
                                  : tok14(viy, vix);
        uint4 vv = *(const uint4*)(vp + 768 + h * 64 + vch0);
        u16 tmp[8]; *(uint4*)tmp = vv;
        u16* vdst = KV + 4096;
        #pragma unroll
        for (int c = 0; c < 8; ++c) vdst[(vch0 + c) * 40 + vkey] = tmp[c];
        if constexpr (W != 32) { adv(siy, six); adv(viy, vix); }
    }

    // Q^T B-frags (loop-invariant; scale applied to scores)
    bf16x8 qf[2];
    #pragma unroll
    for (int hc = 0; hc < 2; ++hc) {
        u16* qv = (u16*)&qf[hc];
        #pragma unroll
        for (int j = 0; j < 8; ++j)
            qv[j] = Qt[(hc * 32 + quad * 8 + j) * 66 + wave * 16 + l15];
    }
    int qme = wave * 16 + l15;
    int qq = qb0 + qme; if (qq >= N) qq = N - 1;
    int qh = qq / W, qw = qq - qh * W;
    float bwreg[2][4];
    int kh_[2][4], kw_[2][4];
    #pragma unroll
    for (int kc2 = 0; kc2 < 2; ++kc2)
        #pragma unroll
        for (int r = 0; r < 4; ++r) {
            int keyl = kc2 * 16 + quad * 4 + r;
            if constexpr (W == 32) {
                bwreg[kc2][r] = bf2f(bwl[qme * 66 + (qw - keyl + CTR)]);
            } else {
                kh_[kc2][r] = keyl / WS;
                kw_[kc2][r] = keyl - kh_[kc2][r] * WS;
            }
        }

    f32x4 of[4] = {};
    float lsum = 0.f;
    __syncthreads();   // tile 0 staged (vmcnt drained)

    for (int kt = 0; kt < NKT; ++kt) {
        int kb = kstart + kt * 32;
        int p = kt & 1;
        const u16* ksp = KV + p * 2048;
        const u16* vtp = KV + 4096 + p * 2560;
        bool pref = (kt + 1 < NKT);
        uint4 vpref;
        if (pref) {
            const u16* kp = (W == 32) ? qkv + (tbase + kb + 32 + skey) * 1152
                                      : tok14(siy, six);
            ldsload16(kp + 384 + h * 64 + sc8 * 8, KV + (1 - p) * 2048 + wave * 512);
            const u16* vp = (W == 32) ? qkv + (tbase + kb + 32 + vkey) * 1152
                                      : tok14(viy, vix);
            vpref = *(const uint4*)(vp + 768 + h * 64 + vch0);
            if constexpr (W != 32) { adv(siy, six); adv(viy, vix); }
        }

        // ---- compute tile kt ----
        f32x4 st[2] = {};
        #pragma unroll
        for (int hc = 0; hc < 2; ++hc) {
            #pragma unroll
            for (int kc2 = 0; kc2 < 2; ++kc2) {
                int key = kc2 * 16 + l15;
                int c8 = hc * 4 + quad;
                int pp = key * 8 + (c8 ^ (key & 7));
                bf16x8 kf = *(const bf16x8*)&ksp[pp * 8];
                st[kc2] = __builtin_amdgcn_mfma_f32_16x16x32_bf16(
                    kf, qf[hc], st[kc2], 0, 0, 0);
            }
        }
        float bh_t = 0.f;
        if constexpr (W == 32) bh_t = bf2f(bhl[qme * 66 + (qh - (kb >> 5) + CTR)]);
        #pragma unroll
        for (int kc2 = 0; kc2 < 2; ++kc2) {
            float pv4[4];
            #pragma unroll
            for (int r = 0; r < 4; ++r) {
                int keyl = kc2 * 16 + quad * 4 + r;
                float b;
                if constexpr (W == 32) {
                    b = bh_t + bwreg[kc2][r];
                } else {
                    b = bf2f(bhl[qme * 66 + (qh - kh_[kc2][r] + CTR)]) +
                        bf2f(bwl[qme * 66 + (qw - kw_[kc2][r] + CTR)]);
                }
                float pv = __expf(fmaf(st[kc2][r], 0.125f, b));
                if (kb + keyl >= N) pv = 0.f;
                lsum += pv;
                pv4[r] = pv;
            }
            uint2 pk;
            pk.x = pk2bf(pv4[0], pv4[1]);
            pk.y = pk2bf(pv4[2], pv4[3]);
            *(uint2*)&Pb[wave * 640 + l15 * 40 + kc2 * 16 + quad * 4] = pk;
        }
        if constexpr (W != 32) {
            #pragma unroll
            for (int kc2 = 0; kc2 < 2; ++kc2)
                #pragma unroll
                for (int r = 0; r < 4; ++r) {
                    kw_[kc2][r] += 4; kh_[kc2][r] += 2;
                    if (kw_[kc2][r] >= WS) { kw_[kc2][r] -= WS; ++kh_[kc2][r]; }
                }
        }
        bf16x8 pf = *(const bf16x8*)&Pb[wave * 640 + l15 * 40 + quad * 8];
        #pragma unroll
        for (int ca = 0; ca < 4; ++ca) {
            bf16x8 vf = *(const bf16x8*)&vtp[(ca * 16 + l15) * 40 + quad * 8];
            of[ca] = __builtin_amdgcn_mfma_f32_16x16x32_bf16(
                vf, pf, of[ca], 0, 0, 0);
        }

        if (pref) {
            u16 tmp[8]; *(uint4*)tmp = vpref;
            u16* vdst = KV + 4096 + (1 - p) * 2560;
            #pragma unroll
            for (int c = 0; c < 8; ++c) vdst[(vch0 + c) * 40 + vkey] = tmp[c];
            __syncthreads();
        }
    }

    lsum += __shfl_xor(lsum, 16);
    lsum += __shfl_xor(lsum, 32);
    int q = qb0 + qme;
    if constexpr (W == 32) {
        // unnormalized partials: O fp32 + l
        size_t ridx = (size_t)z * 24576 + (size_t)uh * 1024 + q;
        float* op = opart + ridx * 64;
        #pragma unroll
        for (int ca = 0; ca < 4; ++ca)
            *(float4*)&op[ca * 16 + quad * 4] = (float4){of[ca][0], of[ca][1],
                                                         of[ca][2], of[ca][3]};
        if (quad == 0) lpart[ridx] = lsum;
    } else {
        float inv = 1.f / lsum;
        if (q < N) {
            int iy = q / WS, ix = q - iy * WS;
            int gy = wy * WS + iy, gx = wx * WS + ix;
            if (gy >= 32 || gx >= 32) return;
            u16* op = outb + (size_t)(wb_ * 1024 + gy * 32 + gx) * 384 + h * 64;
            #pragma unroll
            for (int ca = 0; ca < 4; ++ca) {
                uint2 pk;
                pk.x = pk2bf(of[ca][0] * inv, of[ca][1] * inv);
                pk.y = pk2bf(of[ca][2] * inv, of[ca][3] * inv);
                *(uint2*)&op[ca * 16 + quad * 4] = pk;
            }
        }
    }
}

// ---------------- merge split-key attention partials -------------------------
__global__ __launch_bounds__(256) void attn_merge_kernel(const float* __restrict__ O,
        const float* __restrict__ Lp, u16* __restrict__ attb)
{
    int t = threadIdx.x;
    int idx = blockIdx.x * 4 + (t >> 6);   // uh*1024 + q
    int ch = t & 63;
    float o = O[(size_t)idx * 64 + ch] + O[((size_t)24576 + idx) * 64 + ch];
    float l = Lp[idx] + Lp[24576 + idx];
    int uh = idx >> 10, q = idx & 1023;
    int u = uh / 6, h = uh - u * 6;
    attb[((size_t)(u * 1024 + q)) * 384 + h * 64 + ch] = f2bf(o / l);
}

// ---------------- host helpers ----------------
static inline void launch_gemm(const u16* A, const u16* W, const float* bias,
                               float* outf, u16* outb,
                               int M, int N, int K, int act, hipStream_t s) {
    dim3 g(N / 64, M / 128, 1);
    mfma_gemm4<<<g, 256, 0, s>>>(A, W, bias, outf, outb, nullptr, M, N, K, act, K);
}

static inline void launch_gemm_sk(const u16* A, const u16* W, float* P,
                                  int M, int N, int K, int SK, hipStream_t s) {
    dim3 g(N / 64, M / 128, SK);
    mfma_gemm4<<<g, 256, 0, s>>>(A, W, nullptr, nullptr, nullptr, P,
                                 M, N, K, 0, K / SK);
}

extern "C" void kernel_launch(void* const* d_in, const int* in_sizes, int n_in,
                              void* d_out, int out_size, void* d_ws, size_t ws_size,
                              hipStream_t stream) {
    const float* x      = (const float*)d_in[0];
    const float* patchw = (const float*)d_in[1];
    const float* patchb = (const float*)d_in[2];
    const float* pos    = (const float*)d_in[3];
    const float* n1w    = (const float*)d_in[4];
    const float* n1b    = (const float*)d_in[5];
    const float* qkvw   = (const float*)d_in[6];
    const float* qkvb   = (const float*)d_in[7];
    const float* pw     = (const float*)d_in[8];
    const float* pb     = (const float*)d_in[9];
    const float* n2w    = (const float*)d_in[10];
    const float* n2b    = (const float*)d_in[11];
    const float* f1w    = (const float*)d_in[12];
    const float* f1b    = (const float*)d_in[13];
    const float* f2w    = (const float*)d_in[14];
    const float* f2b    = (const float*)d_in[15];
    const float* rph    = (const float*)d_in[16];
    const float* rpw    = (const float*)d_in[17];
    float* out = (float*)d_out;

    // workspace layout. Overlays cover only dead buffers:
    //  P_patch = attb..mlpb (patch GEMM phase)
    //  P_pf    = qkvx..rsrv (proj/fc2 phases)
    //  Opart   = mlpb (global-attn phase), Lpart = lnb (dead post-qkv)
    float* y   = (float*)d_ws;                  // 1,572,864 f32
    u16* attb  = (u16*)(y + 1572864);           // 1,572,864 u16 (token layout)
    u16* mlpb  = attb + 1572864;                // 6,291,456 u16
    u16* lnb   = mlpb + 6291456;                // 1,572,864 u16
    u16* qkvx  = lnb + 1572864;                 // 4,718,592 u16 (4096x1152)
    u16* rsrv  = qkvx + 4718592;                // 7,864,320 u16
    u16* wb    = rsrv + 7864320;                // 10,918,656 u16 (weights + qkv bias)
    float* posr = (float*)(wb + 10918656);      //   393,216 f32

    u16* colb  = rsrv;                          // overlay: im2col 3,145,728 u16
    float* P_patch = (float*)attb;              // 2 slices over attb+mlpb
    float* P_pf    = (float*)qkvx;              // 2 slices over qkvx+rsrv[:1.6M]
    float* Opart   = (float*)mlpb;              // 2x24576x64 f32 = 12,582,912 B
    float* Lpart   = (float*)lnb;               // 2x24576 f32

    u16* wb_patch = wb;
    u16* wb_qkv   = wb + 294912;
    u16* wb_pw    = wb + 2949120;
    u16* wb_f1    = wb + 3833856;
    u16* wb_f2    = wb + 7372800;
    u16* wqb      = wb + 10911744;              // bf16 qkv bias, 6 x 1152

    setup_kernel<<<(14457600 / 4 + 255) / 256, 256, 0, stream>>>(
        patchw, qkvw, pw, f1w, f2w, qkvb, wb, pos, posr, x, colb);

    launch_gemm_sk(colb, wb_patch, P_patch, NTOK, 384, 768, 2, stream);
    epi_ln_kernel<<<NTOK, 64, 0, stream>>>(P_patch, patchb, posr, y, 0, 2,
                                           n1w, n1b, lnb, nullptr);

    for (int i = 0; i < 6; ++i) {
        bool windowed = (i == 0 || i == 1 || i == 3 || i == 4);
        const float* rh = rph + (size_t)i * 63 * 64;
        const float* rw = rpw + (size_t)i * 63 * 64;
        launch_gemm(lnb, wb_qkv + (size_t)i * 442368, qkvb + i * 1152,
                    nullptr, qkvx, NTOK, 1152, 384, 0, stream);
        if (windowed) {
            attn_mfma<WTOK, WS><<<dim3(NWIN * HEADS, 4, 1), 256, 0, stream>>>(
                qkvx, wqb + i * 1152, rh, rw, attb, nullptr, nullptr);
        } else {
            attn_mfma<1024, 32><<<dim3(B_SZ * HEADS, 16, 2), 256, 0, stream>>>(
                qkvx, wqb + i * 1152, rh, rw, nullptr, Opart, Lpart);
            attn_merge_kernel<<<6144, 256, 0, stream>>>(Opart, Lpart, attb);
        }
        launch_gemm_sk(attb, wb_pw + (size_t)i * 147456, P_pf,
                       NTOK, 384, 384, 2, stream);
        epi_ln_kernel<<<NTOK, 64, 0, stream>>>(P_pf, pb + i * 384, nullptr, y, 1, 2,
                                               n2w + i * 384, n2b + i * 384, lnb,
                                               nullptr);
        launch_gemm(lnb, wb_f1 + (size_t)i * 589824, f1b + i * 1536,
                    nullptr, mlpb, NTOK, 1536, 384, 1, stream);
        launch_gemm_sk(mlpb, wb_f2 + (size_t)i * 589824, P_pf,
                       NTOK, 384, 1536, 2, stream);
        if (i < 5)
            epi_ln_kernel<<<NTOK, 64, 0, stream>>>(P_pf, f2b + i * 384, nullptr, y,
                                                   1, 2, n1w + (i + 1) * 384,
                                                   n1b + (i + 1) * 384, lnb, nullptr);
        else
            epi_ln_kernel<<<NTOK, 64, 0, stream>>>(P_pf, f2b + i * 384, nullptr, y,
                                                   1, 2, nullptr, nullptr, nullptr,
                                                   out);
    }
}